// Round 6
// baseline (190.332 us; speedup 1.0000x reference)
//
#include <hip/hip_runtime.h>

// ---------------- problem constants ----------------
#define NROI  100
#define NB    4          // 400/100 diagonal blocks
#define NEDGE 160000
#define RESN  1000
#define SAMP  50
#define BREP  8          // batch tiling (B=8)
#define MDEG  44         // effective polynomial rank cutoff
#define NMODE (MDEG + 1)
#define BIGF  1.0e9f
#define PAIR_N 4950      // NROI*(NROI-1)/2 upper-triangular pairs (fixed, sentinel-masked)

// ---------------- static device workspace ----------------
__device__ float  g_adj[NB * NROI * NROI];
__device__ float  g_D[NB * NROI * NROI];
__device__ float  g_death1[NB * NROI * NROI];
__device__ float  g_deaths[NB][NROI - 1];
__device__ int    g_usv[NB][NROI - 1];
__device__ int    g_vsv[NB][NROI - 1];
__device__ int    g_par[NB][NROI];
__device__ float2 g_pair[NB][PAIR_N];   // (birth, death) per pair; sentinel (+BIG,-BIG) if MST
__device__ float  g_betti[NB * RESN];
__device__ float  g_smin[NB], g_smax[NB];
__device__ int    g_bnz;              // any nonzero betti? (gates basis/fit)
__device__ double g_q[NMODE][RESN];   // orthonormal poly basis values
__device__ double g_qd[NMODE][RESN];  // derivatives d/dx

// ---------------- helpers ----------------
__device__ inline double wave_sum_f64(double p) {
    for (int off = 32; off > 0; off >>= 1) p += __shfl_xor(p, off, 64);
    return p;
}

// ---------------- 1) zero accumulators ----------------
__global__ void k_zero() {
    const int tid = blockIdx.x * blockDim.x + threadIdx.x;
    if (tid < NB * NROI * NROI) g_adj[tid] = 0.f;
    if (tid == 0) g_bnz = 0;
}

// ---------------- 2) scatter-add diagonal-block edges ----------------
__global__ void k_scatter(const int* __restrict__ ei, const float* __restrict__ ea) {
    const int e = blockIdx.x * blockDim.x + threadIdx.x;
    if (e >= NEDGE) return;
    const int r = ei[e], c = ei[NEDGE + e];
    const int br = r / NROI, bc = c / NROI;
    if (br == bc)
        atomicAdd(&g_adj[br * NROI * NROI + (r - br * NROI) * NROI + (c - bc * NROI)], ea[e]);
}

// ---------------- 3) fused: D = max(1-adj,0) + H1 deaths ----------------
// death1[i,j] = max(D_ij, min_k!=i,j max(D_ik,D_jk)); fmin/fmax exact -> assoc-free.
__device__ inline float dclamp(float a) { const float d = 1.f - a; return d > 0.f ? d : 0.f; }
__global__ void k_death1() {
    const int tid = blockIdx.x * blockDim.x + threadIdx.x;
    if (tid >= NB * NROI * NROI) return;
    const int b  = tid / (NROI * NROI);
    const int ij = tid % (NROI * NROI);
    const int i = ij / NROI, j = ij % NROI;
    const float* __restrict__ ai = g_adj + b * NROI * NROI + i * NROI;
    const float* __restrict__ aj = g_adj + b * NROI * NROI + j * NROI;
    float Tm = BIGF;
    float dij = 0.f;
    for (int k = 0; k < NROI; k += 4) {
        const float4 a = *(const float4*)(ai + k);
        const float4 c = *(const float4*)(aj + k);
        const float di0 = dclamp(a.x), di1 = dclamp(a.y), di2 = dclamp(a.z), di3 = dclamp(a.w);
        const float dj0 = dclamp(c.x), dj1 = dclamp(c.y), dj2 = dclamp(c.z), dj3 = dclamp(c.w);
        float m0 = (k + 0 == i || k + 0 == j) ? BIGF : fmaxf(di0, dj0);
        float m1 = (k + 1 == i || k + 1 == j) ? BIGF : fmaxf(di1, dj1);
        float m2 = (k + 2 == i || k + 2 == j) ? BIGF : fmaxf(di2, dj2);
        float m3 = (k + 3 == i || k + 3 == j) ? BIGF : fmaxf(di3, dj3);
        Tm = fminf(Tm, fminf(fminf(m0, m1), fminf(m2, m3)));
        if (j >= k && j < k + 4) dij = (j == k) ? di0 : (j == k + 1) ? di1 : (j == k + 2) ? di2 : di3;
    }
    g_D[tid]      = dij;
    g_death1[tid] = fmaxf(dij, Tm);
}

// ---------------- 4) Prim MST loop ONLY (single wave per block) ----------------
__global__ void __launch_bounds__(64) k_prim() {
    const int b = blockIdx.x, lane = threadIdx.x;
    const float* __restrict__ Db = g_D + b * NROI * NROI;
    __shared__ float deathsL[NROI - 1];
    __shared__ int   usL[NROI - 1], vsL[NROI - 1];
    const int  i1   = 64 + lane;
    const bool has1 = (i1 < NROI);
    // column-major zero bitmasks straight from global (coalesced per row): lane t = column t.
    unsigned int zc0[4] = {0, 0, 0, 0}, zc1[4] = {0, 0, 0, 0};
    #pragma unroll 4
    for (int j = 0; j < NROI; ++j) {
        const unsigned int bit = 1u << (j & 31);
        if (Db[j * NROI + lane] == 0.f) zc0[j >> 5] |= bit;
        if (has1 && Db[j * NROI + i1] == 0.f) zc1[j >> 5] |= bit;
    }
    unsigned long long Clo = __ballot((zc0[0] & 1u) != 0u);   // row 0 = bit 0 of each column
    unsigned long long Chi = __ballot((zc1[0] & 1u) != 0u);
    unsigned long long Tlo = 1ull, Thi = 0ull;
    bool it0 = (lane == 0), it1 = false;
    bool cand0 = (zc0[0] & 1u) != 0u;
    bool cand1 = (zc1[0] & 1u) != 0u;
    int  par0 = 0, par1 = 0;                     // first zero-offerer (frozen once cand)

    #pragma unroll 1
    for (int step = 0; step < NROI - 1; ++step) {
        const unsigned long long alo = Clo & ~Tlo, ahi = Chi & ~Thi;
        int j;
        if (alo | ahi) {
            // jnp.argmin first-index == first not-in-tree node with mind==0 (D >= 0 always)
            j = alo ? (__ffsll(alo) - 1) : (63 + __ffsll(ahi));
            if (lane == 0) { deathsL[step] = 0.f; usL[step] = -1; vsL[step] = j; }
        } else {
            // rare general fallback: replay mind/parent over insertion order, exact butterfly argmin
            __syncthreads();   // make lane-0 vsL writes visible (uniform branch)
            float m0 = Db[lane]; int p0 = 0;
            float m1 = has1 ? Db[i1] : BIGF; int p1 = 0;
            for (int s = 0; s < step; ++s) {
                const int q = vsL[s];
                const float d0 = Db[q * NROI + lane];
                if (d0 < m0) { m0 = d0; p0 = q; }     // strict <, as reference
                if (has1) {
                    const float d1 = Db[q * NROI + i1];
                    if (d1 < m1) { m1 = d1; p1 = q; }
                }
            }
            const float v0 = it0 ? BIGF : m0;
            const float v1 = (has1 && !it1) ? m1 : BIGF;
            float vv; int idx, pw;
            if (v0 <= v1) { vv = v0; idx = lane; pw = p0; } else { vv = v1; idx = i1; pw = p1; }
            #pragma unroll
            for (int off = 1; off < 64; off <<= 1) {
                const float ov = __shfl_xor(vv, off, 64);
                const int   oi = __shfl_xor(idx, off, 64);
                const int   op = __shfl_xor(pw, off, 64);
                if (ov < vv || (ov == vv && oi < idx)) { vv = ov; idx = oi; pw = op; }
            }
            j = idx;
            if (lane == 0) { deathsL[step] = vv; usL[step] = pw; vsL[step] = j; }
        }
        if (j < 64) Tlo |= 1ull << j; else Thi |= 1ull << (j - 64);
        if (lane == j) it0 = true;
        if (i1 == j)   it1 = true;
        // extract bit j of MY columns (same-lane VALU), rebuild row j's mask via ballot
        const int d = j >> 5, sh = j & 31;
        const unsigned int w0 = (d == 0) ? zc0[0] : (d == 1) ? zc0[1] : (d == 2) ? zc0[2] : zc0[3];
        const unsigned int w1 = (d == 0) ? zc1[0] : (d == 1) ? zc1[1] : (d == 2) ? zc1[2] : zc1[3];
        const bool bit0 = (w0 >> sh) & 1u;
        const bool bit1 = (w1 >> sh) & 1u;
        Clo |= __ballot(bit0);
        Chi |= __ballot(bit1);
        // parent = first zero-offerer; frozen once candidate; in-tree nodes never update
        if (bit0 && !cand0 && !it0) { par0 = j; cand0 = true; }
        if (bit1 && !cand1 && !it1) { par1 = j; cand1 = true; }
    }
    g_par[b][lane] = par0;
    if (has1) g_par[b][i1] = par1;
    __syncthreads();
    for (int s = lane; s < NROI - 1; s += 64) {
        g_deaths[b][s] = deathsL[s];
        g_usv[b][s]    = usL[s];
        g_vsv[b][s]    = vsL[s];
    }
}

// ---------------- 5) parallel post-processing: mst, pair table, smin/smax, dmax, betti ----------------
__global__ void __launch_bounds__(256) k_post() {
    const int b = blockIdx.x, t = threadIdx.x;
    __shared__ unsigned char mstP[NROI * NROI];
    __shared__ float deathsS[NROI - 1];
    __shared__ float ndArr[NROI - 1];
    __shared__ int   ndCnt;
    __shared__ float redn[4], redx[4], redd[4];
    for (int e = t; e < NROI * NROI / 4; e += 256) ((unsigned int*)mstP)[e] = 0;
    if (t < NROI - 1) deathsS[t] = g_deaths[b][t];
    if (t == 0) ndCnt = 0;
    __syncthreads();
    if (t < NROI - 1) {
        const int j = g_vsv[b][t];
        int u = g_usv[b][t];
        if (u < 0) u = g_par[b][j];               // zero-death => parent = first-zero-offerer
        const int a = u < j ? u : j, c = u < j ? j : u;
        mstP[a * NROI + c] = 1;
        const float dth = deathsS[t];
        if (dth != 0.f) { const int p = atomicAdd(&ndCnt, 1); ndArr[p] = dth; }
    }
    __syncthreads();
    // pair table: deterministic triangular slot; MST pairs -> sentinel (tent clamps to exactly 0)
    float mn = BIGF, mx = -BIGF;
    for (int e = t; e < NROI * NROI; e += 256) {
        const int i = e / NROI, j = e % NROI;
        if (i < j) {
            const int pos = i * NROI - (i * (i + 1)) / 2 + (j - i - 1);
            float bv = BIGF, dv = -BIGF;
            if (!mstP[e]) {
                bv = g_D[b * NROI * NROI + e];
                dv = g_death1[b * NROI * NROI + e];
                mn = fminf(mn, bv); mx = fmaxf(mx, dv);
            }
            g_pair[b][pos] = make_float2(bv, dv);
        }
    }
    float dmx = (t < NROI - 1) ? deathsS[t] : -1.f;
    const int lane = t & 63, wv = t >> 6;
    #pragma unroll
    for (int off = 1; off < 64; off <<= 1) {
        mn  = fminf(mn,  __shfl_xor(mn,  off, 64));
        mx  = fmaxf(mx,  __shfl_xor(mx,  off, 64));
        dmx = fmaxf(dmx, __shfl_xor(dmx, off, 64));
    }
    if (lane == 0) { redn[wv] = mn; redx[wv] = mx; redd[wv] = dmx; }
    __syncthreads();
    if (t == 0) {
        for (int z = 1; z < 4; ++z) {
            redn[0] = fminf(redn[0], redn[z]);
            redx[0] = fmaxf(redx[0], redx[z]);
            redd[0] = fmaxf(redd[0], redd[z]);
        }
        g_smin[b] = redn[0]; g_smax[b] = redx[0];
        if (redd[0] > 0.f) atomicOr(&g_bnz, 1);
    }
    __syncthreads();
    // betti: only NONZERO deaths can satisfy g < death (g >= 0 always) -> exact prefilter
    const float dmax  = redd[0];
    const float stepg = dmax / 999.0f;             // f32 linspace step, start = 0
    const int   nd    = ndCnt;
    for (int tt = t; tt < RESN; tt += 256) {
        const float g = (tt == RESN - 1) ? dmax : (float)tt * stepg;
        int c2 = 0;
        for (int s = 0; s < nd; ++s) c2 += (g < ndArr[s]) ? 1 : 0;
        g_betti[b * RESN + tt] = (float)c2;
    }
}

// ---------------- 6) orthonormal polynomial basis (skipped when betti==0) ----------------
__global__ void __launch_bounds__(1024) k_basis() {
    if (g_bnz == 0) return;   // degenerate H0 branch: fit is exactly zero, basis unused
    const int t = threadIdx.x;
    const int lane = t & 63, wv = t >> 6;  // 16 waves
    __shared__ double xs[RESN];
    __shared__ double w[RESN], dwv[RESN];
    __shared__ double cj[NMODE], ctot[NMODE];
    __shared__ double red[16];
    if (t < RESN) {
        xs[t] = (2.0 * (double)t - 999.0) / 999.0;
        const double q0 = 1.0 / sqrt(1000.0);
        g_q[0][t] = q0;
        g_qd[0][t] = 0.0;
    }
    __syncthreads();
    for (int k = 0; k < MDEG; ++k) {
        if (t < RESN) {
            w[t]   = xs[t] * g_q[k][t];
            dwv[t] = g_q[k][t] + xs[t] * g_qd[k][t];
        }
        if (t < NMODE) ctot[t] = 0.0;
        __syncthreads();
        for (int round = 0; round < 2; ++round) {   // CGS twice == stable
            for (int j = wv; j <= k; j += 16) {
                double p = 0.0;
                for (int tt = lane; tt < RESN; tt += 64) p += w[tt] * g_q[j][tt];
                p = wave_sum_f64(p);
                if (lane == 0) cj[j] = p;
            }
            __syncthreads();
            if (t < RESN) {
                double acc = w[t];
                for (int j = 0; j <= k; ++j) acc -= cj[j] * g_q[j][t];
                w[t] = acc;
            }
            if (t <= k) ctot[t] += cj[t];
            __syncthreads();
        }
        if (t < RESN) {
            double acc = dwv[t];
            for (int j = 0; j <= k; ++j) acc -= ctot[j] * g_qd[j][t];
            dwv[t] = acc;
        }
        double p = 0.0;
        for (int tt = t; tt < RESN; tt += 1024) p += w[tt] * w[tt];
        p = wave_sum_f64(p);
        if (lane == 0) red[wv] = p;
        __syncthreads();
        if (t == 0) {
            double s = 0.0;
            for (int z = 0; z < 16; ++z) s += red[z];
            red[0] = sqrt(s);
        }
        __syncthreads();
        const double beta = red[0];
        if (t < RESN) {
            g_q[k + 1][t]  = w[t] / beta;
            g_qd[k + 1][t] = dwv[t] / beta;
        }
        __syncthreads();
    }
}

// ---------------- 7) merged outputs: blocks 0..999 landscape, 1000..1003 poly fit ----------------
__global__ void __launch_bounds__(256) k_out(float* __restrict__ out) {
    if (blockIdx.x < (NB * RESN) / 4) {
        // ---- landscape: one wave per (b, grid point) ----
        const int wave = (blockIdx.x * 256 + threadIdx.x) >> 6;
        const int lane = threadIdx.x & 63;
        const int b = wave / RESN, tt = wave % RESN;
        const float smn = g_smin[b], smx = g_smax[b];
        const float stepg = (smx - smn) / 999.0f;
        const float g = (tt == RESN - 1) ? smx : smn + (float)tt * stepg;
        const float SQ2 = 1.41421356f;           // f32 sqrt(2), as reference
        float t5[5] = {0.f, 0.f, 0.f, 0.f, 0.f};
        const float2* __restrict__ pr = g_pair[b];
        for (int e = lane; e < PAIR_N; e += 64) {
            const float2 p = pr[e];
            float v = fminf(g - p.x, p.y - g);
            v = v > 0.f ? v : 0.f;
            v *= SQ2;
            if (v > t5[4]) {
                t5[4] = v;
                #pragma unroll
                for (int z = 4; z > 0; --z)
                    if (t5[z] > t5[z - 1]) { const float tmp = t5[z - 1]; t5[z - 1] = t5[z]; t5[z] = tmp; }
            }
        }
        // butterfly merge of sorted-desc top-5 lists
        for (int off = 1; off < 64; off <<= 1) {
            float bv[5];
            #pragma unroll
            for (int z = 0; z < 5; ++z) bv[z] = __shfl_xor(t5[z], off, 64);
            float o[5]; int ia = 0, ib = 0;
            #pragma unroll
            for (int z = 0; z < 5; ++z) {
                const bool ta = (ib >= 5) || (ia < 5 && t5[ia] >= bv[ib]);
                o[z] = ta ? t5[ia++] : bv[ib++];
            }
            #pragma unroll
            for (int z = 0; z < 5; ++z) t5[z] = o[z];
        }
        if (lane == 0) {
            const float land = (t5[0] + t5[1] + t5[2] + t5[3] + t5[4]) / 5.0f;
            for (int rep = 0; rep < BREP; ++rep)
                out[(rep * NB + b) * RESN + tt] = land;
        }
        return;
    }
    // ---- polynomial fit outputs ----
    const int b = blockIdx.x - (NB * RESN) / 4, t = threadIdx.x;
    float* oy = out + BREP * NB * RESN;
    float* od = out + 2 * BREP * NB * RESN;
    if (g_bnz == 0) {
        // betti == 0 everywhere -> coef == 0 -> yvals/fderiv exactly 0
        for (int tt = t; tt < RESN; tt += 256) {
            for (int rep = 0; rep < BREP; ++rep) {
                oy[(rep * NB + b) * RESN + tt] = 0.f;
                if (tt >= SAMP && tt < RESN - SAMP)
                    od[(rep * NB + b) * (RESN - 2 * SAMP) + (tt - SAMP)] = 0.f;
            }
        }
        return;
    }
    const int lane = t & 63, wv = t >> 6;  // 4 waves
    __shared__ double dk[NMODE];
    __shared__ float  bet[RESN];
    for (int tt = t; tt < RESN; tt += 256) bet[tt] = g_betti[b * RESN + tt];
    __syncthreads();
    for (int k = wv; k < NMODE; k += 4) {
        double p = 0.0;
        for (int tt = lane; tt < RESN; tt += 64) p += (double)bet[tt] * g_q[k][tt];
        p = wave_sum_f64(p);
        if (lane == 0) dk[k] = p;
    }
    __syncthreads();
    const double scale = 2.0 / 999.0;
    for (int tt = t; tt < RESN; tt += 256) {
        double y = 0.0, d = 0.0;
        for (int k = 0; k < NMODE; ++k) {
            y += dk[k] * g_q[k][tt];
            d += dk[k] * g_qd[k][tt];
        }
        const float yv = (float)y;
        const float fd = (float)(fabs(d) * scale);
        for (int rep = 0; rep < BREP; ++rep) {
            oy[(rep * NB + b) * RESN + tt] = yv;
            if (tt >= SAMP && tt < RESN - SAMP)
                od[(rep * NB + b) * (RESN - 2 * SAMP) + (tt - SAMP)] = fd;
        }
    }
}

// ---------------- launcher ----------------
extern "C" void kernel_launch(void* const* d_in, const int* in_sizes, int n_in,
                              void* d_out, int out_size, void* d_ws, size_t ws_size,
                              hipStream_t stream) {
    const int*   ei  = (const int*)d_in[1];    // edge_index (2, 160000)
    const float* ea  = (const float*)d_in[2];  // edge_attr  (160000, 1)
    float*       out = (float*)d_out;          // [land 32x1000 | yvals 32x1000 | fderiv 32x900]

    k_zero<<<(NB * NROI * NROI + 255) / 256, 256, 0, stream>>>();
    k_scatter<<<(NEDGE + 255) / 256, 256, 0, stream>>>(ei, ea);
    k_death1<<<(NB * NROI * NROI + 255) / 256, 256, 0, stream>>>();
    k_prim<<<NB, 64, 0, stream>>>();
    k_post<<<NB, 256, 0, stream>>>();
    k_basis<<<1, 1024, 0, stream>>>();
    k_out<<<(NB * RESN) / 4 + NB, 256, 0, stream>>>(out);
}

// Round 7
// 172.273 us; speedup vs baseline: 1.1048x; 1.1048x over previous
//
#include <hip/hip_runtime.h>

// ---------------- problem constants ----------------
#define NROI  100
#define NB    4          // 400/100 diagonal blocks
#define NEDGE 160000
#define RESN  1000
#define SAMP  50
#define BREP  8          // batch tiling (B=8)
#define MDEG  44         // effective polynomial rank cutoff
#define NMODE (MDEG + 1)
#define BIGF  1.0e9f
#define PAIR_N 4950      // NROI*(NROI-1)/2 upper-triangular pairs (fixed, sentinel-masked)

// ---------------- static device workspace ----------------
__device__ float  g_adj[NB * NROI * NROI];
__device__ float  g_D[NB * NROI * NROI];
__device__ float  g_death1[NB * NROI * NROI];
__device__ float  g_deaths[NB][NROI - 1];
__device__ int    g_usv[NB][NROI - 1];
__device__ int    g_vsv[NB][NROI - 1];
__device__ int    g_par[NB][NROI];
__device__ float2 g_pair[NB][PAIR_N];   // (birth, death) per pair; sentinel (+BIG,-BIG) if MST
__device__ float  g_betti[NB * RESN];
__device__ float  g_smin[NB], g_smax[NB];
__device__ int    g_bnz;              // any nonzero betti? (gates basis/fit)
__device__ double g_q[NMODE][RESN];   // orthonormal poly basis values
__device__ double g_qd[NMODE][RESN];  // derivatives d/dx

// ---------------- helpers ----------------
__device__ inline double wave_sum_f64(double p) {
    for (int off = 32; off > 0; off >>= 1) p += __shfl_xor(p, off, 64);
    return p;
}

// ---------------- 1) zero accumulators ----------------
__global__ void k_zero() {
    const int tid = blockIdx.x * blockDim.x + threadIdx.x;
    if (tid < NB * NROI * NROI) g_adj[tid] = 0.f;
    if (tid == 0) g_bnz = 0;
}

// ---------------- 2) scatter-add diagonal-block edges ----------------
__global__ void k_scatter(const int* __restrict__ ei, const float* __restrict__ ea) {
    const int e = blockIdx.x * blockDim.x + threadIdx.x;
    if (e >= NEDGE) return;
    const int r = ei[e], c = ei[NEDGE + e];
    const int br = r / NROI, bc = c / NROI;
    if (br == bc)
        atomicAdd(&g_adj[br * NROI * NROI + (r - br * NROI) * NROI + (c - bc * NROI)], ea[e]);
}

// ---------------- 3) fused: D = max(1-adj,0) + H1 deaths ----------------
// death1[i,j] = max(D_ij, min_k!=i,j max(D_ik,D_jk)); fmin/fmax exact -> assoc-free.
__device__ inline float dclamp(float a) { const float d = 1.f - a; return d > 0.f ? d : 0.f; }
__global__ void k_death1() {
    const int tid = blockIdx.x * blockDim.x + threadIdx.x;
    if (tid >= NB * NROI * NROI) return;
    const int b  = tid / (NROI * NROI);
    const int ij = tid % (NROI * NROI);
    const int i = ij / NROI, j = ij % NROI;
    const float* __restrict__ ai = g_adj + b * NROI * NROI + i * NROI;
    const float* __restrict__ aj = g_adj + b * NROI * NROI + j * NROI;
    float Tm = BIGF;
    float dij = 0.f;
    for (int k = 0; k < NROI; k += 4) {
        const float4 a = *(const float4*)(ai + k);
        const float4 c = *(const float4*)(aj + k);
        const float di0 = dclamp(a.x), di1 = dclamp(a.y), di2 = dclamp(a.z), di3 = dclamp(a.w);
        const float dj0 = dclamp(c.x), dj1 = dclamp(c.y), dj2 = dclamp(c.z), dj3 = dclamp(c.w);
        float m0 = (k + 0 == i || k + 0 == j) ? BIGF : fmaxf(di0, dj0);
        float m1 = (k + 1 == i || k + 1 == j) ? BIGF : fmaxf(di1, dj1);
        float m2 = (k + 2 == i || k + 2 == j) ? BIGF : fmaxf(di2, dj2);
        float m3 = (k + 3 == i || k + 3 == j) ? BIGF : fmaxf(di3, dj3);
        Tm = fminf(Tm, fminf(fminf(m0, m1), fminf(m2, m3)));
        if (j >= k && j < k + 4) dij = (j == k) ? di0 : (j == k + 1) ? di1 : (j == k + 2) ? di2 : di3;
    }
    g_D[tid]      = dij;
    g_death1[tid] = fmaxf(dij, Tm);
}

// ---------------- 4) Prim MST loop ONLY (single wave per block) ----------------
__global__ void __launch_bounds__(64) k_prim() {
    const int b = blockIdx.x, lane = threadIdx.x;
    const float* __restrict__ Db = g_D + b * NROI * NROI;
    __shared__ float deathsL[NROI - 1];
    __shared__ int   usL[NROI - 1], vsL[NROI - 1];
    const int  i1   = 64 + lane;
    const bool has1 = (i1 < NROI);
    // column-major zero bitmasks straight from global (coalesced per row): lane t = column t.
    unsigned int zc0[4] = {0, 0, 0, 0}, zc1[4] = {0, 0, 0, 0};
    #pragma unroll 4
    for (int j = 0; j < NROI; ++j) {
        const unsigned int bit = 1u << (j & 31);
        if (Db[j * NROI + lane] == 0.f) zc0[j >> 5] |= bit;
        if (has1 && Db[j * NROI + i1] == 0.f) zc1[j >> 5] |= bit;
    }
    unsigned long long Clo = __ballot((zc0[0] & 1u) != 0u);   // row 0 = bit 0 of each column
    unsigned long long Chi = __ballot((zc1[0] & 1u) != 0u);
    unsigned long long Tlo = 1ull, Thi = 0ull;
    bool it0 = (lane == 0), it1 = false;
    bool cand0 = (zc0[0] & 1u) != 0u;
    bool cand1 = (zc1[0] & 1u) != 0u;
    int  par0 = 0, par1 = 0;                     // first zero-offerer (frozen once cand)

    #pragma unroll 1
    for (int step = 0; step < NROI - 1; ++step) {
        const unsigned long long alo = Clo & ~Tlo, ahi = Chi & ~Thi;
        int j;
        if (alo | ahi) {
            // jnp.argmin first-index == first not-in-tree node with mind==0 (D >= 0 always)
            j = alo ? (__ffsll(alo) - 1) : (63 + __ffsll(ahi));
            if (lane == 0) { deathsL[step] = 0.f; usL[step] = -1; vsL[step] = j; }
        } else {
            // rare general fallback: replay mind/parent over insertion order, exact butterfly argmin
            __syncthreads();   // make lane-0 vsL writes visible (uniform branch)
            float m0 = Db[lane]; int p0 = 0;
            float m1 = has1 ? Db[i1] : BIGF; int p1 = 0;
            for (int s = 0; s < step; ++s) {
                const int q = vsL[s];
                const float d0 = Db[q * NROI + lane];
                if (d0 < m0) { m0 = d0; p0 = q; }     // strict <, as reference
                if (has1) {
                    const float d1 = Db[q * NROI + i1];
                    if (d1 < m1) { m1 = d1; p1 = q; }
                }
            }
            const float v0 = it0 ? BIGF : m0;
            const float v1 = (has1 && !it1) ? m1 : BIGF;
            float vv; int idx, pw;
            if (v0 <= v1) { vv = v0; idx = lane; pw = p0; } else { vv = v1; idx = i1; pw = p1; }
            #pragma unroll
            for (int off = 1; off < 64; off <<= 1) {
                const float ov = __shfl_xor(vv, off, 64);
                const int   oi = __shfl_xor(idx, off, 64);
                const int   op = __shfl_xor(pw, off, 64);
                if (ov < vv || (ov == vv && oi < idx)) { vv = ov; idx = oi; pw = op; }
            }
            j = idx;
            if (lane == 0) { deathsL[step] = vv; usL[step] = pw; vsL[step] = j; }
        }
        if (j < 64) Tlo |= 1ull << j; else Thi |= 1ull << (j - 64);
        if (lane == j) it0 = true;
        if (i1 == j)   it1 = true;
        // extract bit j of MY columns (same-lane VALU), rebuild row j's mask via ballot
        const int d = j >> 5, sh = j & 31;
        const unsigned int w0 = (d == 0) ? zc0[0] : (d == 1) ? zc0[1] : (d == 2) ? zc0[2] : zc0[3];
        const unsigned int w1 = (d == 0) ? zc1[0] : (d == 1) ? zc1[1] : (d == 2) ? zc1[2] : zc1[3];
        const bool bit0 = (w0 >> sh) & 1u;
        const bool bit1 = (w1 >> sh) & 1u;
        Clo |= __ballot(bit0);
        Chi |= __ballot(bit1);
        // parent = first zero-offerer; frozen once candidate; in-tree nodes never update
        if (bit0 && !cand0 && !it0) { par0 = j; cand0 = true; }
        if (bit1 && !cand1 && !it1) { par1 = j; cand1 = true; }
    }
    g_par[b][lane] = par0;
    if (has1) g_par[b][i1] = par1;
    __syncthreads();
    for (int s = lane; s < NROI - 1; s += 64) {
        g_deaths[b][s] = deathsL[s];
        g_usv[b][s]    = usL[s];
        g_vsv[b][s]    = vsL[s];
    }
}

// ---------------- 5) parallel post-processing: mst, pair table, smin/smax, dmax, betti ----------------
__global__ void __launch_bounds__(256) k_post() {
    const int b = blockIdx.x, t = threadIdx.x;
    __shared__ unsigned char mstP[NROI * NROI];
    __shared__ float deathsS[NROI - 1];
    __shared__ float ndArr[NROI - 1];
    __shared__ int   ndCnt;
    __shared__ float redn[4], redx[4], redd[4];
    for (int e = t; e < NROI * NROI / 4; e += 256) ((unsigned int*)mstP)[e] = 0;
    if (t < NROI - 1) deathsS[t] = g_deaths[b][t];
    if (t == 0) ndCnt = 0;
    __syncthreads();
    if (t < NROI - 1) {
        const int j = g_vsv[b][t];
        int u = g_usv[b][t];
        if (u < 0) u = g_par[b][j];               // zero-death => parent = first-zero-offerer
        const int a = u < j ? u : j, c = u < j ? j : u;
        mstP[a * NROI + c] = 1;
        const float dth = deathsS[t];
        if (dth != 0.f) { const int p = atomicAdd(&ndCnt, 1); ndArr[p] = dth; }
    }
    __syncthreads();
    // pair table: deterministic triangular slot; MST pairs -> sentinel (tent clamps to exactly 0)
    float mn = BIGF, mx = -BIGF;
    for (int e = t; e < NROI * NROI; e += 256) {
        const int i = e / NROI, j = e % NROI;
        if (i < j) {
            const int pos = i * NROI - (i * (i + 1)) / 2 + (j - i - 1);
            float bv = BIGF, dv = -BIGF;
            if (!mstP[e]) {
                bv = g_D[b * NROI * NROI + e];
                dv = g_death1[b * NROI * NROI + e];
                mn = fminf(mn, bv); mx = fmaxf(mx, dv);
            }
            g_pair[b][pos] = make_float2(bv, dv);
        }
    }
    float dmx = (t < NROI - 1) ? deathsS[t] : -1.f;
    const int lane = t & 63, wv = t >> 6;
    #pragma unroll
    for (int off = 1; off < 64; off <<= 1) {
        mn  = fminf(mn,  __shfl_xor(mn,  off, 64));
        mx  = fmaxf(mx,  __shfl_xor(mx,  off, 64));
        dmx = fmaxf(dmx, __shfl_xor(dmx, off, 64));
    }
    if (lane == 0) { redn[wv] = mn; redx[wv] = mx; redd[wv] = dmx; }
    __syncthreads();
    if (t == 0) {
        for (int z = 1; z < 4; ++z) {
            redn[0] = fminf(redn[0], redn[z]);
            redx[0] = fmaxf(redx[0], redx[z]);
            redd[0] = fmaxf(redd[0], redd[z]);
        }
        g_smin[b] = redn[0]; g_smax[b] = redx[0];
        if (redd[0] > 0.f) atomicOr(&g_bnz, 1);
    }
    __syncthreads();
    // betti: only NONZERO deaths can satisfy g < death (g >= 0 always) -> exact prefilter
    const float dmax  = redd[0];
    const float stepg = dmax / 999.0f;             // f32 linspace step, start = 0
    const int   nd    = ndCnt;
    for (int tt = t; tt < RESN; tt += 256) {
        const float g = (tt == RESN - 1) ? dmax : (float)tt * stepg;
        int c2 = 0;
        for (int s = 0; s < nd; ++s) c2 += (g < ndArr[s]) ? 1 : 0;
        g_betti[b * RESN + tt] = (float)c2;
    }
}

// ---------------- 6) orthonormal polynomial basis (skipped when betti==0) ----------------
__global__ void __launch_bounds__(1024) k_basis() {
    if (g_bnz == 0) return;   // degenerate H0 branch: fit is exactly zero, basis unused
    const int t = threadIdx.x;
    const int lane = t & 63, wv = t >> 6;  // 16 waves
    __shared__ double xs[RESN];
    __shared__ double w[RESN], dwv[RESN];
    __shared__ double cj[NMODE], ctot[NMODE];
    __shared__ double red[16];
    if (t < RESN) {
        xs[t] = (2.0 * (double)t - 999.0) / 999.0;
        const double q0 = 1.0 / sqrt(1000.0);
        g_q[0][t] = q0;
        g_qd[0][t] = 0.0;
    }
    __syncthreads();
    for (int k = 0; k < MDEG; ++k) {
        if (t < RESN) {
            w[t]   = xs[t] * g_q[k][t];
            dwv[t] = g_q[k][t] + xs[t] * g_qd[k][t];
        }
        if (t < NMODE) ctot[t] = 0.0;
        __syncthreads();
        for (int round = 0; round < 2; ++round) {   // CGS twice == stable
            for (int j = wv; j <= k; j += 16) {
                double p = 0.0;
                for (int tt = lane; tt < RESN; tt += 64) p += w[tt] * g_q[j][tt];
                p = wave_sum_f64(p);
                if (lane == 0) cj[j] = p;
            }
            __syncthreads();
            if (t < RESN) {
                double acc = w[t];
                for (int j = 0; j <= k; ++j) acc -= cj[j] * g_q[j][t];
                w[t] = acc;
            }
            if (t <= k) ctot[t] += cj[t];
            __syncthreads();
        }
        if (t < RESN) {
            double acc = dwv[t];
            for (int j = 0; j <= k; ++j) acc -= ctot[j] * g_qd[j][t];
            dwv[t] = acc;
        }
        double p = 0.0;
        for (int tt = t; tt < RESN; tt += 1024) p += w[tt] * w[tt];
        p = wave_sum_f64(p);
        if (lane == 0) red[wv] = p;
        __syncthreads();
        if (t == 0) {
            double s = 0.0;
            for (int z = 0; z < 16; ++z) s += red[z];
            red[0] = sqrt(s);
        }
        __syncthreads();
        const double beta = red[0];
        if (t < RESN) {
            g_q[k + 1][t]  = w[t] / beta;
            g_qd[k + 1][t] = dwv[t] / beta;
        }
        __syncthreads();
    }
}

// ---------------- 7) merged outputs: blocks 0..999 landscape, 1000..1003 poly fit ----------------
__global__ void __launch_bounds__(256) k_out(float* __restrict__ out) {
    if (blockIdx.x < (NB * RESN) / 4) {
        // ---- landscape: one wave per (b, grid point); top-5 in NAMED scalars only ----
        const int wave = (blockIdx.x * 256 + threadIdx.x) >> 6;
        const int lane = threadIdx.x & 63;
        const int b = wave / RESN, tt = wave % RESN;
        const float smn = g_smin[b], smx = g_smax[b];
        const float stepg = (smx - smn) / 999.0f;
        const float g = (tt == RESN - 1) ? smx : smn + (float)tt * stepg;
        const float SQ2 = 1.41421356f;           // f32 sqrt(2), as reference
        float t50 = 0.f, t51 = 0.f, t52 = 0.f, t53 = 0.f, t54 = 0.f;  // sorted desc
        const float2* __restrict__ pr = g_pair[b];
        #pragma unroll 4
        for (int e = lane; e < PAIR_N; e += 64) {
            const float2 p = pr[e];
            float v = fminf(g - p.x, p.y - g);
            v = v > 0.f ? v : 0.f;
            v *= SQ2;
            if (v > t54) {                        // guarded compare-swap chain, constant names
                t54 = v;
                if (t54 > t53) { const float s = t53; t53 = t54; t54 = s;
                    if (t53 > t52) { const float s2 = t52; t52 = t53; t53 = s2;
                        if (t52 > t51) { const float s3 = t51; t51 = t52; t52 = s3;
                            if (t51 > t50) { const float s4 = t50; t50 = t51; t51 = s4; } } } }
            }
        }
        // butterfly reduce: exact top-5 merge network, C[k] = max(A[k],B[k],max_{i+j=k-1} min(A[i],B[j]))
        #pragma unroll
        for (int off = 1; off < 64; off <<= 1) {
            const float b0 = __shfl_xor(t50, off, 64);
            const float b1 = __shfl_xor(t51, off, 64);
            const float b2 = __shfl_xor(t52, off, 64);
            const float b3 = __shfl_xor(t53, off, 64);
            const float b4 = __shfl_xor(t54, off, 64);
            const float r0 = fmaxf(t50, b0);
            const float r1 = fmaxf(fmaxf(t51, b1), fminf(t50, b0));
            const float r2 = fmaxf(fmaxf(t52, b2), fmaxf(fminf(t50, b1), fminf(t51, b0)));
            const float r3 = fmaxf(fmaxf(t53, b3),
                                   fmaxf(fminf(t50, b2), fmaxf(fminf(t51, b1), fminf(t52, b0))));
            const float r4 = fmaxf(fmaxf(t54, b4),
                                   fmaxf(fmaxf(fminf(t50, b3), fminf(t53, b0)),
                                         fmaxf(fminf(t51, b2), fminf(t52, b1))));
            t50 = r0; t51 = r1; t52 = r2; t53 = r3; t54 = r4;
        }
        if (lane == 0) {
            const float land = (t50 + t51 + t52 + t53 + t54) / 5.0f;
            for (int rep = 0; rep < BREP; ++rep)
                out[(rep * NB + b) * RESN + tt] = land;
        }
        return;
    }
    // ---- polynomial fit outputs ----
    const int b = blockIdx.x - (NB * RESN) / 4, t = threadIdx.x;
    float* oy = out + BREP * NB * RESN;
    float* od = out + 2 * BREP * NB * RESN;
    if (g_bnz == 0) {
        // betti == 0 everywhere -> coef == 0 -> yvals/fderiv exactly 0
        for (int tt = t; tt < RESN; tt += 256) {
            for (int rep = 0; rep < BREP; ++rep) {
                oy[(rep * NB + b) * RESN + tt] = 0.f;
                if (tt >= SAMP && tt < RESN - SAMP)
                    od[(rep * NB + b) * (RESN - 2 * SAMP) + (tt - SAMP)] = 0.f;
            }
        }
        return;
    }
    const int lane = t & 63, wv = t >> 6;  // 4 waves
    __shared__ double dk[NMODE];
    __shared__ float  bet[RESN];
    for (int tt = t; tt < RESN; tt += 256) bet[tt] = g_betti[b * RESN + tt];
    __syncthreads();
    for (int k = wv; k < NMODE; k += 4) {
        double p = 0.0;
        for (int tt = lane; tt < RESN; tt += 64) p += (double)bet[tt] * g_q[k][tt];
        p = wave_sum_f64(p);
        if (lane == 0) dk[k] = p;
    }
    __syncthreads();
    const double scale = 2.0 / 999.0;
    for (int tt = t; tt < RESN; tt += 256) {
        double y = 0.0, d = 0.0;
        for (int k = 0; k < NMODE; ++k) {
            y += dk[k] * g_q[k][tt];
            d += dk[k] * g_qd[k][tt];
        }
        const float yv = (float)y;
        const float fd = (float)(fabs(d) * scale);
        for (int rep = 0; rep < BREP; ++rep) {
            oy[(rep * NB + b) * RESN + tt] = yv;
            if (tt >= SAMP && tt < RESN - SAMP)
                od[(rep * NB + b) * (RESN - 2 * SAMP) + (tt - SAMP)] = fd;
        }
    }
}

// ---------------- launcher ----------------
extern "C" void kernel_launch(void* const* d_in, const int* in_sizes, int n_in,
                              void* d_out, int out_size, void* d_ws, size_t ws_size,
                              hipStream_t stream) {
    const int*   ei  = (const int*)d_in[1];    // edge_index (2, 160000)
    const float* ea  = (const float*)d_in[2];  // edge_attr  (160000, 1)
    float*       out = (float*)d_out;          // [land 32x1000 | yvals 32x1000 | fderiv 32x900]

    k_zero<<<(NB * NROI * NROI + 255) / 256, 256, 0, stream>>>();
    k_scatter<<<(NEDGE + 255) / 256, 256, 0, stream>>>(ei, ea);
    k_death1<<<(NB * NROI * NROI + 255) / 256, 256, 0, stream>>>();
    k_prim<<<NB, 64, 0, stream>>>();
    k_post<<<NB, 256, 0, stream>>>();
    k_basis<<<1, 1024, 0, stream>>>();
    k_out<<<(NB * RESN) / 4 + NB, 256, 0, stream>>>(out);
}

// Round 8
// 134.140 us; speedup vs baseline: 1.4189x; 1.2843x over previous
//
#include <hip/hip_runtime.h>

// ---------------- problem constants ----------------
#define NROI  100
#define NB    4          // 400/100 diagonal blocks
#define NEDGE 160000
#define RESN  1000
#define SAMP  50
#define BREP  8          // batch tiling (B=8)
#define MDEG  44         // effective polynomial rank cutoff
#define NMODE (MDEG + 1)
#define BIGF  1.0e9f
#define PAIR_N 4950      // NROI*(NROI-1)/2 upper-triangular pairs (fixed, sentinel-masked)
#define LPB   8          // landscape grid points per block (2 per wave)

// ---------------- static device workspace ----------------
__device__ float  g_adj[NB * NROI * NROI];
__device__ float  g_D[NB * NROI * NROI];
__device__ float  g_death1[NB * NROI * NROI];
__device__ float  g_deaths[NB][NROI - 1];
__device__ int    g_usv[NB][NROI - 1];
__device__ int    g_vsv[NB][NROI - 1];
__device__ int    g_par[NB][NROI];
__device__ float2 g_pair[NB][PAIR_N];   // (birth, death) per pair; sentinel (+BIG,-BIG) if MST
__device__ float  g_betti[NB * RESN];
__device__ float  g_smin[NB], g_smax[NB];
__device__ int    g_bnz;              // any nonzero betti? (gates basis/fit)
__device__ double g_q[NMODE][RESN];   // orthonormal poly basis values
__device__ double g_qd[NMODE][RESN];  // derivatives d/dx

// ---------------- helpers ----------------
__device__ inline double wave_sum_f64(double p) {
    for (int off = 32; off > 0; off >>= 1) p += __shfl_xor(p, off, 64);
    return p;
}

// ---------------- 1) zero accumulators ----------------
__global__ void k_zero() {
    const int tid = blockIdx.x * blockDim.x + threadIdx.x;
    if (tid < NB * NROI * NROI) g_adj[tid] = 0.f;
    if (tid == 0) g_bnz = 0;
}

// ---------------- 2) scatter-add diagonal-block edges ----------------
__global__ void k_scatter(const int* __restrict__ ei, const float* __restrict__ ea) {
    const int e = blockIdx.x * blockDim.x + threadIdx.x;
    if (e >= NEDGE) return;
    const int r = ei[e], c = ei[NEDGE + e];
    const int br = r / NROI, bc = c / NROI;
    if (br == bc)
        atomicAdd(&g_adj[br * NROI * NROI + (r - br * NROI) * NROI + (c - bc * NROI)], ea[e]);
}

// ---------------- 3) fused: D = max(1-adj,0) + H1 deaths ----------------
// death1[i,j] = max(D_ij, min_k!=i,j max(D_ik,D_jk)); fmin/fmax exact -> assoc-free.
__device__ inline float dclamp(float a) { const float d = 1.f - a; return d > 0.f ? d : 0.f; }
__global__ void k_death1() {
    const int tid = blockIdx.x * blockDim.x + threadIdx.x;
    if (tid >= NB * NROI * NROI) return;
    const int b  = tid / (NROI * NROI);
    const int ij = tid % (NROI * NROI);
    const int i = ij / NROI, j = ij % NROI;
    const float* __restrict__ ai = g_adj + b * NROI * NROI + i * NROI;
    const float* __restrict__ aj = g_adj + b * NROI * NROI + j * NROI;
    float Tm = BIGF;
    float dij = 0.f;
    for (int k = 0; k < NROI; k += 4) {
        const float4 a = *(const float4*)(ai + k);
        const float4 c = *(const float4*)(aj + k);
        const float di0 = dclamp(a.x), di1 = dclamp(a.y), di2 = dclamp(a.z), di3 = dclamp(a.w);
        const float dj0 = dclamp(c.x), dj1 = dclamp(c.y), dj2 = dclamp(c.z), dj3 = dclamp(c.w);
        float m0 = (k + 0 == i || k + 0 == j) ? BIGF : fmaxf(di0, dj0);
        float m1 = (k + 1 == i || k + 1 == j) ? BIGF : fmaxf(di1, dj1);
        float m2 = (k + 2 == i || k + 2 == j) ? BIGF : fmaxf(di2, dj2);
        float m3 = (k + 3 == i || k + 3 == j) ? BIGF : fmaxf(di3, dj3);
        Tm = fminf(Tm, fminf(fminf(m0, m1), fminf(m2, m3)));
        if (j >= k && j < k + 4) dij = (j == k) ? di0 : (j == k + 1) ? di1 : (j == k + 2) ? di2 : di3;
    }
    g_D[tid]      = dij;
    g_death1[tid] = fmaxf(dij, Tm);
}

// ---------------- 4) Prim MST loop ONLY (single wave per block) ----------------
__global__ void __launch_bounds__(64) k_prim() {
    const int b = blockIdx.x, lane = threadIdx.x;
    const float* __restrict__ Db = g_D + b * NROI * NROI;
    __shared__ float deathsL[NROI - 1];
    __shared__ int   usL[NROI - 1], vsL[NROI - 1];
    const int  i1   = 64 + lane;
    const bool has1 = (i1 < NROI);
    // column-major zero bitmasks straight from global (coalesced per row): lane t = column t.
    unsigned int zc0[4] = {0, 0, 0, 0}, zc1[4] = {0, 0, 0, 0};
    #pragma unroll 4
    for (int j = 0; j < NROI; ++j) {
        const unsigned int bit = 1u << (j & 31);
        if (Db[j * NROI + lane] == 0.f) zc0[j >> 5] |= bit;
        if (has1 && Db[j * NROI + i1] == 0.f) zc1[j >> 5] |= bit;
    }
    unsigned long long Clo = __ballot((zc0[0] & 1u) != 0u);   // row 0 = bit 0 of each column
    unsigned long long Chi = __ballot((zc1[0] & 1u) != 0u);
    unsigned long long Tlo = 1ull, Thi = 0ull;
    bool it0 = (lane == 0), it1 = false;
    bool cand0 = (zc0[0] & 1u) != 0u;
    bool cand1 = (zc1[0] & 1u) != 0u;
    int  par0 = 0, par1 = 0;                     // first zero-offerer (frozen once cand)

    #pragma unroll 1
    for (int step = 0; step < NROI - 1; ++step) {
        const unsigned long long alo = Clo & ~Tlo, ahi = Chi & ~Thi;
        int j;
        if (alo | ahi) {
            // jnp.argmin first-index == first not-in-tree node with mind==0 (D >= 0 always)
            j = alo ? (__ffsll(alo) - 1) : (63 + __ffsll(ahi));
            if (lane == 0) { deathsL[step] = 0.f; usL[step] = -1; vsL[step] = j; }
        } else {
            // rare general fallback: replay mind/parent over insertion order, exact butterfly argmin
            __syncthreads();   // make lane-0 vsL writes visible (uniform branch)
            float m0 = Db[lane]; int p0 = 0;
            float m1 = has1 ? Db[i1] : BIGF; int p1 = 0;
            for (int s = 0; s < step; ++s) {
                const int q = vsL[s];
                const float d0 = Db[q * NROI + lane];
                if (d0 < m0) { m0 = d0; p0 = q; }     // strict <, as reference
                if (has1) {
                    const float d1 = Db[q * NROI + i1];
                    if (d1 < m1) { m1 = d1; p1 = q; }
                }
            }
            const float v0 = it0 ? BIGF : m0;
            const float v1 = (has1 && !it1) ? m1 : BIGF;
            float vv; int idx, pw;
            if (v0 <= v1) { vv = v0; idx = lane; pw = p0; } else { vv = v1; idx = i1; pw = p1; }
            #pragma unroll
            for (int off = 1; off < 64; off <<= 1) {
                const float ov = __shfl_xor(vv, off, 64);
                const int   oi = __shfl_xor(idx, off, 64);
                const int   op = __shfl_xor(pw, off, 64);
                if (ov < vv || (ov == vv && oi < idx)) { vv = ov; idx = oi; pw = op; }
            }
            j = idx;
            if (lane == 0) { deathsL[step] = vv; usL[step] = pw; vsL[step] = j; }
        }
        if (j < 64) Tlo |= 1ull << j; else Thi |= 1ull << (j - 64);
        if (lane == j) it0 = true;
        if (i1 == j)   it1 = true;
        // extract bit j of MY columns (same-lane VALU), rebuild row j's mask via ballot
        const int d = j >> 5, sh = j & 31;
        const unsigned int w0 = (d == 0) ? zc0[0] : (d == 1) ? zc0[1] : (d == 2) ? zc0[2] : zc0[3];
        const unsigned int w1 = (d == 0) ? zc1[0] : (d == 1) ? zc1[1] : (d == 2) ? zc1[2] : zc1[3];
        const bool bit0 = (w0 >> sh) & 1u;
        const bool bit1 = (w1 >> sh) & 1u;
        Clo |= __ballot(bit0);
        Chi |= __ballot(bit1);
        // parent = first zero-offerer; frozen once candidate; in-tree nodes never update
        if (bit0 && !cand0 && !it0) { par0 = j; cand0 = true; }
        if (bit1 && !cand1 && !it1) { par1 = j; cand1 = true; }
    }
    g_par[b][lane] = par0;
    if (has1) g_par[b][i1] = par1;
    __syncthreads();
    for (int s = lane; s < NROI - 1; s += 64) {
        g_deaths[b][s] = deathsL[s];
        g_usv[b][s]    = usL[s];
        g_vsv[b][s]    = vsL[s];
    }
}

// ---------------- 5) parallel post-processing: mst, pair table, smin/smax, dmax, betti ----------------
__global__ void __launch_bounds__(256) k_post() {
    const int b = blockIdx.x, t = threadIdx.x;
    __shared__ unsigned char mstP[NROI * NROI];
    __shared__ float deathsS[NROI - 1];
    __shared__ float ndArr[NROI - 1];
    __shared__ int   ndCnt;
    __shared__ float redn[4], redx[4], redd[4];
    for (int e = t; e < NROI * NROI / 4; e += 256) ((unsigned int*)mstP)[e] = 0;
    if (t < NROI - 1) deathsS[t] = g_deaths[b][t];
    if (t == 0) ndCnt = 0;
    __syncthreads();
    if (t < NROI - 1) {
        const int j = g_vsv[b][t];
        int u = g_usv[b][t];
        if (u < 0) u = g_par[b][j];               // zero-death => parent = first-zero-offerer
        const int a = u < j ? u : j, c = u < j ? j : u;
        mstP[a * NROI + c] = 1;
        const float dth = deathsS[t];
        if (dth != 0.f) { const int p = atomicAdd(&ndCnt, 1); ndArr[p] = dth; }
    }
    __syncthreads();
    // pair table: deterministic triangular slot; MST pairs -> sentinel (tent clamps to exactly 0)
    float mn = BIGF, mx = -BIGF;
    for (int e = t; e < NROI * NROI; e += 256) {
        const int i = e / NROI, j = e % NROI;
        if (i < j) {
            const int pos = i * NROI - (i * (i + 1)) / 2 + (j - i - 1);
            float bv = BIGF, dv = -BIGF;
            if (!mstP[e]) {
                bv = g_D[b * NROI * NROI + e];
                dv = g_death1[b * NROI * NROI + e];
                mn = fminf(mn, bv); mx = fmaxf(mx, dv);
            }
            g_pair[b][pos] = make_float2(bv, dv);
        }
    }
    float dmx = (t < NROI - 1) ? deathsS[t] : -1.f;
    const int lane = t & 63, wv = t >> 6;
    #pragma unroll
    for (int off = 1; off < 64; off <<= 1) {
        mn  = fminf(mn,  __shfl_xor(mn,  off, 64));
        mx  = fmaxf(mx,  __shfl_xor(mx,  off, 64));
        dmx = fmaxf(dmx, __shfl_xor(dmx, off, 64));
    }
    if (lane == 0) { redn[wv] = mn; redx[wv] = mx; redd[wv] = dmx; }
    __syncthreads();
    if (t == 0) {
        for (int z = 1; z < 4; ++z) {
            redn[0] = fminf(redn[0], redn[z]);
            redx[0] = fmaxf(redx[0], redx[z]);
            redd[0] = fmaxf(redd[0], redd[z]);
        }
        g_smin[b] = redn[0]; g_smax[b] = redx[0];
        if (redd[0] > 0.f) atomicOr(&g_bnz, 1);
    }
    __syncthreads();
    // betti: only NONZERO deaths can satisfy g < death (g >= 0 always) -> exact prefilter
    const float dmax  = redd[0];
    const float stepg = dmax / 999.0f;             // f32 linspace step, start = 0
    const int   nd    = ndCnt;
    for (int tt = t; tt < RESN; tt += 256) {
        const float g = (tt == RESN - 1) ? dmax : (float)tt * stepg;
        int c2 = 0;
        for (int s = 0; s < nd; ++s) c2 += (g < ndArr[s]) ? 1 : 0;
        g_betti[b * RESN + tt] = (float)c2;
    }
}

// ---------------- 6) orthonormal polynomial basis (skipped when betti==0) ----------------
__global__ void __launch_bounds__(1024) k_basis() {
    if (g_bnz == 0) return;   // degenerate H0 branch: fit is exactly zero, basis unused
    const int t = threadIdx.x;
    const int lane = t & 63, wv = t >> 6;  // 16 waves
    __shared__ double xs[RESN];
    __shared__ double w[RESN], dwv[RESN];
    __shared__ double cj[NMODE], ctot[NMODE];
    __shared__ double red[16];
    if (t < RESN) {
        xs[t] = (2.0 * (double)t - 999.0) / 999.0;
        const double q0 = 1.0 / sqrt(1000.0);
        g_q[0][t] = q0;
        g_qd[0][t] = 0.0;
    }
    __syncthreads();
    for (int k = 0; k < MDEG; ++k) {
        if (t < RESN) {
            w[t]   = xs[t] * g_q[k][t];
            dwv[t] = g_q[k][t] + xs[t] * g_qd[k][t];
        }
        if (t < NMODE) ctot[t] = 0.0;
        __syncthreads();
        for (int round = 0; round < 2; ++round) {   // CGS twice == stable
            for (int j = wv; j <= k; j += 16) {
                double p = 0.0;
                for (int tt = lane; tt < RESN; tt += 64) p += w[tt] * g_q[j][tt];
                p = wave_sum_f64(p);
                if (lane == 0) cj[j] = p;
            }
            __syncthreads();
            if (t < RESN) {
                double acc = w[t];
                for (int j = 0; j <= k; ++j) acc -= cj[j] * g_q[j][t];
                w[t] = acc;
            }
            if (t <= k) ctot[t] += cj[t];
            __syncthreads();
        }
        if (t < RESN) {
            double acc = dwv[t];
            for (int j = 0; j <= k; ++j) acc -= ctot[j] * g_qd[j][t];
            dwv[t] = acc;
        }
        double p = 0.0;
        for (int tt = t; tt < RESN; tt += 1024) p += w[tt] * w[tt];
        p = wave_sum_f64(p);
        if (lane == 0) red[wv] = p;
        __syncthreads();
        if (t == 0) {
            double s = 0.0;
            for (int z = 0; z < 16; ++z) s += red[z];
            red[0] = sqrt(s);
        }
        __syncthreads();
        const double beta = red[0];
        if (t < RESN) {
            g_q[k + 1][t]  = w[t] / beta;
            g_qd[k + 1][t] = dwv[t] / beta;
        }
        __syncthreads();
    }
}

// ---------------- 7) merged outputs: blocks 0..499 landscape (LDS-staged pairs), 500..503 fit ----------------
__global__ void __launch_bounds__(256) k_out(float* __restrict__ out) {
    const int nLand = NB * RESN / LPB;   // 500 blocks, each: one b, LPB grid points
    if (blockIdx.x < nLand) {
        const int t = threadIdx.x;
        const int blocksPerB = RESN / LPB;             // 125
        const int b      = blockIdx.x / blocksPerB;
        const int ptBase = (blockIdx.x % blocksPerB) * LPB;
        __shared__ float2 prL[PAIR_N];
        for (int i = t; i < PAIR_N / 2; i += 256)      // 2475 float4, coalesced
            ((float4*)prL)[i] = ((const float4*)g_pair[b])[i];
        __syncthreads();
        const int wv = t >> 6, lane = t & 63;
        const float smn = g_smin[b], smx = g_smax[b];
        const float stepg = (smx - smn) / 999.0f;
        const int tt0 = ptBase + 2 * wv, tt1 = tt0 + 1;
        const float g0 = (tt0 == RESN - 1) ? smx : smn + (float)tt0 * stepg;
        const float g1 = (tt1 == RESN - 1) ? smx : smn + (float)tt1 * stepg;
        const float SQ2 = 1.41421356f;                 // f32 sqrt(2), as reference
        // two top-5 sets in NAMED scalars (no runtime indexing -> registers)
        float a0 = 0.f, a1 = 0.f, a2 = 0.f, a3 = 0.f, a4 = 0.f;
        float c0 = 0.f, c1 = 0.f, c2 = 0.f, c3 = 0.f, c4 = 0.f;
        #pragma unroll 2
        for (int e = lane; e < PAIR_N; e += 64) {
            const float2 p = prL[e];
            float v = fminf(g0 - p.x, p.y - g0);
            v = v > 0.f ? v : 0.f;
            v *= SQ2;
            if (v > a4) {
                a4 = v;
                if (a4 > a3) { const float s = a3; a3 = a4; a4 = s;
                    if (a3 > a2) { const float s2 = a2; a2 = a3; a3 = s2;
                        if (a2 > a1) { const float s3 = a1; a1 = a2; a2 = s3;
                            if (a1 > a0) { const float s4 = a0; a0 = a1; a1 = s4; } } } }
            }
            float w = fminf(g1 - p.x, p.y - g1);
            w = w > 0.f ? w : 0.f;
            w *= SQ2;
            if (w > c4) {
                c4 = w;
                if (c4 > c3) { const float s = c3; c3 = c4; c4 = s;
                    if (c3 > c2) { const float s2 = c2; c2 = c3; c3 = s2;
                        if (c2 > c1) { const float s3 = c1; c1 = c2; c2 = s3;
                            if (c1 > c0) { const float s4 = c0; c0 = c1; c1 = s4; } } } }
            }
        }
        // butterfly reduce: exact top-5 merge network, C[k] = max(A[k],B[k],max_{i+j=k-1} min(A[i],B[j]))
        #pragma unroll
        for (int off = 1; off < 64; off <<= 1) {
            {
                const float b0 = __shfl_xor(a0, off, 64);
                const float b1 = __shfl_xor(a1, off, 64);
                const float b2 = __shfl_xor(a2, off, 64);
                const float b3 = __shfl_xor(a3, off, 64);
                const float b4 = __shfl_xor(a4, off, 64);
                const float r0 = fmaxf(a0, b0);
                const float r1 = fmaxf(fmaxf(a1, b1), fminf(a0, b0));
                const float r2 = fmaxf(fmaxf(a2, b2), fmaxf(fminf(a0, b1), fminf(a1, b0)));
                const float r3 = fmaxf(fmaxf(a3, b3),
                                       fmaxf(fminf(a0, b2), fmaxf(fminf(a1, b1), fminf(a2, b0))));
                const float r4 = fmaxf(fmaxf(a4, b4),
                                       fmaxf(fmaxf(fminf(a0, b3), fminf(a3, b0)),
                                             fmaxf(fminf(a1, b2), fminf(a2, b1))));
                a0 = r0; a1 = r1; a2 = r2; a3 = r3; a4 = r4;
            }
            {
                const float b0 = __shfl_xor(c0, off, 64);
                const float b1 = __shfl_xor(c1, off, 64);
                const float b2 = __shfl_xor(c2, off, 64);
                const float b3 = __shfl_xor(c3, off, 64);
                const float b4 = __shfl_xor(c4, off, 64);
                const float r0 = fmaxf(c0, b0);
                const float r1 = fmaxf(fmaxf(c1, b1), fminf(c0, b0));
                const float r2 = fmaxf(fmaxf(c2, b2), fmaxf(fminf(c0, b1), fminf(c1, b0)));
                const float r3 = fmaxf(fmaxf(c3, b3),
                                       fmaxf(fminf(c0, b2), fmaxf(fminf(c1, b1), fminf(c2, b0))));
                const float r4 = fmaxf(fmaxf(c4, b4),
                                       fmaxf(fmaxf(fminf(c0, b3), fminf(c3, b0)),
                                             fmaxf(fminf(c1, b2), fminf(c2, b1))));
                c0 = r0; c1 = r1; c2 = r2; c3 = r3; c4 = r4;
            }
        }
        if (lane == 0) {
            const float land0 = (a0 + a1 + a2 + a3 + a4) / 5.0f;
            const float land1 = (c0 + c1 + c2 + c3 + c4) / 5.0f;
            for (int rep = 0; rep < BREP; ++rep) {
                out[(rep * NB + b) * RESN + tt0] = land0;
                out[(rep * NB + b) * RESN + tt1] = land1;
            }
        }
        return;
    }
    // ---- polynomial fit outputs ----
    const int b = blockIdx.x - nLand, t = threadIdx.x;
    float* oy = out + BREP * NB * RESN;
    float* od = out + 2 * BREP * NB * RESN;
    if (g_bnz == 0) {
        // betti == 0 everywhere -> coef == 0 -> yvals/fderiv exactly 0
        for (int tt = t; tt < RESN; tt += 256) {
            for (int rep = 0; rep < BREP; ++rep) {
                oy[(rep * NB + b) * RESN + tt] = 0.f;
                if (tt >= SAMP && tt < RESN - SAMP)
                    od[(rep * NB + b) * (RESN - 2 * SAMP) + (tt - SAMP)] = 0.f;
            }
        }
        return;
    }
    const int lane = t & 63, wv = t >> 6;  // 4 waves
    __shared__ double dk[NMODE];
    __shared__ float  bet[RESN];
    for (int tt = t; tt < RESN; tt += 256) bet[tt] = g_betti[b * RESN + tt];
    __syncthreads();
    for (int k = wv; k < NMODE; k += 4) {
        double p = 0.0;
        for (int tt = lane; tt < RESN; tt += 64) p += (double)bet[tt] * g_q[k][tt];
        p = wave_sum_f64(p);
        if (lane == 0) dk[k] = p;
    }
    __syncthreads();
    const double scale = 2.0 / 999.0;
    for (int tt = t; tt < RESN; tt += 256) {
        double y = 0.0, d = 0.0;
        for (int k = 0; k < NMODE; ++k) {
            y += dk[k] * g_q[k][tt];
            d += dk[k] * g_qd[k][tt];
        }
        const float yv = (float)y;
        const float fd = (float)(fabs(d) * scale);
        for (int rep = 0; rep < BREP; ++rep) {
            oy[(rep * NB + b) * RESN + tt] = yv;
            if (tt >= SAMP && tt < RESN - SAMP)
                od[(rep * NB + b) * (RESN - 2 * SAMP) + (tt - SAMP)] = fd;
        }
    }
}

// ---------------- launcher ----------------
extern "C" void kernel_launch(void* const* d_in, const int* in_sizes, int n_in,
                              void* d_out, int out_size, void* d_ws, size_t ws_size,
                              hipStream_t stream) {
    const int*   ei  = (const int*)d_in[1];    // edge_index (2, 160000)
    const float* ea  = (const float*)d_in[2];  // edge_attr  (160000, 1)
    float*       out = (float*)d_out;          // [land 32x1000 | yvals 32x1000 | fderiv 32x900]

    k_zero<<<(NB * NROI * NROI + 255) / 256, 256, 0, stream>>>();
    k_scatter<<<(NEDGE + 255) / 256, 256, 0, stream>>>(ei, ea);
    k_death1<<<(NB * NROI * NROI + 255) / 256, 256, 0, stream>>>();
    k_prim<<<NB, 64, 0, stream>>>();
    k_post<<<NB, 256, 0, stream>>>();
    k_basis<<<1, 1024, 0, stream>>>();
    k_out<<<NB * RESN / LPB + NB, 256, 0, stream>>>(out);
}

// Round 9
// 110.360 us; speedup vs baseline: 1.7247x; 1.2155x over previous
//
#include <hip/hip_runtime.h>

// ---------------- problem constants ----------------
#define NROI  100
#define NB    4          // 400/100 diagonal blocks
#define NEDGE 160000
#define RESN  1000
#define SAMP  50
#define BREP  8          // batch tiling (B=8)
#define MDEG  44         // effective polynomial rank cutoff
#define NMODE (MDEG + 1)
#define BIGF  1.0e9f
#define PAIR_N 4950      // NROI*(NROI-1)/2 upper-triangular pairs (fixed, sentinel-masked)
#define LPB   8          // landscape grid points per block (2 per wave)

// ---------------- static device workspace ----------------
__device__ float  g_adj[NB * NROI * NROI];
__device__ float  g_D[NB * NROI * NROI];
__device__ float  g_death1[NB * NROI * NROI];
__device__ float  g_deaths[NB][NROI - 1];
__device__ int    g_usv[NB][NROI - 1];
__device__ int    g_vsv[NB][NROI - 1];
__device__ int    g_par[NB][NROI];
__device__ float2 g_pair[NB][PAIR_N];   // (birth, death) per pair; sentinel (+BIG,-BIG) if MST
__device__ float  g_betti[NB * RESN];
__device__ float  g_smin[NB], g_smax[NB];
__device__ int    g_bnz;              // any nonzero betti? (gates basis/fit)
__device__ double g_q[NMODE][RESN];   // orthonormal poly basis values
__device__ double g_qd[NMODE][RESN];  // derivatives d/dx

// ---------------- helpers ----------------
__device__ inline double wave_sum_f64(double p) {
    for (int off = 32; off > 0; off >>= 1) p += __shfl_xor(p, off, 64);
    return p;
}

// ---------------- 1) zero accumulators ----------------
__global__ void k_zero() {
    const int tid = blockIdx.x * blockDim.x + threadIdx.x;
    if (tid < NB * NROI * NROI) g_adj[tid] = 0.f;
    if (tid == 0) g_bnz = 0;
}

// ---------------- 2) scatter-add diagonal-block edges ----------------
__global__ void k_scatter(const int* __restrict__ ei, const float* __restrict__ ea) {
    const int e = blockIdx.x * blockDim.x + threadIdx.x;
    if (e >= NEDGE) return;
    const int r = ei[e], c = ei[NEDGE + e];
    const int br = r / NROI, bc = c / NROI;
    if (br == bc)
        atomicAdd(&g_adj[br * NROI * NROI + (r - br * NROI) * NROI + (c - bc * NROI)], ea[e]);
}

// ---------------- 3) fused: D = max(1-adj,0) + H1 deaths ----------------
// death1[i,j] = max(D_ij, min_k!=i,j max(D_ik,D_jk)); fmin/fmax exact -> assoc-free.
__device__ inline float dclamp(float a) { const float d = 1.f - a; return d > 0.f ? d : 0.f; }
__global__ void k_death1() {
    const int tid = blockIdx.x * blockDim.x + threadIdx.x;
    if (tid >= NB * NROI * NROI) return;
    const int b  = tid / (NROI * NROI);
    const int ij = tid % (NROI * NROI);
    const int i = ij / NROI, j = ij % NROI;
    const float* __restrict__ ai = g_adj + b * NROI * NROI + i * NROI;
    const float* __restrict__ aj = g_adj + b * NROI * NROI + j * NROI;
    float Tm = BIGF;
    float dij = 0.f;
    for (int k = 0; k < NROI; k += 4) {
        const float4 a = *(const float4*)(ai + k);
        const float4 c = *(const float4*)(aj + k);
        const float di0 = dclamp(a.x), di1 = dclamp(a.y), di2 = dclamp(a.z), di3 = dclamp(a.w);
        const float dj0 = dclamp(c.x), dj1 = dclamp(c.y), dj2 = dclamp(c.z), dj3 = dclamp(c.w);
        float m0 = (k + 0 == i || k + 0 == j) ? BIGF : fmaxf(di0, dj0);
        float m1 = (k + 1 == i || k + 1 == j) ? BIGF : fmaxf(di1, dj1);
        float m2 = (k + 2 == i || k + 2 == j) ? BIGF : fmaxf(di2, dj2);
        float m3 = (k + 3 == i || k + 3 == j) ? BIGF : fmaxf(di3, dj3);
        Tm = fminf(Tm, fminf(fminf(m0, m1), fminf(m2, m3)));
        if (j >= k && j < k + 4) dij = (j == k) ? di0 : (j == k + 1) ? di1 : (j == k + 2) ? di2 : di3;
    }
    g_D[tid]      = dij;
    g_death1[tid] = fmaxf(dij, Tm);
}

// ---------------- 4) Prim MST loop: LDS-staged D, early-exit + parallel epilogue ----------------
__global__ void __launch_bounds__(64) k_prim() {
    const int b = blockIdx.x, lane = threadIdx.x;
    const float* __restrict__ Db = g_D + b * NROI * NROI;
    __shared__ float Dl[NROI * NROI];     // 40 KB
    __shared__ float deathsL[NROI - 1];
    __shared__ int   usL[NROI - 1], vsL[NROI - 1];
    // stage D into LDS: 2500 independent float4 copies (one latency exposure)
    for (int i = lane; i < NROI * NROI / 4; i += 64)
        ((float4*)Dl)[i] = ((const float4*)Db)[i];
    for (int s = lane; s < NROI - 1; s += 64) { deathsL[s] = 0.f; usL[s] = -1; }
    __syncthreads();

    const int  i1   = 64 + lane;
    const bool has1 = (i1 < NROI);
    // column-major zero bitmasks from LDS (consecutive lanes -> conflict-free)
    unsigned int zc0[4] = {0, 0, 0, 0}, zc1[4] = {0, 0, 0, 0};
    #pragma unroll 4
    for (int j = 0; j < NROI; ++j) {
        const unsigned int bit = 1u << (j & 31);
        if (Dl[j * NROI + lane] == 0.f) zc0[j >> 5] |= bit;
        if (has1 && Dl[j * NROI + i1] == 0.f) zc1[j >> 5] |= bit;
    }
    unsigned long long Clo = __ballot((zc0[0] & 1u) != 0u);   // row 0 = bit 0 of each column
    unsigned long long Chi = __ballot((zc1[0] & 1u) != 0u);
    unsigned long long Tlo = 1ull, Thi = 0ull;
    const unsigned long long MHI = (1ull << (NROI - 64)) - 1; // 36 valid hi bits
    bool it0 = (lane == 0), it1 = false;
    bool cand0 = (zc0[0] & 1u) != 0u;
    bool cand1 = (zc1[0] & 1u) != 0u;
    int  par0 = 0, par1 = 0;                     // first zero-offerer (frozen once cand)

    int step = 0;
    #pragma unroll 1
    for (; step < NROI - 1; ++step) {
        const unsigned long long alo = Clo & ~Tlo;
        const unsigned long long ahi = Chi & ~Thi & MHI;
        const unsigned long long rlo = ~Tlo;             // remaining (not-in-tree) nodes
        const unsigned long long rhi = ~Thi & MHI;
        // EARLY EXIT: every remaining node is a zero-candidate -> rest of the process is
        // "insert remaining in ascending index, death 0, parent = frozen first-zero-offerer".
        if (alo == rlo && ahi == rhi) break;
        int j;
        if (alo | ahi) {
            // jnp.argmin first-index == first not-in-tree node with mind==0 (D >= 0 always)
            j = alo ? (__ffsll(alo) - 1) : (63 + __ffsll(ahi));
            if (lane == 0) vsL[step] = j;       // deathsL/usL keep defaults 0 / -1
        } else {
            // rare general fallback: replay mind/parent over insertion order, exact butterfly argmin
            __syncthreads();
            float m0 = Dl[lane]; int p0 = 0;
            float m1 = has1 ? Dl[i1] : BIGF; int p1 = 0;
            for (int s = 0; s < step; ++s) {
                const int q = vsL[s];
                const float d0 = Dl[q * NROI + lane];
                if (d0 < m0) { m0 = d0; p0 = q; }     // strict <, as reference
                if (has1) {
                    const float d1 = Dl[q * NROI + i1];
                    if (d1 < m1) { m1 = d1; p1 = q; }
                }
            }
            const float v0 = it0 ? BIGF : m0;
            const float v1 = (has1 && !it1) ? m1 : BIGF;
            float vv; int idx, pw;
            if (v0 <= v1) { vv = v0; idx = lane; pw = p0; } else { vv = v1; idx = i1; pw = p1; }
            #pragma unroll
            for (int off = 1; off < 64; off <<= 1) {
                const float ov = __shfl_xor(vv, off, 64);
                const int   oi = __shfl_xor(idx, off, 64);
                const int   op = __shfl_xor(pw, off, 64);
                if (ov < vv || (ov == vv && oi < idx)) { vv = ov; idx = oi; pw = op; }
            }
            j = idx;
            if (lane == 0) { deathsL[step] = vv; usL[step] = pw; vsL[step] = j; }
        }
        if (j < 64) Tlo |= 1ull << j; else Thi |= 1ull << (j - 64);
        if (lane == j) it0 = true;
        if (i1 == j)   it1 = true;
        // extract bit j of MY columns (same-lane VALU), rebuild row j's mask via ballot
        const int d = j >> 5, sh = j & 31;
        const unsigned int w0 = (d == 0) ? zc0[0] : (d == 1) ? zc0[1] : (d == 2) ? zc0[2] : zc0[3];
        const unsigned int w1 = (d == 0) ? zc1[0] : (d == 1) ? zc1[1] : (d == 2) ? zc1[2] : zc1[3];
        const bool bit0 = (w0 >> sh) & 1u;
        const bool bit1 = (w1 >> sh) & 1u;
        Clo |= __ballot(bit0);
        Chi |= __ballot(bit1);
        // parent = first zero-offerer; frozen once candidate; in-tree nodes never update
        if (bit0 && !cand0 && !it0) { par0 = j; cand0 = true; }
        if (bit1 && !cand1 && !it1) { par1 = j; cand1 = true; }
    }
    // parallel epilogue: remaining nodes inserted in ascending index at steps step..98
    if (step < NROI - 1) {
        const unsigned long long rlo = ~Tlo;
        const unsigned long long rhi = ~Thi & MHI;
        const int nlo = __popcll(rlo);
        if ((rlo >> lane) & 1ull) {
            const int rank = __popcll(rlo & ((1ull << lane) - 1ull));
            vsL[step + rank] = lane;            // deathsL/usL defaults 0 / -1 apply
        }
        if (has1 && ((rhi >> lane) & 1ull)) {
            const int rank = nlo + __popcll(rhi & ((1ull << lane) - 1ull));
            vsL[step + rank] = i1;
        }
    }
    g_par[b][lane] = par0;
    if (has1) g_par[b][i1] = par1;
    __syncthreads();
    for (int s = lane; s < NROI - 1; s += 64) {
        g_deaths[b][s] = deathsL[s];
        g_usv[b][s]    = usL[s];
        g_vsv[b][s]    = vsL[s];
    }
}

// ---------------- 5) parallel post-processing: mst, pair table, smin/smax, dmax, betti ----------------
__global__ void __launch_bounds__(256) k_post() {
    const int b = blockIdx.x, t = threadIdx.x;
    __shared__ unsigned char mstP[NROI * NROI];
    __shared__ float deathsS[NROI - 1];
    __shared__ float ndArr[NROI - 1];
    __shared__ int   ndCnt;
    __shared__ float redn[4], redx[4], redd[4];
    for (int e = t; e < NROI * NROI / 4; e += 256) ((unsigned int*)mstP)[e] = 0;
    if (t < NROI - 1) deathsS[t] = g_deaths[b][t];
    if (t == 0) ndCnt = 0;
    __syncthreads();
    if (t < NROI - 1) {
        const int j = g_vsv[b][t];
        int u = g_usv[b][t];
        if (u < 0) u = g_par[b][j];               // zero-death => parent = first-zero-offerer
        const int a = u < j ? u : j, c = u < j ? j : u;
        mstP[a * NROI + c] = 1;
        const float dth = deathsS[t];
        if (dth != 0.f) { const int p = atomicAdd(&ndCnt, 1); ndArr[p] = dth; }
    }
    __syncthreads();
    // pair table: deterministic triangular slot; MST pairs -> sentinel (tent clamps to exactly 0)
    float mn = BIGF, mx = -BIGF;
    for (int e = t; e < NROI * NROI; e += 256) {
        const int i = e / NROI, j = e % NROI;
        if (i < j) {
            const int pos = i * NROI - (i * (i + 1)) / 2 + (j - i - 1);
            float bv = BIGF, dv = -BIGF;
            if (!mstP[e]) {
                bv = g_D[b * NROI * NROI + e];
                dv = g_death1[b * NROI * NROI + e];
                mn = fminf(mn, bv); mx = fmaxf(mx, dv);
            }
            g_pair[b][pos] = make_float2(bv, dv);
        }
    }
    float dmx = (t < NROI - 1) ? deathsS[t] : -1.f;
    const int lane = t & 63, wv = t >> 6;
    #pragma unroll
    for (int off = 1; off < 64; off <<= 1) {
        mn  = fminf(mn,  __shfl_xor(mn,  off, 64));
        mx  = fmaxf(mx,  __shfl_xor(mx,  off, 64));
        dmx = fmaxf(dmx, __shfl_xor(dmx, off, 64));
    }
    if (lane == 0) { redn[wv] = mn; redx[wv] = mx; redd[wv] = dmx; }
    __syncthreads();
    if (t == 0) {
        for (int z = 1; z < 4; ++z) {
            redn[0] = fminf(redn[0], redn[z]);
            redx[0] = fmaxf(redx[0], redx[z]);
            redd[0] = fmaxf(redd[0], redd[z]);
        }
        g_smin[b] = redn[0]; g_smax[b] = redx[0];
        if (redd[0] > 0.f) atomicOr(&g_bnz, 1);
    }
    __syncthreads();
    // betti: only NONZERO deaths can satisfy g < death (g >= 0 always) -> exact prefilter
    const float dmax  = redd[0];
    const float stepg = dmax / 999.0f;             // f32 linspace step, start = 0
    const int   nd    = ndCnt;
    for (int tt = t; tt < RESN; tt += 256) {
        const float g = (tt == RESN - 1) ? dmax : (float)tt * stepg;
        int c2 = 0;
        for (int s = 0; s < nd; ++s) c2 += (g < ndArr[s]) ? 1 : 0;
        g_betti[b * RESN + tt] = (float)c2;
    }
}

// ---------------- 6) orthonormal polynomial basis (skipped when betti==0) ----------------
__global__ void __launch_bounds__(1024) k_basis() {
    if (g_bnz == 0) return;   // degenerate H0 branch: fit is exactly zero, basis unused
    const int t = threadIdx.x;
    const int lane = t & 63, wv = t >> 6;  // 16 waves
    __shared__ double xs[RESN];
    __shared__ double w[RESN], dwv[RESN];
    __shared__ double cj[NMODE], ctot[NMODE];
    __shared__ double red[16];
    if (t < RESN) {
        xs[t] = (2.0 * (double)t - 999.0) / 999.0;
        const double q0 = 1.0 / sqrt(1000.0);
        g_q[0][t] = q0;
        g_qd[0][t] = 0.0;
    }
    __syncthreads();
    for (int k = 0; k < MDEG; ++k) {
        if (t < RESN) {
            w[t]   = xs[t] * g_q[k][t];
            dwv[t] = g_q[k][t] + xs[t] * g_qd[k][t];
        }
        if (t < NMODE) ctot[t] = 0.0;
        __syncthreads();
        for (int round = 0; round < 2; ++round) {   // CGS twice == stable
            for (int j = wv; j <= k; j += 16) {
                double p = 0.0;
                for (int tt = lane; tt < RESN; tt += 64) p += w[tt] * g_q[j][tt];
                p = wave_sum_f64(p);
                if (lane == 0) cj[j] = p;
            }
            __syncthreads();
            if (t < RESN) {
                double acc = w[t];
                for (int j = 0; j <= k; ++j) acc -= cj[j] * g_q[j][t];
                w[t] = acc;
            }
            if (t <= k) ctot[t] += cj[t];
            __syncthreads();
        }
        if (t < RESN) {
            double acc = dwv[t];
            for (int j = 0; j <= k; ++j) acc -= ctot[j] * g_qd[j][t];
            dwv[t] = acc;
        }
        double p = 0.0;
        for (int tt = t; tt < RESN; tt += 1024) p += w[tt] * w[tt];
        p = wave_sum_f64(p);
        if (lane == 0) red[wv] = p;
        __syncthreads();
        if (t == 0) {
            double s = 0.0;
            for (int z = 0; z < 16; ++z) s += red[z];
            red[0] = sqrt(s);
        }
        __syncthreads();
        const double beta = red[0];
        if (t < RESN) {
            g_q[k + 1][t]  = w[t] / beta;
            g_qd[k + 1][t] = dwv[t] / beta;
        }
        __syncthreads();
    }
}

// ---------------- 7) merged outputs: blocks 0..499 landscape (LDS-staged pairs), 500..503 fit ----------------
__global__ void __launch_bounds__(256) k_out(float* __restrict__ out) {
    const int nLand = NB * RESN / LPB;   // 500 blocks, each: one b, LPB grid points
    if (blockIdx.x < nLand) {
        const int t = threadIdx.x;
        const int blocksPerB = RESN / LPB;             // 125
        const int b      = blockIdx.x / blocksPerB;
        const int ptBase = (blockIdx.x % blocksPerB) * LPB;
        __shared__ float2 prL[PAIR_N];
        for (int i = t; i < PAIR_N / 2; i += 256)      // 2475 float4, coalesced
            ((float4*)prL)[i] = ((const float4*)g_pair[b])[i];
        __syncthreads();
        const int wv = t >> 6, lane = t & 63;
        const float smn = g_smin[b], smx = g_smax[b];
        const float stepg = (smx - smn) / 999.0f;
        const int tt0 = ptBase + 2 * wv, tt1 = tt0 + 1;
        const float g0 = (tt0 == RESN - 1) ? smx : smn + (float)tt0 * stepg;
        const float g1 = (tt1 == RESN - 1) ? smx : smn + (float)tt1 * stepg;
        const float SQ2 = 1.41421356f;                 // f32 sqrt(2), as reference
        // two top-5 sets in NAMED scalars (no runtime indexing -> registers)
        float a0 = 0.f, a1 = 0.f, a2 = 0.f, a3 = 0.f, a4 = 0.f;
        float c0 = 0.f, c1 = 0.f, c2 = 0.f, c3 = 0.f, c4 = 0.f;
        #pragma unroll 2
        for (int e = lane; e < PAIR_N; e += 64) {
            const float2 p = prL[e];
            float v = fminf(g0 - p.x, p.y - g0);
            v = v > 0.f ? v : 0.f;
            v *= SQ2;
            if (v > a4) {
                a4 = v;
                if (a4 > a3) { const float s = a3; a3 = a4; a4 = s;
                    if (a3 > a2) { const float s2 = a2; a2 = a3; a3 = s2;
                        if (a2 > a1) { const float s3 = a1; a1 = a2; a2 = s3;
                            if (a1 > a0) { const float s4 = a0; a0 = a1; a1 = s4; } } } }
            }
            float w = fminf(g1 - p.x, p.y - g1);
            w = w > 0.f ? w : 0.f;
            w *= SQ2;
            if (w > c4) {
                c4 = w;
                if (c4 > c3) { const float s = c3; c3 = c4; c4 = s;
                    if (c3 > c2) { const float s2 = c2; c2 = c3; c3 = s2;
                        if (c2 > c1) { const float s3 = c1; c1 = c2; c2 = s3;
                            if (c1 > c0) { const float s4 = c0; c0 = c1; c1 = s4; } } } }
            }
        }
        // butterfly reduce: exact top-5 merge network, C[k] = max(A[k],B[k],max_{i+j=k-1} min(A[i],B[j]))
        #pragma unroll
        for (int off = 1; off < 64; off <<= 1) {
            {
                const float b0 = __shfl_xor(a0, off, 64);
                const float b1 = __shfl_xor(a1, off, 64);
                const float b2 = __shfl_xor(a2, off, 64);
                const float b3 = __shfl_xor(a3, off, 64);
                const float b4 = __shfl_xor(a4, off, 64);
                const float r0 = fmaxf(a0, b0);
                const float r1 = fmaxf(fmaxf(a1, b1), fminf(a0, b0));
                const float r2 = fmaxf(fmaxf(a2, b2), fmaxf(fminf(a0, b1), fminf(a1, b0)));
                const float r3 = fmaxf(fmaxf(a3, b3),
                                       fmaxf(fminf(a0, b2), fmaxf(fminf(a1, b1), fminf(a2, b0))));
                const float r4 = fmaxf(fmaxf(a4, b4),
                                       fmaxf(fmaxf(fminf(a0, b3), fminf(a3, b0)),
                                             fmaxf(fminf(a1, b2), fminf(a2, b1))));
                a0 = r0; a1 = r1; a2 = r2; a3 = r3; a4 = r4;
            }
            {
                const float b0 = __shfl_xor(c0, off, 64);
                const float b1 = __shfl_xor(c1, off, 64);
                const float b2 = __shfl_xor(c2, off, 64);
                const float b3 = __shfl_xor(c3, off, 64);
                const float b4 = __shfl_xor(c4, off, 64);
                const float r0 = fmaxf(c0, b0);
                const float r1 = fmaxf(fmaxf(c1, b1), fminf(c0, b0));
                const float r2 = fmaxf(fmaxf(c2, b2), fmaxf(fminf(c0, b1), fminf(c1, b0)));
                const float r3 = fmaxf(fmaxf(c3, b3),
                                       fmaxf(fminf(c0, b2), fmaxf(fminf(c1, b1), fminf(c2, b0))));
                const float r4 = fmaxf(fmaxf(c4, b4),
                                       fmaxf(fmaxf(fminf(c0, b3), fminf(c3, b0)),
                                             fmaxf(fminf(c1, b2), fminf(c2, b1))));
                c0 = r0; c1 = r1; c2 = r2; c3 = r3; c4 = r4;
            }
        }
        if (lane == 0) {
            const float land0 = (a0 + a1 + a2 + a3 + a4) / 5.0f;
            const float land1 = (c0 + c1 + c2 + c3 + c4) / 5.0f;
            for (int rep = 0; rep < BREP; ++rep) {
                out[(rep * NB + b) * RESN + tt0] = land0;
                out[(rep * NB + b) * RESN + tt1] = land1;
            }
        }
        return;
    }
    // ---- polynomial fit outputs ----
    const int b = blockIdx.x - nLand, t = threadIdx.x;
    float* oy = out + BREP * NB * RESN;
    float* od = out + 2 * BREP * NB * RESN;
    if (g_bnz == 0) {
        // betti == 0 everywhere -> coef == 0 -> yvals/fderiv exactly 0
        for (int tt = t; tt < RESN; tt += 256) {
            for (int rep = 0; rep < BREP; ++rep) {
                oy[(rep * NB + b) * RESN + tt] = 0.f;
                if (tt >= SAMP && tt < RESN - SAMP)
                    od[(rep * NB + b) * (RESN - 2 * SAMP) + (tt - SAMP)] = 0.f;
            }
        }
        return;
    }
    const int lane = t & 63, wv = t >> 6;  // 4 waves
    __shared__ double dk[NMODE];
    __shared__ float  bet[RESN];
    for (int tt = t; tt < RESN; tt += 256) bet[tt] = g_betti[b * RESN + tt];
    __syncthreads();
    for (int k = wv; k < NMODE; k += 4) {
        double p = 0.0;
        for (int tt = lane; tt < RESN; tt += 64) p += (double)bet[tt] * g_q[k][tt];
        p = wave_sum_f64(p);
        if (lane == 0) dk[k] = p;
    }
    __syncthreads();
    const double scale = 2.0 / 999.0;
    for (int tt = t; tt < RESN; tt += 256) {
        double y = 0.0, d = 0.0;
        for (int k = 0; k < NMODE; ++k) {
            y += dk[k] * g_q[k][tt];
            d += dk[k] * g_qd[k][tt];
        }
        const float yv = (float)y;
        const float fd = (float)(fabs(d) * scale);
        for (int rep = 0; rep < BREP; ++rep) {
            oy[(rep * NB + b) * RESN + tt] = yv;
            if (tt >= SAMP && tt < RESN - SAMP)
                od[(rep * NB + b) * (RESN - 2 * SAMP) + (tt - SAMP)] = fd;
        }
    }
}

// ---------------- launcher ----------------
extern "C" void kernel_launch(void* const* d_in, const int* in_sizes, int n_in,
                              void* d_out, int out_size, void* d_ws, size_t ws_size,
                              hipStream_t stream) {
    const int*   ei  = (const int*)d_in[1];    // edge_index (2, 160000)
    const float* ea  = (const float*)d_in[2];  // edge_attr  (160000, 1)
    float*       out = (float*)d_out;          // [land 32x1000 | yvals 32x1000 | fderiv 32x900]

    k_zero<<<(NB * NROI * NROI + 255) / 256, 256, 0, stream>>>();
    k_scatter<<<(NEDGE + 255) / 256, 256, 0, stream>>>(ei, ea);
    k_death1<<<(NB * NROI * NROI + 255) / 256, 256, 0, stream>>>();
    k_prim<<<NB, 64, 0, stream>>>();
    k_post<<<NB, 256, 0, stream>>>();
    k_basis<<<1, 1024, 0, stream>>>();
    k_out<<<NB * RESN / LPB + NB, 256, 0, stream>>>(out);
}

// Round 10
// 98.757 us; speedup vs baseline: 1.9273x; 1.1175x over previous
//
#include <hip/hip_runtime.h>

// ---------------- problem constants ----------------
#define NROI  100
#define NB    4          // 400/100 diagonal blocks
#define NEDGE 160000
#define RESN  1000
#define SAMP  50
#define BREP  8          // batch tiling (B=8)
#define MDEG  44         // effective polynomial rank cutoff
#define NMODE (MDEG + 1)
#define BIGF  1.0e9f
#define PAIR_N 4950      // NROI*(NROI-1)/2 upper-triangular pairs (fixed, sentinel-masked)
#define LPB   8          // landscape grid points per block (2 per wave)

// ---------------- static device workspace ----------------
__device__ float  g_adj[NB * NROI * NROI];
__device__ float  g_D[NB * NROI * NROI];
__device__ float  g_death1[NB * NROI * NROI];
__device__ float2 g_pair[NB][PAIR_N];   // (birth, death) per pair; sentinel (+BIG,-BIG) if MST
__device__ float  g_betti[NB * RESN];
__device__ float  g_smin[NB], g_smax[NB];
__device__ int    g_bnz;                // any nonzero betti? (gates basis/fit path)
__device__ double g_qb[NB][NMODE][RESN];   // per-b orthonormal poly basis (dead path on this data)
__device__ double g_qdb[NB][NMODE][RESN];  // derivatives

// ---------------- helpers ----------------
__device__ inline double wave_sum_f64(double p) {
    for (int off = 32; off > 0; off >>= 1) p += __shfl_xor(p, off, 64);
    return p;
}

// ---------------- 1) zero accumulators ----------------
__global__ void k_zero() {
    const int tid = blockIdx.x * blockDim.x + threadIdx.x;
    if (tid < NB * NROI * NROI) g_adj[tid] = 0.f;
    if (tid == 0) g_bnz = 0;
}

// ---------------- 2) scatter-add diagonal-block edges ----------------
__global__ void k_scatter(const int* __restrict__ ei, const float* __restrict__ ea) {
    const int e = blockIdx.x * blockDim.x + threadIdx.x;
    if (e >= NEDGE) return;
    const int r = ei[e], c = ei[NEDGE + e];
    const int br = r / NROI, bc = c / NROI;
    if (br == bc)
        atomicAdd(&g_adj[br * NROI * NROI + (r - br * NROI) * NROI + (c - bc * NROI)], ea[e]);
}

// ---------------- 3) fused: D = max(1-adj,0) + H1 deaths ----------------
// death1[i,j] = max(D_ij, min_k!=i,j max(D_ik,D_jk)); fmin/fmax exact -> assoc-free.
__device__ inline float dclamp(float a) { const float d = 1.f - a; return d > 0.f ? d : 0.f; }
__global__ void k_death1() {
    const int tid = blockIdx.x * blockDim.x + threadIdx.x;
    if (tid >= NB * NROI * NROI) return;
    const int b  = tid / (NROI * NROI);
    const int ij = tid % (NROI * NROI);
    const int i = ij / NROI, j = ij % NROI;
    const float* __restrict__ ai = g_adj + b * NROI * NROI + i * NROI;
    const float* __restrict__ aj = g_adj + b * NROI * NROI + j * NROI;
    float Tm = BIGF;
    float dij = 0.f;
    for (int k = 0; k < NROI; k += 4) {
        const float4 a = *(const float4*)(ai + k);
        const float4 c = *(const float4*)(aj + k);
        const float di0 = dclamp(a.x), di1 = dclamp(a.y), di2 = dclamp(a.z), di3 = dclamp(a.w);
        const float dj0 = dclamp(c.x), dj1 = dclamp(c.y), dj2 = dclamp(c.z), dj3 = dclamp(c.w);
        float m0 = (k + 0 == i || k + 0 == j) ? BIGF : fmaxf(di0, dj0);
        float m1 = (k + 1 == i || k + 1 == j) ? BIGF : fmaxf(di1, dj1);
        float m2 = (k + 2 == i || k + 2 == j) ? BIGF : fmaxf(di2, dj2);
        float m3 = (k + 3 == i || k + 3 == j) ? BIGF : fmaxf(di3, dj3);
        Tm = fminf(Tm, fminf(fminf(m0, m1), fminf(m2, m3)));
        if (j >= k && j < k + 4) dij = (j == k) ? di0 : (j == k + 1) ? di1 : (j == k + 2) ? di2 : di3;
    }
    g_D[tid]      = dij;
    g_death1[tid] = fmaxf(dij, Tm);
}

// ---------------- 4) merged Prim + post-processing (4 blocks x 256) ----------------
__global__ void __launch_bounds__(256) k_prim() {
    const int b = blockIdx.x, t = threadIdx.x;
    const int lane = t & 63, wvi = t >> 6;
    const float* __restrict__ Db = g_D + b * NROI * NROI;
    __shared__ float Dl[NROI * NROI];          // 40 KB
    __shared__ float deathsL[NROI - 1];
    __shared__ int   usL[NROI - 1], vsL[NROI - 1];
    __shared__ int   parL[NROI];
    __shared__ unsigned char mstP[NROI * NROI];
    __shared__ float ndArr[NROI - 1];
    __shared__ int   ndCnt;
    __shared__ float redn[4], redx[4], redd[4];
    // stage D into LDS + init (all 256 threads)
    for (int i = t; i < NROI * NROI / 4; i += 256)
        ((float4*)Dl)[i] = ((const float4*)Db)[i];
    for (int e = t; e < NROI * NROI / 4; e += 256) ((unsigned int*)mstP)[e] = 0;
    for (int s = t; s < NROI - 1; s += 256) { deathsL[s] = 0.f; usL[s] = -1; }
    if (t == 0) ndCnt = 0;
    __syncthreads();

    // ---- wave 0 only: bitmask Prim loop (no barriers inside -> other waves park at next sync) ----
    if (t < 64) {
        const int  i1   = 64 + lane;
        const bool has1 = (i1 < NROI);
        // column-major zero bitmasks from LDS (consecutive lanes -> conflict-free)
        unsigned int zc0[4] = {0, 0, 0, 0}, zc1[4] = {0, 0, 0, 0};
        #pragma unroll 4
        for (int j = 0; j < NROI; ++j) {
            const unsigned int bit = 1u << (j & 31);
            if (Dl[j * NROI + lane] == 0.f) zc0[j >> 5] |= bit;
            if (has1 && Dl[j * NROI + i1] == 0.f) zc1[j >> 5] |= bit;
        }
        unsigned long long Clo = __ballot((zc0[0] & 1u) != 0u);   // row 0 = bit 0 of each column
        unsigned long long Chi = __ballot((zc1[0] & 1u) != 0u);
        unsigned long long Tlo = 1ull, Thi = 0ull;
        const unsigned long long MHI = (1ull << (NROI - 64)) - 1; // 36 valid hi bits
        bool it0 = (lane == 0), it1 = false;
        bool cand0 = (zc0[0] & 1u) != 0u;
        bool cand1 = (zc1[0] & 1u) != 0u;
        int  par0 = 0, par1 = 0;                 // first zero-offerer (frozen once cand)

        int step = 0;
        #pragma unroll 1
        for (; step < NROI - 1; ++step) {
            const unsigned long long alo = Clo & ~Tlo;
            const unsigned long long ahi = Chi & ~Thi & MHI;
            const unsigned long long rlo = ~Tlo;             // remaining nodes
            const unsigned long long rhi = ~Thi & MHI;
            // EARLY EXIT: all remaining are zero-candidates -> rest inserts ascending, death 0
            if (alo == rlo && ahi == rhi) break;
            int j;
            if (alo | ahi) {
                // jnp.argmin first-index == first not-in-tree node with mind==0 (D >= 0 always)
                j = alo ? (__ffsll(alo) - 1) : (63 + __ffsll(ahi));
                if (lane == 0) vsL[step] = j;    // deathsL/usL keep defaults 0 / -1
            } else {
                // rare general fallback: replay mind/parent over insertion order (single-wave LDS
                // ordering guarantees lane-0's earlier vsL writes are visible; no barrier needed)
                float m0 = Dl[lane]; int p0 = 0;
                float m1 = has1 ? Dl[i1] : BIGF; int p1 = 0;
                for (int s = 0; s < step; ++s) {
                    const int q = vsL[s];
                    const float d0 = Dl[q * NROI + lane];
                    if (d0 < m0) { m0 = d0; p0 = q; }     // strict <, as reference
                    if (has1) {
                        const float d1 = Dl[q * NROI + i1];
                        if (d1 < m1) { m1 = d1; p1 = q; }
                    }
                }
                const float v0 = it0 ? BIGF : m0;
                const float v1 = (has1 && !it1) ? m1 : BIGF;
                float vv; int idx, pw;
                if (v0 <= v1) { vv = v0; idx = lane; pw = p0; } else { vv = v1; idx = i1; pw = p1; }
                #pragma unroll
                for (int off = 1; off < 64; off <<= 1) {
                    const float ov = __shfl_xor(vv, off, 64);
                    const int   oi = __shfl_xor(idx, off, 64);
                    const int   op = __shfl_xor(pw, off, 64);
                    if (ov < vv || (ov == vv && oi < idx)) { vv = ov; idx = oi; pw = op; }
                }
                j = idx;
                if (lane == 0) { deathsL[step] = vv; usL[step] = pw; vsL[step] = j; }
            }
            if (j < 64) Tlo |= 1ull << j; else Thi |= 1ull << (j - 64);
            if (lane == j) it0 = true;
            if (i1 == j)   it1 = true;
            // extract bit j of MY columns (same-lane VALU), rebuild row j's mask via ballot
            const int d = j >> 5, sh = j & 31;
            const unsigned int w0 = (d == 0) ? zc0[0] : (d == 1) ? zc0[1] : (d == 2) ? zc0[2] : zc0[3];
            const unsigned int w1 = (d == 0) ? zc1[0] : (d == 1) ? zc1[1] : (d == 2) ? zc1[2] : zc1[3];
            const bool bit0 = (w0 >> sh) & 1u;
            const bool bit1 = (w1 >> sh) & 1u;
            Clo |= __ballot(bit0);
            Chi |= __ballot(bit1);
            // parent = first zero-offerer; frozen once candidate; in-tree nodes never update
            if (bit0 && !cand0 && !it0) { par0 = j; cand0 = true; }
            if (bit1 && !cand1 && !it1) { par1 = j; cand1 = true; }
        }
        // parallel epilogue: remaining nodes inserted ascending at steps step..98
        if (step < NROI - 1) {
            const unsigned long long rlo = ~Tlo;
            const unsigned long long rhi = ~Thi & MHI;
            const int nlo = __popcll(rlo);
            if ((rlo >> lane) & 1ull) {
                const int rank = __popcll(rlo & ((1ull << lane) - 1ull));
                vsL[step + rank] = lane;
            }
            if (has1 && ((rhi >> lane) & 1ull)) {
                const int rank = nlo + __popcll(rhi & ((1ull << lane) - 1ull));
                vsL[step + rank] = i1;
            }
        }
        parL[lane] = par0;
        if (has1) parL[i1] = par1;
    }
    __syncthreads();

    // ---- all 256 threads: mst bitmap + nonzero-death list ----
    if (t < NROI - 1) {
        const int j = vsL[t];
        int u = usL[t];
        if (u < 0) u = parL[j];                   // zero-death => parent = first-zero-offerer
        const int a = u < j ? u : j, c = u < j ? j : u;
        mstP[a * NROI + c] = 1;
        const float dth = deathsL[t];
        if (dth != 0.f) { const int p = atomicAdd(&ndCnt, 1); ndArr[p] = dth; }
    }
    __syncthreads();
    // pair table: deterministic triangular slot; MST pairs -> sentinel (tent clamps to exactly 0)
    float mn = BIGF, mx = -BIGF;
    for (int e = t; e < NROI * NROI; e += 256) {
        const int i = e / NROI, j = e % NROI;
        if (i < j) {
            const int pos = i * NROI - (i * (i + 1)) / 2 + (j - i - 1);
            float bv = BIGF, dv = -BIGF;
            if (!mstP[e]) {
                bv = Dl[e];
                dv = g_death1[b * NROI * NROI + e];
                mn = fminf(mn, bv); mx = fmaxf(mx, dv);
            }
            g_pair[b][pos] = make_float2(bv, dv);
        }
    }
    float dmx = (t < NROI - 1) ? deathsL[t] : -1.f;
    #pragma unroll
    for (int off = 1; off < 64; off <<= 1) {
        mn  = fminf(mn,  __shfl_xor(mn,  off, 64));
        mx  = fmaxf(mx,  __shfl_xor(mx,  off, 64));
        dmx = fmaxf(dmx, __shfl_xor(dmx, off, 64));
    }
    if (lane == 0) { redn[wvi] = mn; redx[wvi] = mx; redd[wvi] = dmx; }
    __syncthreads();
    if (t == 0) {
        for (int z = 1; z < 4; ++z) {
            redn[0] = fminf(redn[0], redn[z]);
            redx[0] = fmaxf(redx[0], redx[z]);
            redd[0] = fmaxf(redd[0], redd[z]);
        }
        g_smin[b] = redn[0]; g_smax[b] = redx[0];
        if (redd[0] > 0.f) atomicOr(&g_bnz, 1);
    }
    __syncthreads();
    // betti: only NONZERO deaths can satisfy g < death (g >= 0 always) -> exact prefilter
    const float dmax  = redd[0];
    const float stepg = dmax / 999.0f;             // f32 linspace step, start = 0
    const int   nd    = ndCnt;
    for (int tt = t; tt < RESN; tt += 256) {
        const float g = (tt == RESN - 1) ? dmax : (float)tt * stepg;
        int c2 = 0;
        for (int s = 0; s < nd; ++s) c2 += (g < ndArr[s]) ? 1 : 0;
        g_betti[b * RESN + tt] = (float)c2;
    }
}

// ---------------- 5) merged outputs: 500 landscape blocks + 4 fit blocks (basis inlined) --------
__global__ void __launch_bounds__(256) k_out(float* __restrict__ out) {
    const int nLand = NB * RESN / LPB;   // 500 blocks, each: one b, LPB grid points
    const int t = threadIdx.x;
    const int wv = t >> 6, lane = t & 63;
    if (blockIdx.x < nLand) {
        const int blocksPerB = RESN / LPB;             // 125
        const int b      = blockIdx.x / blocksPerB;
        const int ptBase = (blockIdx.x % blocksPerB) * LPB;
        __shared__ float2 prL[PAIR_N];
        for (int i = t; i < PAIR_N / 2; i += 256)      // 2475 float4, coalesced
            ((float4*)prL)[i] = ((const float4*)g_pair[b])[i];
        __syncthreads();
        const float smn = g_smin[b], smx = g_smax[b];
        const float stepg = (smx - smn) / 999.0f;
        const int tt0 = ptBase + 2 * wv, tt1 = tt0 + 1;
        const float g0 = (tt0 == RESN - 1) ? smx : smn + (float)tt0 * stepg;
        const float g1 = (tt1 == RESN - 1) ? smx : smn + (float)tt1 * stepg;
        const float SQ2 = 1.41421356f;                 // f32 sqrt(2), as reference
        // two top-5 sets in NAMED scalars (no runtime indexing -> registers)
        float a0 = 0.f, a1 = 0.f, a2 = 0.f, a3 = 0.f, a4 = 0.f;
        float c0 = 0.f, c1 = 0.f, c2 = 0.f, c3 = 0.f, c4 = 0.f;
        #pragma unroll 2
        for (int e = lane; e < PAIR_N; e += 64) {
            const float2 p = prL[e];
            float v = fminf(g0 - p.x, p.y - g0);
            v = v > 0.f ? v : 0.f;
            v *= SQ2;
            if (v > a4) {
                a4 = v;
                if (a4 > a3) { const float s = a3; a3 = a4; a4 = s;
                    if (a3 > a2) { const float s2 = a2; a2 = a3; a3 = s2;
                        if (a2 > a1) { const float s3 = a1; a1 = a2; a2 = s3;
                            if (a1 > a0) { const float s4 = a0; a0 = a1; a1 = s4; } } } }
            }
            float w = fminf(g1 - p.x, p.y - g1);
            w = w > 0.f ? w : 0.f;
            w *= SQ2;
            if (w > c4) {
                c4 = w;
                if (c4 > c3) { const float s = c3; c3 = c4; c4 = s;
                    if (c3 > c2) { const float s2 = c2; c2 = c3; c3 = s2;
                        if (c2 > c1) { const float s3 = c1; c1 = c2; c2 = s3;
                            if (c1 > c0) { const float s4 = c0; c0 = c1; c1 = s4; } } } }
            }
        }
        // butterfly reduce: exact top-5 merge network, C[k] = max(A[k],B[k],max_{i+j=k-1} min(A[i],B[j]))
        #pragma unroll
        for (int off = 1; off < 64; off <<= 1) {
            {
                const float b0 = __shfl_xor(a0, off, 64);
                const float b1 = __shfl_xor(a1, off, 64);
                const float b2 = __shfl_xor(a2, off, 64);
                const float b3 = __shfl_xor(a3, off, 64);
                const float b4 = __shfl_xor(a4, off, 64);
                const float r0 = fmaxf(a0, b0);
                const float r1 = fmaxf(fmaxf(a1, b1), fminf(a0, b0));
                const float r2 = fmaxf(fmaxf(a2, b2), fmaxf(fminf(a0, b1), fminf(a1, b0)));
                const float r3 = fmaxf(fmaxf(a3, b3),
                                       fmaxf(fminf(a0, b2), fmaxf(fminf(a1, b1), fminf(a2, b0))));
                const float r4 = fmaxf(fmaxf(a4, b4),
                                       fmaxf(fmaxf(fminf(a0, b3), fminf(a3, b0)),
                                             fmaxf(fminf(a1, b2), fminf(a2, b1))));
                a0 = r0; a1 = r1; a2 = r2; a3 = r3; a4 = r4;
            }
            {
                const float b0 = __shfl_xor(c0, off, 64);
                const float b1 = __shfl_xor(c1, off, 64);
                const float b2 = __shfl_xor(c2, off, 64);
                const float b3 = __shfl_xor(c3, off, 64);
                const float b4 = __shfl_xor(c4, off, 64);
                const float r0 = fmaxf(c0, b0);
                const float r1 = fmaxf(fmaxf(c1, b1), fminf(c0, b0));
                const float r2 = fmaxf(fmaxf(c2, b2), fmaxf(fminf(c0, b1), fminf(c1, b0)));
                const float r3 = fmaxf(fmaxf(c3, b3),
                                       fmaxf(fminf(c0, b2), fmaxf(fminf(c1, b1), fminf(c2, b0))));
                const float r4 = fmaxf(fmaxf(c4, b4),
                                       fmaxf(fmaxf(fminf(c0, b3), fminf(c3, b0)),
                                             fmaxf(fminf(c1, b2), fminf(c2, b1))));
                c0 = r0; c1 = r1; c2 = r2; c3 = r3; c4 = r4;
            }
        }
        if (lane == 0) {
            const float land0 = (a0 + a1 + a2 + a3 + a4) / 5.0f;
            const float land1 = (c0 + c1 + c2 + c3 + c4) / 5.0f;
            for (int rep = 0; rep < BREP; ++rep) {
                out[(rep * NB + b) * RESN + tt0] = land0;
                out[(rep * NB + b) * RESN + tt1] = land1;
            }
        }
        return;
    }
    // ---- polynomial fit outputs (basis computed inline per-b; dead path when bnz==0) ----
    const int b = blockIdx.x - nLand;
    float* oy = out + BREP * NB * RESN;
    float* od = out + 2 * BREP * NB * RESN;
    if (g_bnz == 0) {
        // betti == 0 everywhere -> coef == 0 -> yvals/fderiv exactly 0
        for (int tt = t; tt < RESN; tt += 256) {
            for (int rep = 0; rep < BREP; ++rep) {
                oy[(rep * NB + b) * RESN + tt] = 0.f;
                if (tt >= SAMP && tt < RESN - SAMP)
                    od[(rep * NB + b) * (RESN - 2 * SAMP) + (tt - SAMP)] = 0.f;
            }
        }
        return;
    }
    // --- orthonormal basis (Lanczos on diag(x), CGS x2, f64), 256-thread version ---
    {
        __shared__ double xs[RESN];
        __shared__ double w[RESN], dwv[RESN];
        __shared__ double cj[NMODE], ctot[NMODE];
        __shared__ double red2[4];
        for (int tt = t; tt < RESN; tt += 256) {
            xs[tt] = (2.0 * (double)tt - 999.0) / 999.0;
            g_qb[b][0][tt]  = 1.0 / sqrt(1000.0);
            g_qdb[b][0][tt] = 0.0;
        }
        __syncthreads();
        for (int k = 0; k < MDEG; ++k) {
            for (int tt = t; tt < RESN; tt += 256) {
                w[tt]   = xs[tt] * g_qb[b][k][tt];
                dwv[tt] = g_qb[b][k][tt] + xs[tt] * g_qdb[b][k][tt];
            }
            if (t < NMODE) ctot[t] = 0.0;
            __syncthreads();
            for (int round = 0; round < 2; ++round) {
                for (int j = wv; j <= k; j += 4) {
                    double p = 0.0;
                    for (int tt = lane; tt < RESN; tt += 64) p += w[tt] * g_qb[b][j][tt];
                    p = wave_sum_f64(p);
                    if (lane == 0) cj[j] = p;
                }
                __syncthreads();
                for (int tt = t; tt < RESN; tt += 256) {
                    double acc = w[tt];
                    for (int j = 0; j <= k; ++j) acc -= cj[j] * g_qb[b][j][tt];
                    w[tt] = acc;
                }
                if (t <= k) ctot[t] += cj[t];
                __syncthreads();
            }
            for (int tt = t; tt < RESN; tt += 256) {
                double acc = dwv[tt];
                for (int j = 0; j <= k; ++j) acc -= ctot[j] * g_qdb[b][j][tt];
                dwv[tt] = acc;
            }
            double p = 0.0;
            for (int tt = t; tt < RESN; tt += 256) p += w[tt] * w[tt];
            p = wave_sum_f64(p);
            if (lane == 0) red2[wv] = p;
            __syncthreads();
            if (t == 0) red2[0] = sqrt(red2[0] + red2[1] + red2[2] + red2[3]);
            __syncthreads();
            const double beta = red2[0];
            for (int tt = t; tt < RESN; tt += 256) {
                g_qb[b][k + 1][tt]  = w[tt] / beta;
                g_qdb[b][k + 1][tt] = dwv[tt] / beta;
            }
            __syncthreads();
        }
    }
    // --- fit: project betti onto basis; emit yvals and |derivative|*scale ---
    {
        __shared__ double dk[NMODE];
        __shared__ float  bet[RESN];
        for (int tt = t; tt < RESN; tt += 256) bet[tt] = g_betti[b * RESN + tt];
        __syncthreads();
        for (int k = wv; k < NMODE; k += 4) {
            double p = 0.0;
            for (int tt = lane; tt < RESN; tt += 64) p += (double)bet[tt] * g_qb[b][k][tt];
            p = wave_sum_f64(p);
            if (lane == 0) dk[k] = p;
        }
        __syncthreads();
        const double scale = 2.0 / 999.0;
        for (int tt = t; tt < RESN; tt += 256) {
            double y = 0.0, d = 0.0;
            for (int k = 0; k < NMODE; ++k) {
                y += dk[k] * g_qb[b][k][tt];
                d += dk[k] * g_qdb[b][k][tt];
            }
            const float yv = (float)y;
            const float fd = (float)(fabs(d) * scale);
            for (int rep = 0; rep < BREP; ++rep) {
                oy[(rep * NB + b) * RESN + tt] = yv;
                if (tt >= SAMP && tt < RESN - SAMP)
                    od[(rep * NB + b) * (RESN - 2 * SAMP) + (tt - SAMP)] = fd;
            }
        }
    }
}

// ---------------- launcher ----------------
extern "C" void kernel_launch(void* const* d_in, const int* in_sizes, int n_in,
                              void* d_out, int out_size, void* d_ws, size_t ws_size,
                              hipStream_t stream) {
    const int*   ei  = (const int*)d_in[1];    // edge_index (2, 160000)
    const float* ea  = (const float*)d_in[2];  // edge_attr  (160000, 1)
    float*       out = (float*)d_out;          // [land 32x1000 | yvals 32x1000 | fderiv 32x900]

    k_zero<<<(NB * NROI * NROI + 255) / 256, 256, 0, stream>>>();
    k_scatter<<<(NEDGE + 255) / 256, 256, 0, stream>>>(ei, ea);
    k_death1<<<(NB * NROI * NROI + 255) / 256, 256, 0, stream>>>();
    k_prim<<<NB, 256, 0, stream>>>();
    k_out<<<NB * RESN / LPB + NB, 256, 0, stream>>>(out);
}

// Round 11
// 91.114 us; speedup vs baseline: 2.0889x; 1.0839x over previous
//
#include <hip/hip_runtime.h>

// ---------------- problem constants ----------------
#define NROI  100
#define NB    4          // 400/100 diagonal blocks
#define NEDGE 160000
#define RESN  1000
#define SAMP  50
#define BREP  8          // batch tiling (B=8)
#define MDEG  44         // effective polynomial rank cutoff
#define NMODE (MDEG + 1)
#define BIGF  1.0e9f
#define PAIR_N 4950      // NROI*(NROI-1)/2 upper-triangular pairs (fixed, sentinel-masked)
#define LPB   8          // landscape grid points per block (2 per wave)

// ---------------- static device workspace ----------------
__device__ float  g_adj[NB * NROI * NROI];
__device__ float  g_D[NB * NROI * NROI];
__device__ float  g_death1[NB * NROI * NROI];
__device__ float2 g_pair[NB][PAIR_N];   // (birth, death) per pair; sentinel (+BIG,-BIG) if MST
__device__ float  g_betti[NB * RESN];
__device__ float  g_smin[NB], g_smax[NB];
__device__ int    g_bnz;                // any nonzero betti? (gates basis/fit path)
__device__ double g_qb[NB][NMODE][RESN];   // per-b orthonormal poly basis (dead path on this data)
__device__ double g_qdb[NB][NMODE][RESN];  // derivatives

// ---------------- helpers ----------------
__device__ inline double wave_sum_f64(double p) {
    for (int off = 32; off > 0; off >>= 1) p += __shfl_xor(p, off, 64);
    return p;
}

// ---------------- 1) zero accumulators ----------------
__global__ void k_zero() {
    const int tid = blockIdx.x * blockDim.x + threadIdx.x;
    if (tid < NB * NROI * NROI) g_adj[tid] = 0.f;
    if (tid == 0) g_bnz = 0;
}

// ---------------- 2) scatter-add diagonal-block edges ----------------
__global__ void k_scatter(const int* __restrict__ ei, const float* __restrict__ ea) {
    const int e = blockIdx.x * blockDim.x + threadIdx.x;
    if (e >= NEDGE) return;
    const int r = ei[e], c = ei[NEDGE + e];
    const int br = r / NROI, bc = c / NROI;
    if (br == bc)
        atomicAdd(&g_adj[br * NROI * NROI + (r - br * NROI) * NROI + (c - bc * NROI)], ea[e]);
}

// ---------------- 3) fused: D = max(1-adj,0) + H1 deaths ----------------
// death1[i,j] = max(D_ij, min_k!=i,j max(D_ik,D_jk)); fmin/fmax exact -> assoc-free.
__device__ inline float dclamp(float a) { const float d = 1.f - a; return d > 0.f ? d : 0.f; }
__global__ void k_death1() {
    const int tid = blockIdx.x * blockDim.x + threadIdx.x;
    if (tid >= NB * NROI * NROI) return;
    const int b  = tid / (NROI * NROI);
    const int ij = tid % (NROI * NROI);
    const int i = ij / NROI, j = ij % NROI;
    const float* __restrict__ ai = g_adj + b * NROI * NROI + i * NROI;
    const float* __restrict__ aj = g_adj + b * NROI * NROI + j * NROI;
    float Tm = BIGF;
    float dij = 0.f;
    for (int k = 0; k < NROI; k += 4) {
        const float4 a = *(const float4*)(ai + k);
        const float4 c = *(const float4*)(aj + k);
        const float di0 = dclamp(a.x), di1 = dclamp(a.y), di2 = dclamp(a.z), di3 = dclamp(a.w);
        const float dj0 = dclamp(c.x), dj1 = dclamp(c.y), dj2 = dclamp(c.z), dj3 = dclamp(c.w);
        float m0 = (k + 0 == i || k + 0 == j) ? BIGF : fmaxf(di0, dj0);
        float m1 = (k + 1 == i || k + 1 == j) ? BIGF : fmaxf(di1, dj1);
        float m2 = (k + 2 == i || k + 2 == j) ? BIGF : fmaxf(di2, dj2);
        float m3 = (k + 3 == i || k + 3 == j) ? BIGF : fmaxf(di3, dj3);
        Tm = fminf(Tm, fminf(fminf(m0, m1), fminf(m2, m3)));
        if (j >= k && j < k + 4) dij = (j == k) ? di0 : (j == k + 1) ? di1 : (j == k + 2) ? di2 : di3;
    }
    g_D[tid]      = dij;
    g_death1[tid] = fmaxf(dij, Tm);
}

// ---------------- 4) merged Prim + post-processing (4 blocks x 256) ----------------
__global__ void __launch_bounds__(256) k_prim() {
    const int b = blockIdx.x, t = threadIdx.x;
    const int lane = t & 63, wvi = t >> 6;
    const float* __restrict__ Db = g_D + b * NROI * NROI;
    __shared__ float Dl[NROI * NROI];          // 40 KB
    __shared__ float deathsL[NROI - 1];
    __shared__ int   usL[NROI - 1], vsL[NROI - 1];
    __shared__ int   parL[NROI];
    __shared__ unsigned char mstP[NROI * NROI];
    __shared__ float ndArr[NROI - 1];
    __shared__ int   ndCnt;
    __shared__ float redn[4], redx[4], redd[4];
    // stage D into LDS + init (all 256 threads)
    for (int i = t; i < NROI * NROI / 4; i += 256)
        ((float4*)Dl)[i] = ((const float4*)Db)[i];
    for (int e = t; e < NROI * NROI / 4; e += 256) ((unsigned int*)mstP)[e] = 0;
    for (int s = t; s < NROI - 1; s += 256) { deathsL[s] = 0.f; usL[s] = -1; }
    if (t == 0) ndCnt = 0;
    __syncthreads();

    // ---- wave 0 only: bitmask Prim loop (no barriers inside -> other waves park at next sync) ----
    if (t < 64) {
        const int  i1   = 64 + lane;
        const bool has1 = (i1 < NROI);
        // column-major zero bitmasks from LDS (consecutive lanes -> conflict-free)
        unsigned int zc0[4] = {0, 0, 0, 0}, zc1[4] = {0, 0, 0, 0};
        #pragma unroll 16
        for (int j = 0; j < NROI; ++j) {
            const unsigned int bit = 1u << (j & 31);
            if (Dl[j * NROI + lane] == 0.f) zc0[j >> 5] |= bit;
            if (has1 && Dl[j * NROI + i1] == 0.f) zc1[j >> 5] |= bit;
        }
        unsigned long long Clo = __ballot((zc0[0] & 1u) != 0u);   // row 0 = bit 0 of each column
        unsigned long long Chi = __ballot((zc1[0] & 1u) != 0u);
        unsigned long long Tlo = 1ull, Thi = 0ull;
        const unsigned long long MHI = (1ull << (NROI - 64)) - 1; // 36 valid hi bits
        bool it0 = (lane == 0), it1 = false;
        bool cand0 = (zc0[0] & 1u) != 0u;
        bool cand1 = (zc1[0] & 1u) != 0u;
        int  par0 = 0, par1 = 0;                 // first zero-offerer (frozen once cand)

        int step = 0;
        #pragma unroll 1
        for (; step < NROI - 1; ++step) {
            const unsigned long long alo = Clo & ~Tlo;
            const unsigned long long ahi = Chi & ~Thi & MHI;
            const unsigned long long rlo = ~Tlo;             // remaining nodes
            const unsigned long long rhi = ~Thi & MHI;
            // EARLY EXIT: all remaining are zero-candidates -> rest inserts ascending, death 0
            if (alo == rlo && ahi == rhi) break;
            int j;
            if (alo | ahi) {
                // jnp.argmin first-index == first not-in-tree node with mind==0 (D >= 0 always)
                j = alo ? (__ffsll(alo) - 1) : (63 + __ffsll(ahi));
                if (lane == 0) vsL[step] = j;    // deathsL/usL keep defaults 0 / -1
            } else {
                // rare general fallback: replay mind/parent over insertion order (single-wave LDS
                // ordering guarantees lane-0's earlier vsL writes are visible; no barrier needed)
                float m0 = Dl[lane]; int p0 = 0;
                float m1 = has1 ? Dl[i1] : BIGF; int p1 = 0;
                for (int s = 0; s < step; ++s) {
                    const int q = vsL[s];
                    const float d0 = Dl[q * NROI + lane];
                    if (d0 < m0) { m0 = d0; p0 = q; }     // strict <, as reference
                    if (has1) {
                        const float d1 = Dl[q * NROI + i1];
                        if (d1 < m1) { m1 = d1; p1 = q; }
                    }
                }
                const float v0 = it0 ? BIGF : m0;
                const float v1 = (has1 && !it1) ? m1 : BIGF;
                float vv; int idx, pw;
                if (v0 <= v1) { vv = v0; idx = lane; pw = p0; } else { vv = v1; idx = i1; pw = p1; }
                #pragma unroll
                for (int off = 1; off < 64; off <<= 1) {
                    const float ov = __shfl_xor(vv, off, 64);
                    const int   oi = __shfl_xor(idx, off, 64);
                    const int   op = __shfl_xor(pw, off, 64);
                    if (ov < vv || (ov == vv && oi < idx)) { vv = ov; idx = oi; pw = op; }
                }
                j = idx;
                if (lane == 0) { deathsL[step] = vv; usL[step] = pw; vsL[step] = j; }
            }
            if (j < 64) Tlo |= 1ull << j; else Thi |= 1ull << (j - 64);
            if (lane == j) it0 = true;
            if (i1 == j)   it1 = true;
            // extract bit j of MY columns (same-lane VALU), rebuild row j's mask via ballot
            const int d = j >> 5, sh = j & 31;
            const unsigned int w0 = (d == 0) ? zc0[0] : (d == 1) ? zc0[1] : (d == 2) ? zc0[2] : zc0[3];
            const unsigned int w1 = (d == 0) ? zc1[0] : (d == 1) ? zc1[1] : (d == 2) ? zc1[2] : zc1[3];
            const bool bit0 = (w0 >> sh) & 1u;
            const bool bit1 = (w1 >> sh) & 1u;
            Clo |= __ballot(bit0);
            Chi |= __ballot(bit1);
            // parent = first zero-offerer; frozen once candidate; in-tree nodes never update
            if (bit0 && !cand0 && !it0) { par0 = j; cand0 = true; }
            if (bit1 && !cand1 && !it1) { par1 = j; cand1 = true; }
        }
        // parallel epilogue: remaining nodes inserted ascending at steps step..98
        if (step < NROI - 1) {
            const unsigned long long rlo = ~Tlo;
            const unsigned long long rhi = ~Thi & MHI;
            const int nlo = __popcll(rlo);
            if ((rlo >> lane) & 1ull) {
                const int rank = __popcll(rlo & ((1ull << lane) - 1ull));
                vsL[step + rank] = lane;
            }
            if (has1 && ((rhi >> lane) & 1ull)) {
                const int rank = nlo + __popcll(rhi & ((1ull << lane) - 1ull));
                vsL[step + rank] = i1;
            }
        }
        parL[lane] = par0;
        if (has1) parL[i1] = par1;
    }
    __syncthreads();

    // ---- all 256 threads: mst bitmap + nonzero-death list ----
    if (t < NROI - 1) {
        const int j = vsL[t];
        int u = usL[t];
        if (u < 0) u = parL[j];                   // zero-death => parent = first-zero-offerer
        const int a = u < j ? u : j, c = u < j ? j : u;
        mstP[a * NROI + c] = 1;
        const float dth = deathsL[t];
        if (dth != 0.f) { const int p = atomicAdd(&ndCnt, 1); ndArr[p] = dth; }
    }
    __syncthreads();
    // pair table: e4-major, UNCONDITIONAL wide loads (global float4 + LDS b128 + mstP word)
    // so the compiler pipelines all 10 iterations; per-element semantics unchanged.
    float mn = BIGF, mx = -BIGF;
    const float4* __restrict__ d14 = (const float4*)(g_death1 + b * NROI * NROI);
    for (int e4 = t; e4 < NROI * NROI / 4; e4 += 256) {
        const float4 d4 = d14[e4];                           // coalesced, unconditional
        const float4 b4 = ((const float4*)Dl)[e4];           // LDS, unconditional
        const unsigned int m4 = ((const unsigned int*)mstP)[e4];
        const int e = e4 * 4;
        #pragma unroll
        for (int z = 0; z < 4; ++z) {
            const int ee = e + z;
            const int i = ee / NROI, j = ee % NROI;
            if (i < j) {
                const int pos = i * NROI - (i * (i + 1)) / 2 + (j - i - 1);
                const bool mst = ((m4 >> (8 * z)) & 0xffu) != 0u;
                float bv = BIGF, dv = -BIGF;
                if (!mst) {
                    bv = (z == 0) ? b4.x : (z == 1) ? b4.y : (z == 2) ? b4.z : b4.w;
                    dv = (z == 0) ? d4.x : (z == 1) ? d4.y : (z == 2) ? d4.z : d4.w;
                    mn = fminf(mn, bv); mx = fmaxf(mx, dv);
                }
                g_pair[b][pos] = make_float2(bv, dv);
            }
        }
    }
    float dmx = (t < NROI - 1) ? deathsL[t] : -1.f;
    #pragma unroll
    for (int off = 1; off < 64; off <<= 1) {
        mn  = fminf(mn,  __shfl_xor(mn,  off, 64));
        mx  = fmaxf(mx,  __shfl_xor(mx,  off, 64));
        dmx = fmaxf(dmx, __shfl_xor(dmx, off, 64));
    }
    if (lane == 0) { redn[wvi] = mn; redx[wvi] = mx; redd[wvi] = dmx; }
    __syncthreads();
    if (t == 0) {
        for (int z = 1; z < 4; ++z) {
            redn[0] = fminf(redn[0], redn[z]);
            redx[0] = fmaxf(redx[0], redx[z]);
            redd[0] = fmaxf(redd[0], redd[z]);
        }
        g_smin[b] = redn[0]; g_smax[b] = redx[0];
        if (redd[0] > 0.f) atomicOr(&g_bnz, 1);
    }
    __syncthreads();
    // betti: only NONZERO deaths can satisfy g < death (g >= 0 always) -> exact prefilter
    const float dmax  = redd[0];
    const float stepg = dmax / 999.0f;             // f32 linspace step, start = 0
    const int   nd    = ndCnt;
    for (int tt = t; tt < RESN; tt += 256) {
        const float g = (tt == RESN - 1) ? dmax : (float)tt * stepg;
        int c2 = 0;
        for (int s = 0; s < nd; ++s) c2 += (g < ndArr[s]) ? 1 : 0;
        g_betti[b * RESN + tt] = (float)c2;
    }
}

// ---------------- 5) merged outputs: 500 landscape blocks + 4 fit blocks (basis inlined) --------
__global__ void __launch_bounds__(256) k_out(float* __restrict__ out) {
    const int nLand = NB * RESN / LPB;   // 500 blocks, each: one b, LPB grid points
    const int t = threadIdx.x;
    const int wv = t >> 6, lane = t & 63;
    if (blockIdx.x < nLand) {
        const int blocksPerB = RESN / LPB;             // 125
        const int b      = blockIdx.x / blocksPerB;
        const int ptBase = (blockIdx.x % blocksPerB) * LPB;
        __shared__ float2 prL[PAIR_N];
        for (int i = t; i < PAIR_N / 2; i += 256)      // 2475 float4, coalesced
            ((float4*)prL)[i] = ((const float4*)g_pair[b])[i];
        __syncthreads();
        const float smn = g_smin[b], smx = g_smax[b];
        const float stepg = (smx - smn) / 999.0f;
        const int tt0 = ptBase + 2 * wv, tt1 = tt0 + 1;
        const float g0 = (tt0 == RESN - 1) ? smx : smn + (float)tt0 * stepg;
        const float g1 = (tt1 == RESN - 1) ? smx : smn + (float)tt1 * stepg;
        const float SQ2 = 1.41421356f;                 // f32 sqrt(2), as reference
        // two top-5 sets in NAMED scalars (no runtime indexing -> registers)
        float a0 = 0.f, a1 = 0.f, a2 = 0.f, a3 = 0.f, a4 = 0.f;
        float c0 = 0.f, c1 = 0.f, c2 = 0.f, c3 = 0.f, c4 = 0.f;
        #pragma unroll 2
        for (int e = lane; e < PAIR_N; e += 64) {
            const float2 p = prL[e];
            float v = fminf(g0 - p.x, p.y - g0);
            v = v > 0.f ? v : 0.f;
            v *= SQ2;
            if (v > a4) {
                a4 = v;
                if (a4 > a3) { const float s = a3; a3 = a4; a4 = s;
                    if (a3 > a2) { const float s2 = a2; a2 = a3; a3 = s2;
                        if (a2 > a1) { const float s3 = a1; a1 = a2; a2 = s3;
                            if (a1 > a0) { const float s4 = a0; a0 = a1; a1 = s4; } } } }
            }
            float w = fminf(g1 - p.x, p.y - g1);
            w = w > 0.f ? w : 0.f;
            w *= SQ2;
            if (w > c4) {
                c4 = w;
                if (c4 > c3) { const float s = c3; c3 = c4; c4 = s;
                    if (c3 > c2) { const float s2 = c2; c2 = c3; c3 = s2;
                        if (c2 > c1) { const float s3 = c1; c1 = c2; c2 = s3;
                            if (c1 > c0) { const float s4 = c0; c0 = c1; c1 = s4; } } } }
            }
        }
        // butterfly reduce: exact top-5 merge network, C[k] = max(A[k],B[k],max_{i+j=k-1} min(A[i],B[j]))
        #pragma unroll
        for (int off = 1; off < 64; off <<= 1) {
            {
                const float b0 = __shfl_xor(a0, off, 64);
                const float b1 = __shfl_xor(a1, off, 64);
                const float b2 = __shfl_xor(a2, off, 64);
                const float b3 = __shfl_xor(a3, off, 64);
                const float b4 = __shfl_xor(a4, off, 64);
                const float r0 = fmaxf(a0, b0);
                const float r1 = fmaxf(fmaxf(a1, b1), fminf(a0, b0));
                const float r2 = fmaxf(fmaxf(a2, b2), fmaxf(fminf(a0, b1), fminf(a1, b0)));
                const float r3 = fmaxf(fmaxf(a3, b3),
                                       fmaxf(fminf(a0, b2), fmaxf(fminf(a1, b1), fminf(a2, b0))));
                const float r4 = fmaxf(fmaxf(a4, b4),
                                       fmaxf(fmaxf(fminf(a0, b3), fminf(a3, b0)),
                                             fmaxf(fminf(a1, b2), fminf(a2, b1))));
                a0 = r0; a1 = r1; a2 = r2; a3 = r3; a4 = r4;
            }
            {
                const float b0 = __shfl_xor(c0, off, 64);
                const float b1 = __shfl_xor(c1, off, 64);
                const float b2 = __shfl_xor(c2, off, 64);
                const float b3 = __shfl_xor(c3, off, 64);
                const float b4 = __shfl_xor(c4, off, 64);
                const float r0 = fmaxf(c0, b0);
                const float r1 = fmaxf(fmaxf(c1, b1), fminf(c0, b0));
                const float r2 = fmaxf(fmaxf(c2, b2), fmaxf(fminf(c0, b1), fminf(c1, b0)));
                const float r3 = fmaxf(fmaxf(c3, b3),
                                       fmaxf(fminf(c0, b2), fmaxf(fminf(c1, b1), fminf(c2, b0))));
                const float r4 = fmaxf(fmaxf(c4, b4),
                                       fmaxf(fmaxf(fminf(c0, b3), fminf(c3, b0)),
                                             fmaxf(fminf(c1, b2), fminf(c2, b1))));
                c0 = r0; c1 = r1; c2 = r2; c3 = r3; c4 = r4;
            }
        }
        if (lane == 0) {
            const float land0 = (a0 + a1 + a2 + a3 + a4) / 5.0f;
            const float land1 = (c0 + c1 + c2 + c3 + c4) / 5.0f;
            for (int rep = 0; rep < BREP; ++rep) {
                out[(rep * NB + b) * RESN + tt0] = land0;
                out[(rep * NB + b) * RESN + tt1] = land1;
            }
        }
        return;
    }
    // ---- polynomial fit outputs (basis computed inline per-b; dead path when bnz==0) ----
    const int b = blockIdx.x - nLand;
    float* oy = out + BREP * NB * RESN;
    float* od = out + 2 * BREP * NB * RESN;
    if (g_bnz == 0) {
        // betti == 0 everywhere -> coef == 0 -> yvals/fderiv exactly 0
        for (int tt = t; tt < RESN; tt += 256) {
            for (int rep = 0; rep < BREP; ++rep) {
                oy[(rep * NB + b) * RESN + tt] = 0.f;
                if (tt >= SAMP && tt < RESN - SAMP)
                    od[(rep * NB + b) * (RESN - 2 * SAMP) + (tt - SAMP)] = 0.f;
            }
        }
        return;
    }
    // --- orthonormal basis (Lanczos on diag(x), CGS x2, f64), 256-thread version ---
    {
        __shared__ double xs[RESN];
        __shared__ double w[RESN], dwv[RESN];
        __shared__ double cj[NMODE], ctot[NMODE];
        __shared__ double red2[4];
        for (int tt = t; tt < RESN; tt += 256) {
            xs[tt] = (2.0 * (double)tt - 999.0) / 999.0;
            g_qb[b][0][tt]  = 1.0 / sqrt(1000.0);
            g_qdb[b][0][tt] = 0.0;
        }
        __syncthreads();
        for (int k = 0; k < MDEG; ++k) {
            for (int tt = t; tt < RESN; tt += 256) {
                w[tt]   = xs[tt] * g_qb[b][k][tt];
                dwv[tt] = g_qb[b][k][tt] + xs[tt] * g_qdb[b][k][tt];
            }
            if (t < NMODE) ctot[t] = 0.0;
            __syncthreads();
            for (int round = 0; round < 2; ++round) {
                for (int j = wv; j <= k; j += 4) {
                    double p = 0.0;
                    for (int tt = lane; tt < RESN; tt += 64) p += w[tt] * g_qb[b][j][tt];
                    p = wave_sum_f64(p);
                    if (lane == 0) cj[j] = p;
                }
                __syncthreads();
                for (int tt = t; tt < RESN; tt += 256) {
                    double acc = w[tt];
                    for (int j = 0; j <= k; ++j) acc -= cj[j] * g_qb[b][j][tt];
                    w[tt] = acc;
                }
                if (t <= k) ctot[t] += cj[t];
                __syncthreads();
            }
            for (int tt = t; tt < RESN; tt += 256) {
                double acc = dwv[tt];
                for (int j = 0; j <= k; ++j) acc -= ctot[j] * g_qdb[b][j][tt];
                dwv[tt] = acc;
            }
            double p = 0.0;
            for (int tt = t; tt < RESN; tt += 256) p += w[tt] * w[tt];
            p = wave_sum_f64(p);
            if (lane == 0) red2[wv] = p;
            __syncthreads();
            if (t == 0) red2[0] = sqrt(red2[0] + red2[1] + red2[2] + red2[3]);
            __syncthreads();
            const double beta = red2[0];
            for (int tt = t; tt < RESN; tt += 256) {
                g_qb[b][k + 1][tt]  = w[tt] / beta;
                g_qdb[b][k + 1][tt] = dwv[tt] / beta;
            }
            __syncthreads();
        }
    }
    // --- fit: project betti onto basis; emit yvals and |derivative|*scale ---
    {
        __shared__ double dk[NMODE];
        __shared__ float  bet[RESN];
        for (int tt = t; tt < RESN; tt += 256) bet[tt] = g_betti[b * RESN + tt];
        __syncthreads();
        for (int k = wv; k < NMODE; k += 4) {
            double p = 0.0;
            for (int tt = lane; tt < RESN; tt += 64) p += (double)bet[tt] * g_qb[b][k][tt];
            p = wave_sum_f64(p);
            if (lane == 0) dk[k] = p;
        }
        __syncthreads();
        const double scale = 2.0 / 999.0;
        for (int tt = t; tt < RESN; tt += 256) {
            double y = 0.0, d = 0.0;
            for (int k = 0; k < NMODE; ++k) {
                y += dk[k] * g_qb[b][k][tt];
                d += dk[k] * g_qdb[b][k][tt];
            }
            const float yv = (float)y;
            const float fd = (float)(fabs(d) * scale);
            for (int rep = 0; rep < BREP; ++rep) {
                oy[(rep * NB + b) * RESN + tt] = yv;
                if (tt >= SAMP && tt < RESN - SAMP)
                    od[(rep * NB + b) * (RESN - 2 * SAMP) + (tt - SAMP)] = fd;
            }
        }
    }
}

// ---------------- launcher ----------------
extern "C" void kernel_launch(void* const* d_in, const int* in_sizes, int n_in,
                              void* d_out, int out_size, void* d_ws, size_t ws_size,
                              hipStream_t stream) {
    const int*   ei  = (const int*)d_in[1];    // edge_index (2, 160000)
    const float* ea  = (const float*)d_in[2];  // edge_attr  (160000, 1)
    float*       out = (float*)d_out;          // [land 32x1000 | yvals 32x1000 | fderiv 32x900]

    k_zero<<<(NB * NROI * NROI + 255) / 256, 256, 0, stream>>>();
    k_scatter<<<(NEDGE + 255) / 256, 256, 0, stream>>>(ei, ea);
    k_death1<<<(NB * NROI * NROI + 255) / 256, 256, 0, stream>>>();
    k_prim<<<NB, 256, 0, stream>>>();
    k_out<<<NB * RESN / LPB + NB, 256, 0, stream>>>(out);
}

// Round 12
// 83.307 us; speedup vs baseline: 2.2847x; 1.0937x over previous
//
#include <hip/hip_runtime.h>

// ---------------- problem constants ----------------
#define NROI  100
#define NB    4          // 400/100 diagonal blocks
#define NEDGE 160000
#define RESN  1000
#define SAMP  50
#define BREP  8          // batch tiling (B=8)
#define MDEG  44         // effective polynomial rank cutoff
#define NMODE (MDEG + 1)
#define BIGF  1.0e9f
#define PAIR_N 4950      // NROI*(NROI-1)/2 upper-triangular pairs (fixed, sentinel-masked)
#define LPB   8          // landscape grid points per block (2 per wave)

// ---------------- static device workspace ----------------
// INVARIANT: g_adj == 0 at kernel_launch entry. Holds on call 1 (.bss zero-init) and is
// re-established by k_out's fit blocks at the end of every call (replaces a k_zero launch).
__device__ float  g_adj[NB * NROI * NROI];
__device__ float  g_D[NB * NROI * NROI];
__device__ float  g_death1[NB * NROI * NROI];
__device__ float2 g_pair[NB][PAIR_N];   // (birth, death) per pair; sentinel (+BIG,-BIG) if MST
__device__ float  g_betti[NB * RESN];
__device__ float  g_smin[NB], g_smax[NB];
__device__ int    g_bnz;                // any nonzero betti? (zeroed each call by k_death1)
__device__ double g_qb[NB][NMODE][RESN];   // per-b orthonormal poly basis (dead path on this data)
__device__ double g_qdb[NB][NMODE][RESN];  // derivatives

// ---------------- helpers ----------------
__device__ inline double wave_sum_f64(double p) {
    for (int off = 32; off > 0; off >>= 1) p += __shfl_xor(p, off, 64);
    return p;
}

// ---------------- 1) scatter-add diagonal-block edges (g_adj pre-zeroed, see invariant) -------
__global__ void k_scatter(const int* __restrict__ ei, const float* __restrict__ ea) {
    const int e = blockIdx.x * blockDim.x + threadIdx.x;
    if (e >= NEDGE) return;
    const int r = ei[e], c = ei[NEDGE + e];
    const int br = r / NROI, bc = c / NROI;
    if (br == bc)
        atomicAdd(&g_adj[br * NROI * NROI + (r - br * NROI) * NROI + (c - bc * NROI)], ea[e]);
}

// ---------------- 2) fused: D = max(1-adj,0) (all cells) + H1 deaths (upper triangle only) ----
// death1[i,j] = max(D_ij, min_k!=i,j max(D_ik,D_jk)); fmin/fmax exact -> assoc-free.
// Only i<j cells of g_death1 are ever consumed (pair table guards i<j).
__device__ inline float dclamp(float a) { const float d = 1.f - a; return d > 0.f ? d : 0.f; }
__global__ void k_death1() {
    const int tid = blockIdx.x * blockDim.x + threadIdx.x;
    if (tid >= NB * NROI * NROI) return;
    if (tid == 0) g_bnz = 0;                  // before k_prim's atomicOr (stream-ordered)
    const int b  = tid / (NROI * NROI);
    const int ij = tid % (NROI * NROI);
    const int i = ij / NROI, j = ij % NROI;
    const float* __restrict__ ai = g_adj + b * NROI * NROI + i * NROI;
    const float* __restrict__ aj = g_adj + b * NROI * NROI + j * NROI;
    const float dij = dclamp(ai[j]);
    g_D[tid] = dij;                            // full matrix needed by Prim
    if (i >= j) return;                        // Tm loop only where death1 is consumed
    float Tm = BIGF;
    for (int k = 0; k < NROI; k += 4) {
        const float4 a = *(const float4*)(ai + k);
        const float4 c = *(const float4*)(aj + k);
        const float di0 = dclamp(a.x), di1 = dclamp(a.y), di2 = dclamp(a.z), di3 = dclamp(a.w);
        const float dj0 = dclamp(c.x), dj1 = dclamp(c.y), dj2 = dclamp(c.z), dj3 = dclamp(c.w);
        float m0 = (k + 0 == i || k + 0 == j) ? BIGF : fmaxf(di0, dj0);
        float m1 = (k + 1 == i || k + 1 == j) ? BIGF : fmaxf(di1, dj1);
        float m2 = (k + 2 == i || k + 2 == j) ? BIGF : fmaxf(di2, dj2);
        float m3 = (k + 3 == i || k + 3 == j) ? BIGF : fmaxf(di3, dj3);
        Tm = fminf(Tm, fminf(fminf(m0, m1), fminf(m2, m3)));
    }
    g_death1[tid] = fmaxf(dij, Tm);
}

// ---------------- 3) merged Prim + post-processing (4 blocks x 256) ----------------
__global__ void __launch_bounds__(256) k_prim() {
    const int b = blockIdx.x, t = threadIdx.x;
    const int lane = t & 63, wvi = t >> 6;
    const float* __restrict__ Db = g_D + b * NROI * NROI;
    __shared__ float Dl[NROI * NROI];          // 40 KB
    __shared__ float deathsL[NROI - 1];
    __shared__ int   usL[NROI - 1], vsL[NROI - 1];
    __shared__ int   parL[NROI];
    __shared__ unsigned char mstP[NROI * NROI];
    __shared__ float ndArr[NROI - 1];
    __shared__ int   ndCnt;
    __shared__ float redn[4], redx[4], redd[4];
    // stage D into LDS + init (all 256 threads)
    for (int i = t; i < NROI * NROI / 4; i += 256)
        ((float4*)Dl)[i] = ((const float4*)Db)[i];
    for (int e = t; e < NROI * NROI / 4; e += 256) ((unsigned int*)mstP)[e] = 0;
    for (int s = t; s < NROI - 1; s += 256) { deathsL[s] = 0.f; usL[s] = -1; }
    if (t == 0) ndCnt = 0;
    __syncthreads();

    // ---- wave 0 only: bitmask Prim loop (no barriers inside -> other waves park at next sync) ----
    if (t < 64) {
        const int  i1   = 64 + lane;
        const bool has1 = (i1 < NROI);
        // column-major zero bitmasks from LDS (consecutive lanes -> conflict-free)
        unsigned int zc0[4] = {0, 0, 0, 0}, zc1[4] = {0, 0, 0, 0};
        #pragma unroll 16
        for (int j = 0; j < NROI; ++j) {
            const unsigned int bit = 1u << (j & 31);
            if (Dl[j * NROI + lane] == 0.f) zc0[j >> 5] |= bit;
            if (has1 && Dl[j * NROI + i1] == 0.f) zc1[j >> 5] |= bit;
        }
        unsigned long long Clo = __ballot((zc0[0] & 1u) != 0u);   // row 0 = bit 0 of each column
        unsigned long long Chi = __ballot((zc1[0] & 1u) != 0u);
        unsigned long long Tlo = 1ull, Thi = 0ull;
        const unsigned long long MHI = (1ull << (NROI - 64)) - 1; // 36 valid hi bits
        bool it0 = (lane == 0), it1 = false;
        bool cand0 = (zc0[0] & 1u) != 0u;
        bool cand1 = (zc1[0] & 1u) != 0u;
        int  par0 = 0, par1 = 0;                 // first zero-offerer (frozen once cand)

        int step = 0;
        #pragma unroll 1
        for (; step < NROI - 1; ++step) {
            const unsigned long long alo = Clo & ~Tlo;
            const unsigned long long ahi = Chi & ~Thi & MHI;
            const unsigned long long rlo = ~Tlo;             // remaining nodes
            const unsigned long long rhi = ~Thi & MHI;
            // EARLY EXIT: all remaining are zero-candidates -> rest inserts ascending, death 0
            if (alo == rlo && ahi == rhi) break;
            int j;
            if (alo | ahi) {
                // jnp.argmin first-index == first not-in-tree node with mind==0 (D >= 0 always)
                j = alo ? (__ffsll(alo) - 1) : (63 + __ffsll(ahi));
                if (lane == 0) vsL[step] = j;    // deathsL/usL keep defaults 0 / -1
            } else {
                // rare general fallback: replay mind/parent over insertion order (single-wave LDS
                // ordering guarantees lane-0's earlier vsL writes are visible; no barrier needed)
                float m0 = Dl[lane]; int p0 = 0;
                float m1 = has1 ? Dl[i1] : BIGF; int p1 = 0;
                for (int s = 0; s < step; ++s) {
                    const int q = vsL[s];
                    const float d0 = Dl[q * NROI + lane];
                    if (d0 < m0) { m0 = d0; p0 = q; }     // strict <, as reference
                    if (has1) {
                        const float d1 = Dl[q * NROI + i1];
                        if (d1 < m1) { m1 = d1; p1 = q; }
                    }
                }
                const float v0 = it0 ? BIGF : m0;
                const float v1 = (has1 && !it1) ? m1 : BIGF;
                float vv; int idx, pw;
                if (v0 <= v1) { vv = v0; idx = lane; pw = p0; } else { vv = v1; idx = i1; pw = p1; }
                #pragma unroll
                for (int off = 1; off < 64; off <<= 1) {
                    const float ov = __shfl_xor(vv, off, 64);
                    const int   oi = __shfl_xor(idx, off, 64);
                    const int   op = __shfl_xor(pw, off, 64);
                    if (ov < vv || (ov == vv && oi < idx)) { vv = ov; idx = oi; pw = op; }
                }
                j = idx;
                if (lane == 0) { deathsL[step] = vv; usL[step] = pw; vsL[step] = j; }
            }
            if (j < 64) Tlo |= 1ull << j; else Thi |= 1ull << (j - 64);
            if (lane == j) it0 = true;
            if (i1 == j)   it1 = true;
            // extract bit j of MY columns (same-lane VALU), rebuild row j's mask via ballot
            const int d = j >> 5, sh = j & 31;
            const unsigned int w0 = (d == 0) ? zc0[0] : (d == 1) ? zc0[1] : (d == 2) ? zc0[2] : zc0[3];
            const unsigned int w1 = (d == 0) ? zc1[0] : (d == 1) ? zc1[1] : (d == 2) ? zc1[2] : zc1[3];
            const bool bit0 = (w0 >> sh) & 1u;
            const bool bit1 = (w1 >> sh) & 1u;
            Clo |= __ballot(bit0);
            Chi |= __ballot(bit1);
            // parent = first zero-offerer; frozen once candidate; in-tree nodes never update
            if (bit0 && !cand0 && !it0) { par0 = j; cand0 = true; }
            if (bit1 && !cand1 && !it1) { par1 = j; cand1 = true; }
        }
        // parallel epilogue: remaining nodes inserted ascending at steps step..98
        if (step < NROI - 1) {
            const unsigned long long rlo = ~Tlo;
            const unsigned long long rhi = ~Thi & MHI;
            const int nlo = __popcll(rlo);
            if ((rlo >> lane) & 1ull) {
                const int rank = __popcll(rlo & ((1ull << lane) - 1ull));
                vsL[step + rank] = lane;
            }
            if (has1 && ((rhi >> lane) & 1ull)) {
                const int rank = nlo + __popcll(rhi & ((1ull << lane) - 1ull));
                vsL[step + rank] = i1;
            }
        }
        parL[lane] = par0;
        if (has1) parL[i1] = par1;
    }
    __syncthreads();

    // ---- all 256 threads: mst bitmap + nonzero-death list ----
    if (t < NROI - 1) {
        const int j = vsL[t];
        int u = usL[t];
        if (u < 0) u = parL[j];                   // zero-death => parent = first-zero-offerer
        const int a = u < j ? u : j, c = u < j ? j : u;
        mstP[a * NROI + c] = 1;
        const float dth = deathsL[t];
        if (dth != 0.f) { const int p = atomicAdd(&ndCnt, 1); ndArr[p] = dth; }
    }
    __syncthreads();
    // pair table: e4-major, UNCONDITIONAL wide loads (global float4 + LDS b128 + mstP word)
    // so the compiler pipelines all 10 iterations; per-element semantics unchanged.
    float mn = BIGF, mx = -BIGF;
    const float4* __restrict__ d14 = (const float4*)(g_death1 + b * NROI * NROI);
    for (int e4 = t; e4 < NROI * NROI / 4; e4 += 256) {
        const float4 d4 = d14[e4];                           // coalesced, unconditional
        const float4 b4 = ((const float4*)Dl)[e4];           // LDS, unconditional
        const unsigned int m4 = ((const unsigned int*)mstP)[e4];
        const int e = e4 * 4;
        #pragma unroll
        for (int z = 0; z < 4; ++z) {
            const int ee = e + z;
            const int i = ee / NROI, j = ee % NROI;
            if (i < j) {
                const int pos = i * NROI - (i * (i + 1)) / 2 + (j - i - 1);
                const bool mst = ((m4 >> (8 * z)) & 0xffu) != 0u;
                float bv = BIGF, dv = -BIGF;
                if (!mst) {
                    bv = (z == 0) ? b4.x : (z == 1) ? b4.y : (z == 2) ? b4.z : b4.w;
                    dv = (z == 0) ? d4.x : (z == 1) ? d4.y : (z == 2) ? d4.z : d4.w;
                    mn = fminf(mn, bv); mx = fmaxf(mx, dv);
                }
                g_pair[b][pos] = make_float2(bv, dv);
            }
        }
    }
    float dmx = (t < NROI - 1) ? deathsL[t] : -1.f;
    #pragma unroll
    for (int off = 1; off < 64; off <<= 1) {
        mn  = fminf(mn,  __shfl_xor(mn,  off, 64));
        mx  = fmaxf(mx,  __shfl_xor(mx,  off, 64));
        dmx = fmaxf(dmx, __shfl_xor(dmx, off, 64));
    }
    if (lane == 0) { redn[wvi] = mn; redx[wvi] = mx; redd[wvi] = dmx; }
    __syncthreads();
    if (t == 0) {
        for (int z = 1; z < 4; ++z) {
            redn[0] = fminf(redn[0], redn[z]);
            redx[0] = fmaxf(redx[0], redx[z]);
            redd[0] = fmaxf(redd[0], redd[z]);
        }
        g_smin[b] = redn[0]; g_smax[b] = redx[0];
        if (redd[0] > 0.f) atomicOr(&g_bnz, 1);
    }
    __syncthreads();
    // betti: only NONZERO deaths can satisfy g < death (g >= 0 always) -> exact prefilter
    const float dmax  = redd[0];
    const float stepg = dmax / 999.0f;             // f32 linspace step, start = 0
    const int   nd    = ndCnt;
    for (int tt = t; tt < RESN; tt += 256) {
        const float g = (tt == RESN - 1) ? dmax : (float)tt * stepg;
        int c2 = 0;
        for (int s = 0; s < nd; ++s) c2 += (g < ndArr[s]) ? 1 : 0;
        g_betti[b * RESN + tt] = (float)c2;
    }
}

// ---------------- 4) merged outputs: 500 landscape blocks + 4 fit blocks (basis inlined) --------
__global__ void __launch_bounds__(256) k_out(float* __restrict__ out) {
    const int nLand = NB * RESN / LPB;   // 500 blocks, each: one b, LPB grid points
    const int t = threadIdx.x;
    const int wv = t >> 6, lane = t & 63;
    if (blockIdx.x < nLand) {
        const int blocksPerB = RESN / LPB;             // 125
        const int b      = blockIdx.x / blocksPerB;
        const int ptBase = (blockIdx.x % blocksPerB) * LPB;
        __shared__ float2 prL[PAIR_N];
        for (int i = t; i < PAIR_N / 2; i += 256)      // 2475 float4, coalesced
            ((float4*)prL)[i] = ((const float4*)g_pair[b])[i];
        __syncthreads();
        const float smn = g_smin[b], smx = g_smax[b];
        const float stepg = (smx - smn) / 999.0f;
        const int tt0 = ptBase + 2 * wv, tt1 = tt0 + 1;
        const float g0 = (tt0 == RESN - 1) ? smx : smn + (float)tt0 * stepg;
        const float g1 = (tt1 == RESN - 1) ? smx : smn + (float)tt1 * stepg;
        const float SQ2 = 1.41421356f;                 // f32 sqrt(2), as reference
        // two top-5 sets in NAMED scalars (no runtime indexing -> registers)
        float a0 = 0.f, a1 = 0.f, a2 = 0.f, a3 = 0.f, a4 = 0.f;
        float c0 = 0.f, c1 = 0.f, c2 = 0.f, c3 = 0.f, c4 = 0.f;
        #pragma unroll 2
        for (int e = lane; e < PAIR_N; e += 64) {
            const float2 p = prL[e];
            float v = fminf(g0 - p.x, p.y - g0);
            v = v > 0.f ? v : 0.f;
            v *= SQ2;
            if (v > a4) {
                a4 = v;
                if (a4 > a3) { const float s = a3; a3 = a4; a4 = s;
                    if (a3 > a2) { const float s2 = a2; a2 = a3; a3 = s2;
                        if (a2 > a1) { const float s3 = a1; a1 = a2; a2 = s3;
                            if (a1 > a0) { const float s4 = a0; a0 = a1; a1 = s4; } } } }
            }
            float w = fminf(g1 - p.x, p.y - g1);
            w = w > 0.f ? w : 0.f;
            w *= SQ2;
            if (w > c4) {
                c4 = w;
                if (c4 > c3) { const float s = c3; c3 = c4; c4 = s;
                    if (c3 > c2) { const float s2 = c2; c2 = c3; c3 = s2;
                        if (c2 > c1) { const float s3 = c1; c1 = c2; c2 = s3;
                            if (c1 > c0) { const float s4 = c0; c0 = c1; c1 = s4; } } } }
            }
        }
        // butterfly reduce: exact top-5 merge network, C[k] = max(A[k],B[k],max_{i+j=k-1} min(A[i],B[j]))
        #pragma unroll
        for (int off = 1; off < 64; off <<= 1) {
            {
                const float b0 = __shfl_xor(a0, off, 64);
                const float b1 = __shfl_xor(a1, off, 64);
                const float b2 = __shfl_xor(a2, off, 64);
                const float b3 = __shfl_xor(a3, off, 64);
                const float b4 = __shfl_xor(a4, off, 64);
                const float r0 = fmaxf(a0, b0);
                const float r1 = fmaxf(fmaxf(a1, b1), fminf(a0, b0));
                const float r2 = fmaxf(fmaxf(a2, b2), fmaxf(fminf(a0, b1), fminf(a1, b0)));
                const float r3 = fmaxf(fmaxf(a3, b3),
                                       fmaxf(fminf(a0, b2), fmaxf(fminf(a1, b1), fminf(a2, b0))));
                const float r4 = fmaxf(fmaxf(a4, b4),
                                       fmaxf(fmaxf(fminf(a0, b3), fminf(a3, b0)),
                                             fmaxf(fminf(a1, b2), fminf(a2, b1))));
                a0 = r0; a1 = r1; a2 = r2; a3 = r3; a4 = r4;
            }
            {
                const float b0 = __shfl_xor(c0, off, 64);
                const float b1 = __shfl_xor(c1, off, 64);
                const float b2 = __shfl_xor(c2, off, 64);
                const float b3 = __shfl_xor(c3, off, 64);
                const float b4 = __shfl_xor(c4, off, 64);
                const float r0 = fmaxf(c0, b0);
                const float r1 = fmaxf(fmaxf(c1, b1), fminf(c0, b0));
                const float r2 = fmaxf(fmaxf(c2, b2), fmaxf(fminf(c0, b1), fminf(c1, b0)));
                const float r3 = fmaxf(fmaxf(c3, b3),
                                       fmaxf(fminf(c0, b2), fmaxf(fminf(c1, b1), fminf(c2, b0))));
                const float r4 = fmaxf(fmaxf(c4, b4),
                                       fmaxf(fmaxf(fminf(c0, b3), fminf(c3, b0)),
                                             fmaxf(fminf(c1, b2), fminf(c2, b1))));
                c0 = r0; c1 = r1; c2 = r2; c3 = r3; c4 = r4;
            }
        }
        if (lane == 0) {
            const float land0 = (a0 + a1 + a2 + a3 + a4) / 5.0f;
            const float land1 = (c0 + c1 + c2 + c3 + c4) / 5.0f;
            for (int rep = 0; rep < BREP; ++rep) {
                out[(rep * NB + b) * RESN + tt0] = land0;
                out[(rep * NB + b) * RESN + tt1] = land1;
            }
        }
        return;
    }
    // ---- fit blocks: re-zero g_adj for the next call (replaces k_zero; see invariant) ----
    const int b = blockIdx.x - nLand;
    {
        float4* az = (float4*)(g_adj + b * NROI * NROI);
        const float4 z4 = make_float4(0.f, 0.f, 0.f, 0.f);
        for (int i = t; i < NROI * NROI / 4; i += 256) az[i] = z4;
    }
    // ---- polynomial fit outputs (basis computed inline per-b; dead path when bnz==0) ----
    float* oy = out + BREP * NB * RESN;
    float* od = out + 2 * BREP * NB * RESN;
    if (g_bnz == 0) {
        // betti == 0 everywhere -> coef == 0 -> yvals/fderiv exactly 0
        for (int tt = t; tt < RESN; tt += 256) {
            for (int rep = 0; rep < BREP; ++rep) {
                oy[(rep * NB + b) * RESN + tt] = 0.f;
                if (tt >= SAMP && tt < RESN - SAMP)
                    od[(rep * NB + b) * (RESN - 2 * SAMP) + (tt - SAMP)] = 0.f;
            }
        }
        return;
    }
    // --- orthonormal basis (Lanczos on diag(x), CGS x2, f64), 256-thread version ---
    {
        __shared__ double xs[RESN];
        __shared__ double w[RESN], dwv[RESN];
        __shared__ double cj[NMODE], ctot[NMODE];
        __shared__ double red2[4];
        for (int tt = t; tt < RESN; tt += 256) {
            xs[tt] = (2.0 * (double)tt - 999.0) / 999.0;
            g_qb[b][0][tt]  = 1.0 / sqrt(1000.0);
            g_qdb[b][0][tt] = 0.0;
        }
        __syncthreads();
        for (int k = 0; k < MDEG; ++k) {
            for (int tt = t; tt < RESN; tt += 256) {
                w[tt]   = xs[tt] * g_qb[b][k][tt];
                dwv[tt] = g_qb[b][k][tt] + xs[tt] * g_qdb[b][k][tt];
            }
            if (t < NMODE) ctot[t] = 0.0;
            __syncthreads();
            for (int round = 0; round < 2; ++round) {
                for (int j = wv; j <= k; j += 4) {
                    double p = 0.0;
                    for (int tt = lane; tt < RESN; tt += 64) p += w[tt] * g_qb[b][j][tt];
                    p = wave_sum_f64(p);
                    if (lane == 0) cj[j] = p;
                }
                __syncthreads();
                for (int tt = t; tt < RESN; tt += 256) {
                    double acc = w[tt];
                    for (int j = 0; j <= k; ++j) acc -= cj[j] * g_qb[b][j][tt];
                    w[tt] = acc;
                }
                if (t <= k) ctot[t] += cj[t];
                __syncthreads();
            }
            for (int tt = t; tt < RESN; tt += 256) {
                double acc = dwv[tt];
                for (int j = 0; j <= k; ++j) acc -= ctot[j] * g_qdb[b][j][tt];
                dwv[tt] = acc;
            }
            double p = 0.0;
            for (int tt = t; tt < RESN; tt += 256) p += w[tt] * w[tt];
            p = wave_sum_f64(p);
            if (lane == 0) red2[wv] = p;
            __syncthreads();
            if (t == 0) red2[0] = sqrt(red2[0] + red2[1] + red2[2] + red2[3]);
            __syncthreads();
            const double beta = red2[0];
            for (int tt = t; tt < RESN; tt += 256) {
                g_qb[b][k + 1][tt]  = w[tt] / beta;
                g_qdb[b][k + 1][tt] = dwv[tt] / beta;
            }
            __syncthreads();
        }
    }
    // --- fit: project betti onto basis; emit yvals and |derivative|*scale ---
    {
        __shared__ double dk[NMODE];
        __shared__ float  bet[RESN];
        for (int tt = t; tt < RESN; tt += 256) bet[tt] = g_betti[b * RESN + tt];
        __syncthreads();
        for (int k = wv; k < NMODE; k += 4) {
            double p = 0.0;
            for (int tt = lane; tt < RESN; tt += 64) p += (double)bet[tt] * g_qb[b][k][tt];
            p = wave_sum_f64(p);
            if (lane == 0) dk[k] = p;
        }
        __syncthreads();
        const double scale = 2.0 / 999.0;
        for (int tt = t; tt < RESN; tt += 256) {
            double y = 0.0, d = 0.0;
            for (int k = 0; k < NMODE; ++k) {
                y += dk[k] * g_qb[b][k][tt];
                d += dk[k] * g_qdb[b][k][tt];
            }
            const float yv = (float)y;
            const float fd = (float)(fabs(d) * scale);
            for (int rep = 0; rep < BREP; ++rep) {
                oy[(rep * NB + b) * RESN + tt] = yv;
                if (tt >= SAMP && tt < RESN - SAMP)
                    od[(rep * NB + b) * (RESN - 2 * SAMP) + (tt - SAMP)] = fd;
            }
        }
    }
}

// ---------------- launcher (4 dispatches) ----------------
extern "C" void kernel_launch(void* const* d_in, const int* in_sizes, int n_in,
                              void* d_out, int out_size, void* d_ws, size_t ws_size,
                              hipStream_t stream) {
    const int*   ei  = (const int*)d_in[1];    // edge_index (2, 160000)
    const float* ea  = (const float*)d_in[2];  // edge_attr  (160000, 1)
    float*       out = (float*)d_out;          // [land 32x1000 | yvals 32x1000 | fderiv 32x900]

    k_scatter<<<(NEDGE + 255) / 256, 256, 0, stream>>>(ei, ea);
    k_death1<<<(NB * NROI * NROI + 255) / 256, 256, 0, stream>>>();
    k_prim<<<NB, 256, 0, stream>>>();
    k_out<<<NB * RESN / LPB + NB, 256, 0, stream>>>(out);
}

// Round 13
// 77.367 us; speedup vs baseline: 2.4601x; 1.0768x over previous
//
#include <hip/hip_runtime.h>

// ---------------- problem constants ----------------
#define NROI  100
#define NB    4          // 400/100 diagonal blocks
#define NEDGE 160000
#define RESN  1000
#define SAMP  50
#define BREP  8          // batch tiling (B=8)
#define MDEG  44         // effective polynomial rank cutoff
#define NMODE (MDEG + 1)
#define BIGF  1.0e9f
#define PAIR_N 4950      // NROI*(NROI-1)/2 upper-triangular pairs (fixed, sentinel-masked)
#define LPB   8          // landscape grid points per block (2 per wave)

// ---------------- static device workspace ----------------
// INVARIANT: g_adj == 0 at kernel_launch entry. Holds on call 1 (.bss zero-init) and is
// re-established by k_out's fit blocks at the end of every call (replaces a k_zero launch).
__device__ float  g_adj[NB * NROI * NROI];
__device__ float  g_D[NB * NROI * NROI];
__device__ float  g_death1[NB * NROI * NROI];   // upper-tri written each call; lower-tri stays 0
__device__ float2 g_pair[NB][PAIR_N];   // (birth, death) per pair; sentinel (+BIG,-BIG) if MST
__device__ float  g_betti[NB * RESN];
__device__ float  g_smin[NB], g_smax[NB];
__device__ int    g_bnz;                // any nonzero betti? (zeroed each call by k_death1)
__device__ double g_qb[NB][NMODE][RESN];   // per-b orthonormal poly basis (dead path on this data)
__device__ double g_qdb[NB][NMODE][RESN];  // derivatives

// ---------------- helpers ----------------
__device__ inline double wave_sum_f64(double p) {
    for (int off = 32; off > 0; off >>= 1) p += __shfl_xor(p, off, 64);
    return p;
}

// ---------------- 1) scatter-add diagonal-block edges (g_adj pre-zeroed, see invariant) -------
__global__ void k_scatter(const int* __restrict__ ei, const float* __restrict__ ea) {
    const int e = blockIdx.x * blockDim.x + threadIdx.x;
    if (e >= NEDGE) return;
    const int r = ei[e], c = ei[NEDGE + e];
    const int br = r / NROI, bc = c / NROI;
    if (br == bc)
        atomicAdd(&g_adj[br * NROI * NROI + (r - br * NROI) * NROI + (c - bc * NROI)], ea[e]);
}

// ---------------- 2) fused: D = max(1-adj,0) (all cells) + H1 deaths (upper triangle only) ----
// death1[i,j] = max(D_ij, min_k!=i,j max(D_ik,D_jk)); fmin/fmax exact -> assoc-free.
__device__ inline float dclamp(float a) { const float d = 1.f - a; return d > 0.f ? d : 0.f; }
__global__ void k_death1() {
    const int tid = blockIdx.x * blockDim.x + threadIdx.x;
    if (tid >= NB * NROI * NROI) return;
    if (tid == 0) g_bnz = 0;                  // before k_prim's atomicOr (stream-ordered)
    const int b  = tid / (NROI * NROI);
    const int ij = tid % (NROI * NROI);
    const int i = ij / NROI, j = ij % NROI;
    const float* __restrict__ ai = g_adj + b * NROI * NROI + i * NROI;
    const float* __restrict__ aj = g_adj + b * NROI * NROI + j * NROI;
    const float dij = dclamp(ai[j]);
    g_D[tid] = dij;                            // full matrix needed by Prim
    if (i >= j) return;                        // Tm loop only where death1 is consumed
    float Tm = BIGF;
    for (int k = 0; k < NROI; k += 4) {        // static trip count 25 -> compiler unrolls
        const float4 a = *(const float4*)(ai + k);
        const float4 c = *(const float4*)(aj + k);
        const float di0 = dclamp(a.x), di1 = dclamp(a.y), di2 = dclamp(a.z), di3 = dclamp(a.w);
        const float dj0 = dclamp(c.x), dj1 = dclamp(c.y), dj2 = dclamp(c.z), dj3 = dclamp(c.w);
        float m0 = (k + 0 == i || k + 0 == j) ? BIGF : fmaxf(di0, dj0);
        float m1 = (k + 1 == i || k + 1 == j) ? BIGF : fmaxf(di1, dj1);
        float m2 = (k + 2 == i || k + 2 == j) ? BIGF : fmaxf(di2, dj2);
        float m3 = (k + 3 == i || k + 3 == j) ? BIGF : fmaxf(di3, dj3);
        Tm = fminf(Tm, fminf(fminf(m0, m1), fminf(m2, m3)));
    }
    g_death1[tid] = fmaxf(dij, Tm);
}

// ---------------- 3) merged Prim + post-processing (4 blocks x 256) ----------------
__global__ void __launch_bounds__(256) k_prim() {
    const int b = blockIdx.x, t = threadIdx.x;
    const int lane = t & 63, wvi = t >> 6;
    const float* __restrict__ Db = g_D + b * NROI * NROI;
    __shared__ float Dl[NROI * NROI];          // 40 KB
    __shared__ float deathsL[NROI - 1];
    __shared__ int   usL[NROI - 1], vsL[NROI - 1];
    __shared__ int   parL[NROI];
    __shared__ unsigned char mstP[NROI * NROI];
    __shared__ float ndArr[NROI - 1];
    __shared__ int   ndCnt;
    __shared__ float redn[4], redx[4], redd[4];
    // stage D into LDS: MANUALLY 10-deep unrolled, clamped indices -> all 10 global loads
    // issue back-to-back (one latency exposure instead of ten).
    {
        const float4* __restrict__ Db4 = (const float4*)Db;
        float4 r0, r1, r2, r3, r4, r5, r6, r7, r8, r9;
        {
            int i0 = t,           i1 = t + 256,  i2 = t + 512,  i3 = t + 768,  i4 = t + 1024;
            int i5 = t + 1280,    i6 = t + 1536, i7 = t + 1792, i8 = t + 2048, i9 = t + 2304;
            if (i9 > 2499) i9 = 2499;   // only last slice can exceed (t>=196)
            r0 = Db4[i0]; r1 = Db4[i1]; r2 = Db4[i2]; r3 = Db4[i3]; r4 = Db4[i4];
            r5 = Db4[i5]; r6 = Db4[i6]; r7 = Db4[i7]; r8 = Db4[i8]; r9 = Db4[i9];
        }
        float4* Dl4 = (float4*)Dl;
        Dl4[t] = r0; Dl4[t + 256] = r1; Dl4[t + 512] = r2; Dl4[t + 768] = r3;
        Dl4[t + 1024] = r4; Dl4[t + 1280] = r5; Dl4[t + 1536] = r6; Dl4[t + 1792] = r7;
        Dl4[t + 2048] = r8;
        if (t + 2304 < 2500) Dl4[t + 2304] = r9;
    }
    for (int e = t; e < NROI * NROI / 4; e += 256) ((unsigned int*)mstP)[e] = 0;
    for (int s = t; s < NROI - 1; s += 256) { deathsL[s] = 0.f; usL[s] = -1; }
    if (t == 0) ndCnt = 0;
    __syncthreads();

    // ---- wave 0 only: bitmask Prim loop (no barriers inside -> other waves park at next sync) ----
    if (t < 64) {
        const int  i1   = 64 + lane;
        const bool has1 = (i1 < NROI);
        // column-major zero bitmasks from LDS (consecutive lanes -> conflict-free)
        unsigned int zc0[4] = {0, 0, 0, 0}, zc1[4] = {0, 0, 0, 0};
        #pragma unroll 16
        for (int j = 0; j < NROI; ++j) {
            const unsigned int bit = 1u << (j & 31);
            if (Dl[j * NROI + lane] == 0.f) zc0[j >> 5] |= bit;
            if (has1 && Dl[j * NROI + i1] == 0.f) zc1[j >> 5] |= bit;
        }
        unsigned long long Clo = __ballot((zc0[0] & 1u) != 0u);   // row 0 = bit 0 of each column
        unsigned long long Chi = __ballot((zc1[0] & 1u) != 0u);
        unsigned long long Tlo = 1ull, Thi = 0ull;
        const unsigned long long MHI = (1ull << (NROI - 64)) - 1; // 36 valid hi bits
        bool it0 = (lane == 0), it1 = false;
        bool cand0 = (zc0[0] & 1u) != 0u;
        bool cand1 = (zc1[0] & 1u) != 0u;
        int  par0 = 0, par1 = 0;                 // first zero-offerer (frozen once cand)

        int step = 0;
        #pragma unroll 1
        for (; step < NROI - 1; ++step) {
            const unsigned long long alo = Clo & ~Tlo;
            const unsigned long long ahi = Chi & ~Thi & MHI;
            const unsigned long long rlo = ~Tlo;             // remaining nodes
            const unsigned long long rhi = ~Thi & MHI;
            // EARLY EXIT: all remaining are zero-candidates -> rest inserts ascending, death 0
            if (alo == rlo && ahi == rhi) break;
            int j;
            if (alo | ahi) {
                // jnp.argmin first-index == first not-in-tree node with mind==0 (D >= 0 always)
                j = alo ? (__ffsll(alo) - 1) : (63 + __ffsll(ahi));
                if (lane == 0) vsL[step] = j;    // deathsL/usL keep defaults 0 / -1
            } else {
                // rare general fallback: replay mind/parent over insertion order (single-wave LDS
                // ordering guarantees lane-0's earlier vsL writes are visible; no barrier needed)
                float m0 = Dl[lane]; int p0 = 0;
                float m1 = has1 ? Dl[i1] : BIGF; int p1 = 0;
                for (int s = 0; s < step; ++s) {
                    const int q = vsL[s];
                    const float d0 = Dl[q * NROI + lane];
                    if (d0 < m0) { m0 = d0; p0 = q; }     // strict <, as reference
                    if (has1) {
                        const float d1 = Dl[q * NROI + i1];
                        if (d1 < m1) { m1 = d1; p1 = q; }
                    }
                }
                const float v0 = it0 ? BIGF : m0;
                const float v1 = (has1 && !it1) ? m1 : BIGF;
                float vv; int idx, pw;
                if (v0 <= v1) { vv = v0; idx = lane; pw = p0; } else { vv = v1; idx = i1; pw = p1; }
                #pragma unroll
                for (int off = 1; off < 64; off <<= 1) {
                    const float ov = __shfl_xor(vv, off, 64);
                    const int   oi = __shfl_xor(idx, off, 64);
                    const int   op = __shfl_xor(pw, off, 64);
                    if (ov < vv || (ov == vv && oi < idx)) { vv = ov; idx = oi; pw = op; }
                }
                j = idx;
                if (lane == 0) { deathsL[step] = vv; usL[step] = pw; vsL[step] = j; }
            }
            if (j < 64) Tlo |= 1ull << j; else Thi |= 1ull << (j - 64);
            if (lane == j) it0 = true;
            if (i1 == j)   it1 = true;
            // extract bit j of MY columns (same-lane VALU), rebuild row j's mask via ballot
            const int d = j >> 5, sh = j & 31;
            const unsigned int w0 = (d == 0) ? zc0[0] : (d == 1) ? zc0[1] : (d == 2) ? zc0[2] : zc0[3];
            const unsigned int w1 = (d == 0) ? zc1[0] : (d == 1) ? zc1[1] : (d == 2) ? zc1[2] : zc1[3];
            const bool bit0 = (w0 >> sh) & 1u;
            const bool bit1 = (w1 >> sh) & 1u;
            Clo |= __ballot(bit0);
            Chi |= __ballot(bit1);
            // parent = first zero-offerer; frozen once candidate; in-tree nodes never update
            if (bit0 && !cand0 && !it0) { par0 = j; cand0 = true; }
            if (bit1 && !cand1 && !it1) { par1 = j; cand1 = true; }
        }
        // parallel epilogue: remaining nodes inserted ascending at steps step..98
        if (step < NROI - 1) {
            const unsigned long long rlo = ~Tlo;
            const unsigned long long rhi = ~Thi & MHI;
            const int nlo = __popcll(rlo);
            if ((rlo >> lane) & 1ull) {
                const int rank = __popcll(rlo & ((1ull << lane) - 1ull));
                vsL[step + rank] = lane;
            }
            if (has1 && ((rhi >> lane) & 1ull)) {
                const int rank = nlo + __popcll(rhi & ((1ull << lane) - 1ull));
                vsL[step + rank] = i1;
            }
        }
        parL[lane] = par0;
        if (has1) parL[i1] = par1;
    }
    __syncthreads();

    // ---- all 256 threads: mst bitmap + nonzero-death list ----
    if (t < NROI - 1) {
        const int j = vsL[t];
        int u = usL[t];
        if (u < 0) u = parL[j];                   // zero-death => parent = first-zero-offerer
        const int a = u < j ? u : j, c = u < j ? j : u;
        mstP[a * NROI + c] = 1;
        const float dth = deathsL[t];
        if (dth != 0.f) { const int p = atomicAdd(&ndCnt, 1); ndArr[p] = dth; }
    }
    __syncthreads();
    // pair table: 10-deep manually unrolled g_death1 prefetch (one latency exposure),
    // then per-element selects/writes. Clamped duplicate loads' values are discarded.
    float mn = BIGF, mx = -BIGF;
    {
        const float4* __restrict__ d14 = (const float4*)(g_death1 + b * NROI * NROI);
        float4 d4r[10];
        {
            int i9 = t + 2304; if (i9 > 2499) i9 = 2499;
            d4r[0] = d14[t];        d4r[1] = d14[t + 256];  d4r[2] = d14[t + 512];
            d4r[3] = d14[t + 768];  d4r[4] = d14[t + 1024]; d4r[5] = d14[t + 1280];
            d4r[6] = d14[t + 1536]; d4r[7] = d14[t + 1792]; d4r[8] = d14[t + 2048];
            d4r[9] = d14[i9];
        }
        #pragma unroll
        for (int kk = 0; kk < 10; ++kk) {
            const int e4 = t + kk * 256;
            if (e4 < NROI * NROI / 4) {
                const float4 d4 = d4r[kk];
                const float4 b4 = ((const float4*)Dl)[e4];
                const unsigned int m4 = ((const unsigned int*)mstP)[e4];
                const int e = e4 * 4;
                #pragma unroll
                for (int z = 0; z < 4; ++z) {
                    const int ee = e + z;
                    const int i = ee / NROI, j = ee % NROI;
                    if (i < j) {
                        const int pos = i * NROI - (i * (i + 1)) / 2 + (j - i - 1);
                        const bool mst = ((m4 >> (8 * z)) & 0xffu) != 0u;
                        float bv = BIGF, dv = -BIGF;
                        if (!mst) {
                            bv = (z == 0) ? b4.x : (z == 1) ? b4.y : (z == 2) ? b4.z : b4.w;
                            dv = (z == 0) ? d4.x : (z == 1) ? d4.y : (z == 2) ? d4.z : d4.w;
                            mn = fminf(mn, bv); mx = fmaxf(mx, dv);
                        }
                        g_pair[b][pos] = make_float2(bv, dv);
                    }
                }
            }
        }
    }
    float dmx = (t < NROI - 1) ? deathsL[t] : -1.f;
    #pragma unroll
    for (int off = 1; off < 64; off <<= 1) {
        mn  = fminf(mn,  __shfl_xor(mn,  off, 64));
        mx  = fmaxf(mx,  __shfl_xor(mx,  off, 64));
        dmx = fmaxf(dmx, __shfl_xor(dmx, off, 64));
    }
    if (lane == 0) { redn[wvi] = mn; redx[wvi] = mx; redd[wvi] = dmx; }
    __syncthreads();
    if (t == 0) {
        for (int z = 1; z < 4; ++z) {
            redn[0] = fminf(redn[0], redn[z]);
            redx[0] = fmaxf(redx[0], redx[z]);
            redd[0] = fmaxf(redd[0], redd[z]);
        }
        g_smin[b] = redn[0]; g_smax[b] = redx[0];
        if (redd[0] > 0.f) atomicOr(&g_bnz, 1);
    }
    __syncthreads();
    // betti: only NONZERO deaths can satisfy g < death (g >= 0 always) -> exact prefilter
    const float dmax  = redd[0];
    const float stepg = dmax / 999.0f;             // f32 linspace step, start = 0
    const int   nd    = ndCnt;
    for (int tt = t; tt < RESN; tt += 256) {
        const float g = (tt == RESN - 1) ? dmax : (float)tt * stepg;
        int c2 = 0;
        for (int s = 0; s < nd; ++s) c2 += (g < ndArr[s]) ? 1 : 0;
        g_betti[b * RESN + tt] = (float)c2;
    }
}

// ---------------- 4) merged outputs: 500 landscape blocks + 4 fit blocks (basis inlined) --------
__global__ void __launch_bounds__(256) k_out(float* __restrict__ out) {
    const int nLand = NB * RESN / LPB;   // 500 blocks, each: one b, LPB grid points
    const int t = threadIdx.x;
    const int wv = t >> 6, lane = t & 63;
    if (blockIdx.x < nLand) {
        const int blocksPerB = RESN / LPB;             // 125
        const int b      = blockIdx.x / blocksPerB;
        const int ptBase = (blockIdx.x % blocksPerB) * LPB;
        __shared__ float2 prL[PAIR_N];
        // 2475 float4: 10-deep manual unroll, clamped (one latency exposure)
        {
            const float4* __restrict__ gp4 = (const float4*)g_pair[b];
            float4 s[10];
            {
                int i8 = t + 2048; if (i8 > 2474) i8 = 2474;
                int i9 = t + 2304; if (i9 > 2474) i9 = 2474;
                s[0] = gp4[t];        s[1] = gp4[t + 256];  s[2] = gp4[t + 512];
                s[3] = gp4[t + 768];  s[4] = gp4[t + 1024]; s[5] = gp4[t + 1280];
                s[6] = gp4[t + 1536]; s[7] = gp4[t + 1792]; s[8] = gp4[i8];
                s[9] = gp4[i9];
            }
            float4* p4 = (float4*)prL;
            p4[t] = s[0]; p4[t + 256] = s[1]; p4[t + 512] = s[2]; p4[t + 768] = s[3];
            p4[t + 1024] = s[4]; p4[t + 1280] = s[5]; p4[t + 1536] = s[6]; p4[t + 1792] = s[7];
            if (t + 2048 < 2475) p4[t + 2048] = s[8];
            if (t + 2304 < 2475) p4[t + 2304] = s[9];
        }
        __syncthreads();
        const float smn = g_smin[b], smx = g_smax[b];
        const float stepg = (smx - smn) / 999.0f;
        const int tt0 = ptBase + 2 * wv, tt1 = tt0 + 1;
        const float g0 = (tt0 == RESN - 1) ? smx : smn + (float)tt0 * stepg;
        const float g1 = (tt1 == RESN - 1) ? smx : smn + (float)tt1 * stepg;
        const float SQ2 = 1.41421356f;                 // f32 sqrt(2), as reference
        // two top-5 sets in NAMED scalars (no runtime indexing -> registers)
        float a0 = 0.f, a1 = 0.f, a2 = 0.f, a3 = 0.f, a4 = 0.f;
        float c0 = 0.f, c1 = 0.f, c2 = 0.f, c3 = 0.f, c4 = 0.f;
        #pragma unroll 2
        for (int e = lane; e < PAIR_N; e += 64) {
            const float2 p = prL[e];
            float v = fminf(g0 - p.x, p.y - g0);
            v = v > 0.f ? v : 0.f;
            v *= SQ2;
            if (v > a4) {
                a4 = v;
                if (a4 > a3) { const float s = a3; a3 = a4; a4 = s;
                    if (a3 > a2) { const float s2 = a2; a2 = a3; a3 = s2;
                        if (a2 > a1) { const float s3 = a1; a1 = a2; a2 = s3;
                            if (a1 > a0) { const float s4 = a0; a0 = a1; a1 = s4; } } } }
            }
            float w = fminf(g1 - p.x, p.y - g1);
            w = w > 0.f ? w : 0.f;
            w *= SQ2;
            if (w > c4) {
                c4 = w;
                if (c4 > c3) { const float s = c3; c3 = c4; c4 = s;
                    if (c3 > c2) { const float s2 = c2; c2 = c3; c3 = s2;
                        if (c2 > c1) { const float s3 = c1; c1 = c2; c2 = s3;
                            if (c1 > c0) { const float s4 = c0; c0 = c1; c1 = s4; } } } }
            }
        }
        // butterfly reduce: exact top-5 merge network, C[k] = max(A[k],B[k],max_{i+j=k-1} min(A[i],B[j]))
        #pragma unroll
        for (int off = 1; off < 64; off <<= 1) {
            {
                const float b0 = __shfl_xor(a0, off, 64);
                const float b1 = __shfl_xor(a1, off, 64);
                const float b2 = __shfl_xor(a2, off, 64);
                const float b3 = __shfl_xor(a3, off, 64);
                const float b4 = __shfl_xor(a4, off, 64);
                const float r0 = fmaxf(a0, b0);
                const float r1 = fmaxf(fmaxf(a1, b1), fminf(a0, b0));
                const float r2 = fmaxf(fmaxf(a2, b2), fmaxf(fminf(a0, b1), fminf(a1, b0)));
                const float r3 = fmaxf(fmaxf(a3, b3),
                                       fmaxf(fminf(a0, b2), fmaxf(fminf(a1, b1), fminf(a2, b0))));
                const float r4 = fmaxf(fmaxf(a4, b4),
                                       fmaxf(fmaxf(fminf(a0, b3), fminf(a3, b0)),
                                             fmaxf(fminf(a1, b2), fminf(a2, b1))));
                a0 = r0; a1 = r1; a2 = r2; a3 = r3; a4 = r4;
            }
            {
                const float b0 = __shfl_xor(c0, off, 64);
                const float b1 = __shfl_xor(c1, off, 64);
                const float b2 = __shfl_xor(c2, off, 64);
                const float b3 = __shfl_xor(c3, off, 64);
                const float b4 = __shfl_xor(c4, off, 64);
                const float r0 = fmaxf(c0, b0);
                const float r1 = fmaxf(fmaxf(c1, b1), fminf(c0, b0));
                const float r2 = fmaxf(fmaxf(c2, b2), fmaxf(fminf(c0, b1), fminf(c1, b0)));
                const float r3 = fmaxf(fmaxf(c3, b3),
                                       fmaxf(fminf(c0, b2), fmaxf(fminf(c1, b1), fminf(c2, b0))));
                const float r4 = fmaxf(fmaxf(c4, b4),
                                       fmaxf(fmaxf(fminf(c0, b3), fminf(c3, b0)),
                                             fmaxf(fminf(c1, b2), fminf(c2, b1))));
                c0 = r0; c1 = r1; c2 = r2; c3 = r3; c4 = r4;
            }
        }
        if (lane == 0) {
            const float land0 = (a0 + a1 + a2 + a3 + a4) / 5.0f;
            const float land1 = (c0 + c1 + c2 + c3 + c4) / 5.0f;
            for (int rep = 0; rep < BREP; ++rep) {
                out[(rep * NB + b) * RESN + tt0] = land0;
                out[(rep * NB + b) * RESN + tt1] = land1;
            }
        }
        return;
    }
    // ---- fit blocks: re-zero g_adj for the next call (replaces k_zero; see invariant) ----
    const int b = blockIdx.x - nLand;
    {
        float4* az = (float4*)(g_adj + b * NROI * NROI);
        const float4 z4 = make_float4(0.f, 0.f, 0.f, 0.f);
        for (int i = t; i < NROI * NROI / 4; i += 256) az[i] = z4;
    }
    // ---- polynomial fit outputs (basis computed inline per-b; dead path when bnz==0) ----
    float* oy = out + BREP * NB * RESN;
    float* od = out + 2 * BREP * NB * RESN;
    if (g_bnz == 0) {
        // betti == 0 everywhere -> coef == 0 -> yvals/fderiv exactly 0
        for (int tt = t; tt < RESN; tt += 256) {
            for (int rep = 0; rep < BREP; ++rep) {
                oy[(rep * NB + b) * RESN + tt] = 0.f;
                if (tt >= SAMP && tt < RESN - SAMP)
                    od[(rep * NB + b) * (RESN - 2 * SAMP) + (tt - SAMP)] = 0.f;
            }
        }
        return;
    }
    // --- orthonormal basis (Lanczos on diag(x), CGS x2, f64), 256-thread version ---
    {
        __shared__ double xs[RESN];
        __shared__ double w[RESN], dwv[RESN];
        __shared__ double cj[NMODE], ctot[NMODE];
        __shared__ double red2[4];
        for (int tt = t; tt < RESN; tt += 256) {
            xs[tt] = (2.0 * (double)tt - 999.0) / 999.0;
            g_qb[b][0][tt]  = 1.0 / sqrt(1000.0);
            g_qdb[b][0][tt] = 0.0;
        }
        __syncthreads();
        for (int k = 0; k < MDEG; ++k) {
            for (int tt = t; tt < RESN; tt += 256) {
                w[tt]   = xs[tt] * g_qb[b][k][tt];
                dwv[tt] = g_qb[b][k][tt] + xs[tt] * g_qdb[b][k][tt];
            }
            if (t < NMODE) ctot[t] = 0.0;
            __syncthreads();
            for (int round = 0; round < 2; ++round) {
                for (int j = wv; j <= k; j += 4) {
                    double p = 0.0;
                    for (int tt = lane; tt < RESN; tt += 64) p += w[tt] * g_qb[b][j][tt];
                    p = wave_sum_f64(p);
                    if (lane == 0) cj[j] = p;
                }
                __syncthreads();
                for (int tt = t; tt < RESN; tt += 256) {
                    double acc = w[tt];
                    for (int j = 0; j <= k; ++j) acc -= cj[j] * g_qb[b][j][tt];
                    w[tt] = acc;
                }
                if (t <= k) ctot[t] += cj[t];
                __syncthreads();
            }
            for (int tt = t; tt < RESN; tt += 256) {
                double acc = dwv[tt];
                for (int j = 0; j <= k; ++j) acc -= ctot[j] * g_qdb[b][j][tt];
                dwv[tt] = acc;
            }
            double p = 0.0;
            for (int tt = t; tt < RESN; tt += 256) p += w[tt] * w[tt];
            p = wave_sum_f64(p);
            if (lane == 0) red2[wv] = p;
            __syncthreads();
            if (t == 0) red2[0] = sqrt(red2[0] + red2[1] + red2[2] + red2[3]);
            __syncthreads();
            const double beta = red2[0];
            for (int tt = t; tt < RESN; tt += 256) {
                g_qb[b][k + 1][tt]  = w[tt] / beta;
                g_qdb[b][k + 1][tt] = dwv[tt] / beta;
            }
            __syncthreads();
        }
    }
    // --- fit: project betti onto basis; emit yvals and |derivative|*scale ---
    {
        __shared__ double dk[NMODE];
        __shared__ float  bet[RESN];
        for (int tt = t; tt < RESN; tt += 256) bet[tt] = g_betti[b * RESN + tt];
        __syncthreads();
        for (int k = wv; k < NMODE; k += 4) {
            double p = 0.0;
            for (int tt = lane; tt < RESN; tt += 64) p += (double)bet[tt] * g_qb[b][k][tt];
            p = wave_sum_f64(p);
            if (lane == 0) dk[k] = p;
        }
        __syncthreads();
        const double scale = 2.0 / 999.0;
        for (int tt = t; tt < RESN; tt += 256) {
            double y = 0.0, d = 0.0;
            for (int k = 0; k < NMODE; ++k) {
                y += dk[k] * g_qb[b][k][tt];
                d += dk[k] * g_qdb[b][k][tt];
            }
            const float yv = (float)y;
            const float fd = (float)(fabs(d) * scale);
            for (int rep = 0; rep < BREP; ++rep) {
                oy[(rep * NB + b) * RESN + tt] = yv;
                if (tt >= SAMP && tt < RESN - SAMP)
                    od[(rep * NB + b) * (RESN - 2 * SAMP) + (tt - SAMP)] = fd;
            }
        }
    }
}

// ---------------- launcher (4 dispatches) ----------------
extern "C" void kernel_launch(void* const* d_in, const int* in_sizes, int n_in,
                              void* d_out, int out_size, void* d_ws, size_t ws_size,
                              hipStream_t stream) {
    const int*   ei  = (const int*)d_in[1];    // edge_index (2, 160000)
    const float* ea  = (const float*)d_in[2];  // edge_attr  (160000, 1)
    float*       out = (float*)d_out;          // [land 32x1000 | yvals 32x1000 | fderiv 32x900]

    k_scatter<<<(NEDGE + 255) / 256, 256, 0, stream>>>(ei, ea);
    k_death1<<<(NB * NROI * NROI + 255) / 256, 256, 0, stream>>>();
    k_prim<<<NB, 256, 0, stream>>>();
    k_out<<<NB * RESN / LPB + NB, 256, 0, stream>>>(out);
}

// Round 15
// 77.329 us; speedup vs baseline: 2.4613x; 1.0005x over previous
//
#include <hip/hip_runtime.h>

// ---------------- problem constants ----------------
#define NROI  100
#define NB    4          // 400/100 diagonal blocks
#define NEDGE 160000
#define RESN  1000
#define SAMP  50
#define BREP  8          // batch tiling (B=8)
#define MDEG  44         // effective polynomial rank cutoff
#define NMODE (MDEG + 1)
#define BIGF  1.0e9f
#define PAIR_N 4950      // NROI*(NROI-1)/2 upper-triangular pairs (fixed, sentinel-masked)
#define LPB   8          // landscape grid points per block (2 per wave)

// ---------------- static device workspace ----------------
// INVARIANT: g_adj == 0 at kernel_launch entry. Holds on call 1 (.bss zero-init) and is
// re-established by k_out's fit blocks at the end of every call (replaces a k_zero launch).
__device__ float  g_adj[NB * NROI * NROI];
__device__ float  g_D[NB * NROI * NROI];
__device__ float  g_death1[NB * NROI * NROI];   // upper-tri written each call; lower-tri stays 0
__device__ float2 g_pair[NB][PAIR_N];   // (birth, death) per pair; sentinel (+BIG,-BIG) if MST
__device__ float  g_betti[NB * RESN];
__device__ float  g_smin[NB], g_smax[NB];
__device__ int    g_bnz;                // any nonzero betti? (zeroed each call by k_death1)
__device__ double g_qb[NB][NMODE][RESN];   // per-b orthonormal poly basis (dead path on this data)
__device__ double g_qdb[NB][NMODE][RESN];  // derivatives

// ---------------- helpers ----------------
__device__ inline double wave_sum_f64(double p) {
    for (int off = 32; off > 0; off >>= 1) p += __shfl_xor(p, off, 64);
    return p;
}

// ---------------- 1) scatter-add diagonal-block edges (g_adj pre-zeroed, see invariant) -------
__global__ void k_scatter(const int* __restrict__ ei, const float* __restrict__ ea) {
    const int e = blockIdx.x * blockDim.x + threadIdx.x;
    if (e >= NEDGE) return;
    const int r = ei[e], c = ei[NEDGE + e];
    const int br = r / NROI, bc = c / NROI;
    if (br == bc)
        atomicAdd(&g_adj[br * NROI * NROI + (r - br * NROI) * NROI + (c - bc * NROI)], ea[e]);
}

// ---------------- 2) fused: D = max(1-adj,0) (all cells) + H1 deaths (upper triangle only) ----
// death1[i,j] = max(D_ij, min_k!=i,j max(D_ik,D_jk)); fmin/fmax exact -> assoc-free.
__device__ inline float dclamp(float a) { const float d = 1.f - a; return d > 0.f ? d : 0.f; }
__global__ void k_death1() {
    const int tid = blockIdx.x * blockDim.x + threadIdx.x;
    if (tid >= NB * NROI * NROI) return;
    if (tid == 0) g_bnz = 0;                  // before k_prim's atomicOr (stream-ordered)
    const int b  = tid / (NROI * NROI);
    const int ij = tid % (NROI * NROI);
    const int i = ij / NROI, j = ij % NROI;
    const float* __restrict__ ai = g_adj + b * NROI * NROI + i * NROI;
    const float* __restrict__ aj = g_adj + b * NROI * NROI + j * NROI;
    const float dij = dclamp(ai[j]);
    g_D[tid] = dij;                            // full matrix needed by Prim
    if (i >= j) return;                        // Tm loop only where death1 is consumed
    float Tm = BIGF;
    for (int k = 0; k < NROI; k += 4) {        // static trip count 25 -> compiler unrolls
        const float4 a = *(const float4*)(ai + k);
        const float4 c = *(const float4*)(aj + k);
        const float di0 = dclamp(a.x), di1 = dclamp(a.y), di2 = dclamp(a.z), di3 = dclamp(a.w);
        const float dj0 = dclamp(c.x), dj1 = dclamp(c.y), dj2 = dclamp(c.z), dj3 = dclamp(c.w);
        float m0 = (k + 0 == i || k + 0 == j) ? BIGF : fmaxf(di0, dj0);
        float m1 = (k + 1 == i || k + 1 == j) ? BIGF : fmaxf(di1, dj1);
        float m2 = (k + 2 == i || k + 2 == j) ? BIGF : fmaxf(di2, dj2);
        float m3 = (k + 3 == i || k + 3 == j) ? BIGF : fmaxf(di3, dj3);
        Tm = fminf(Tm, fminf(fminf(m0, m1), fminf(m2, m3)));
    }
    g_death1[tid] = fmaxf(dij, Tm);
}

// ---------------- 3) merged Prim + post-processing (4 blocks x 256) ----------------
__global__ void __launch_bounds__(256) k_prim() {
    const int b = blockIdx.x, t = threadIdx.x;
    const int lane = t & 63, wvi = t >> 6;
    const float* __restrict__ Db = g_D + b * NROI * NROI;
    __shared__ float Dl[NROI * NROI];          // 40 KB
    __shared__ float deathsL[NROI - 1];
    __shared__ int   usL[NROI - 1], vsL[NROI - 1];
    __shared__ int   parL[NROI];
    __shared__ unsigned char mstP[NROI * NROI];
    __shared__ float ndArr[NROI - 1];
    __shared__ int   ndCnt;
    __shared__ float redn[4], redx[4], redd[4];
    // stage D into LDS: MANUALLY 10-deep unrolled, clamped indices -> all 10 global loads
    // issue back-to-back (one latency exposure instead of ten).
    {
        const float4* __restrict__ Db4 = (const float4*)Db;
        float4 r0, r1, r2, r3, r4, r5, r6, r7, r8, r9;
        {
            int i0 = t,           i1 = t + 256,  i2 = t + 512,  i3 = t + 768,  i4 = t + 1024;
            int i5 = t + 1280,    i6 = t + 1536, i7 = t + 1792, i8 = t + 2048, i9 = t + 2304;
            if (i9 > 2499) i9 = 2499;   // only last slice can exceed (t>=196)
            r0 = Db4[i0]; r1 = Db4[i1]; r2 = Db4[i2]; r3 = Db4[i3]; r4 = Db4[i4];
            r5 = Db4[i5]; r6 = Db4[i6]; r7 = Db4[i7]; r8 = Db4[i8]; r9 = Db4[i9];
        }
        float4* Dl4 = (float4*)Dl;
        Dl4[t] = r0; Dl4[t + 256] = r1; Dl4[t + 512] = r2; Dl4[t + 768] = r3;
        Dl4[t + 1024] = r4; Dl4[t + 1280] = r5; Dl4[t + 1536] = r6; Dl4[t + 1792] = r7;
        Dl4[t + 2048] = r8;
        if (t + 2304 < 2500) Dl4[t + 2304] = r9;
    }
    for (int e = t; e < NROI * NROI / 4; e += 256) ((unsigned int*)mstP)[e] = 0;
    for (int s = t; s < NROI - 1; s += 256) { deathsL[s] = 0.f; usL[s] = -1; }
    if (t == 0) ndCnt = 0;
    __syncthreads();

    // ---- wave 0 only: bitmask Prim loop (no barriers inside -> other waves park at next sync) ----
    if (t < 64) {
        const int  i1   = 64 + lane;
        const bool has1 = (i1 < NROI);
        // column-major zero bitmasks from LDS (consecutive lanes -> conflict-free)
        unsigned int zc0[4] = {0, 0, 0, 0}, zc1[4] = {0, 0, 0, 0};
        #pragma unroll 16
        for (int j = 0; j < NROI; ++j) {
            const unsigned int bit = 1u << (j & 31);
            if (Dl[j * NROI + lane] == 0.f) zc0[j >> 5] |= bit;
            if (has1 && Dl[j * NROI + i1] == 0.f) zc1[j >> 5] |= bit;
        }
        unsigned long long Clo = __ballot((zc0[0] & 1u) != 0u);   // row 0 = bit 0 of each column
        unsigned long long Chi = __ballot((zc1[0] & 1u) != 0u);
        unsigned long long Tlo = 1ull, Thi = 0ull;
        const unsigned long long MHI = (1ull << (NROI - 64)) - 1; // 36 valid hi bits
        bool it0 = (lane == 0), it1 = false;
        bool cand0 = (zc0[0] & 1u) != 0u;
        bool cand1 = (zc1[0] & 1u) != 0u;
        int  par0 = 0, par1 = 0;                 // first zero-offerer (frozen once cand)

        int step = 0;
        #pragma unroll 1
        for (; step < NROI - 1; ++step) {
            const unsigned long long alo = Clo & ~Tlo;
            const unsigned long long ahi = Chi & ~Thi & MHI;
            const unsigned long long rlo = ~Tlo;             // remaining nodes
            const unsigned long long rhi = ~Thi & MHI;
            // EARLY EXIT: all remaining are zero-candidates -> rest inserts ascending, death 0
            if (alo == rlo && ahi == rhi) break;
            int j;
            if (alo | ahi) {
                // jnp.argmin first-index == first not-in-tree node with mind==0 (D >= 0 always)
                j = alo ? (__ffsll(alo) - 1) : (63 + __ffsll(ahi));
                if (lane == 0) vsL[step] = j;    // deathsL/usL keep defaults 0 / -1
            } else {
                // rare general fallback: replay mind/parent over insertion order (single-wave LDS
                // ordering guarantees lane-0's earlier vsL writes are visible; no barrier needed)
                float m0 = Dl[lane]; int p0 = 0;
                float m1 = has1 ? Dl[i1] : BIGF; int p1 = 0;
                for (int s = 0; s < step; ++s) {
                    const int q = vsL[s];
                    const float d0 = Dl[q * NROI + lane];
                    if (d0 < m0) { m0 = d0; p0 = q; }     // strict <, as reference
                    if (has1) {
                        const float d1 = Dl[q * NROI + i1];
                        if (d1 < m1) { m1 = d1; p1 = q; }
                    }
                }
                const float v0 = it0 ? BIGF : m0;
                const float v1 = (has1 && !it1) ? m1 : BIGF;
                float vv; int idx, pw;
                if (v0 <= v1) { vv = v0; idx = lane; pw = p0; } else { vv = v1; idx = i1; pw = p1; }
                #pragma unroll
                for (int off = 1; off < 64; off <<= 1) {
                    const float ov = __shfl_xor(vv, off, 64);
                    const int   oi = __shfl_xor(idx, off, 64);
                    const int   op = __shfl_xor(pw, off, 64);
                    if (ov < vv || (ov == vv && oi < idx)) { vv = ov; idx = oi; pw = op; }
                }
                j = idx;
                if (lane == 0) { deathsL[step] = vv; usL[step] = pw; vsL[step] = j; }
            }
            if (j < 64) Tlo |= 1ull << j; else Thi |= 1ull << (j - 64);
            if (lane == j) it0 = true;
            if (i1 == j)   it1 = true;
            // extract bit j of MY columns (same-lane VALU), rebuild row j's mask via ballot
            const int d = j >> 5, sh = j & 31;
            const unsigned int w0 = (d == 0) ? zc0[0] : (d == 1) ? zc0[1] : (d == 2) ? zc0[2] : zc0[3];
            const unsigned int w1 = (d == 0) ? zc1[0] : (d == 1) ? zc1[1] : (d == 2) ? zc1[2] : zc1[3];
            const bool bit0 = (w0 >> sh) & 1u;
            const bool bit1 = (w1 >> sh) & 1u;
            Clo |= __ballot(bit0);
            Chi |= __ballot(bit1);
            // parent = first zero-offerer; frozen once candidate; in-tree nodes never update
            if (bit0 && !cand0 && !it0) { par0 = j; cand0 = true; }
            if (bit1 && !cand1 && !it1) { par1 = j; cand1 = true; }
        }
        // parallel epilogue: remaining nodes inserted ascending at steps step..98
        if (step < NROI - 1) {
            const unsigned long long rlo = ~Tlo;
            const unsigned long long rhi = ~Thi & MHI;
            const int nlo = __popcll(rlo);
            if ((rlo >> lane) & 1ull) {
                const int rank = __popcll(rlo & ((1ull << lane) - 1ull));
                vsL[step + rank] = lane;
            }
            if (has1 && ((rhi >> lane) & 1ull)) {
                const int rank = nlo + __popcll(rhi & ((1ull << lane) - 1ull));
                vsL[step + rank] = i1;
            }
        }
        parL[lane] = par0;
        if (has1) parL[i1] = par1;
    }
    __syncthreads();

    // ---- all 256 threads: mst bitmap + nonzero-death list ----
    if (t < NROI - 1) {
        const int j = vsL[t];
        int u = usL[t];
        if (u < 0) u = parL[j];                   // zero-death => parent = first-zero-offerer
        const int a = u < j ? u : j, c = u < j ? j : u;
        mstP[a * NROI + c] = 1;
        const float dth = deathsL[t];
        if (dth != 0.f) { const int p = atomicAdd(&ndCnt, 1); ndArr[p] = dth; }
    }
    __syncthreads();
    // pair table: 10-deep manually unrolled g_death1 prefetch (one latency exposure),
    // then per-element selects/writes. Clamped duplicate loads' values are discarded.
    float mn = BIGF, mx = -BIGF;
    {
        const float4* __restrict__ d14 = (const float4*)(g_death1 + b * NROI * NROI);
        float4 d4r[10];
        {
            int i9 = t + 2304; if (i9 > 2499) i9 = 2499;
            d4r[0] = d14[t];        d4r[1] = d14[t + 256];  d4r[2] = d14[t + 512];
            d4r[3] = d14[t + 768];  d4r[4] = d14[t + 1024]; d4r[5] = d14[t + 1280];
            d4r[6] = d14[t + 1536]; d4r[7] = d14[t + 1792]; d4r[8] = d14[t + 2048];
            d4r[9] = d14[i9];
        }
        #pragma unroll
        for (int kk = 0; kk < 10; ++kk) {
            const int e4 = t + kk * 256;
            if (e4 < NROI * NROI / 4) {
                const float4 d4 = d4r[kk];
                const float4 b4 = ((const float4*)Dl)[e4];
                const unsigned int m4 = ((const unsigned int*)mstP)[e4];
                const int e = e4 * 4;
                #pragma unroll
                for (int z = 0; z < 4; ++z) {
                    const int ee = e + z;
                    const int i = ee / NROI, j = ee % NROI;
                    if (i < j) {
                        const int pos = i * NROI - (i * (i + 1)) / 2 + (j - i - 1);
                        const bool mst = ((m4 >> (8 * z)) & 0xffu) != 0u;
                        float bv = BIGF, dv = -BIGF;
                        if (!mst) {
                            bv = (z == 0) ? b4.x : (z == 1) ? b4.y : (z == 2) ? b4.z : b4.w;
                            dv = (z == 0) ? d4.x : (z == 1) ? d4.y : (z == 2) ? d4.z : d4.w;
                            mn = fminf(mn, bv); mx = fmaxf(mx, dv);
                        }
                        g_pair[b][pos] = make_float2(bv, dv);
                    }
                }
            }
        }
    }
    float dmx = (t < NROI - 1) ? deathsL[t] : -1.f;
    #pragma unroll
    for (int off = 1; off < 64; off <<= 1) {
        mn  = fminf(mn,  __shfl_xor(mn,  off, 64));
        mx  = fmaxf(mx,  __shfl_xor(mx,  off, 64));
        dmx = fmaxf(dmx, __shfl_xor(dmx, off, 64));
    }
    if (lane == 0) { redn[wvi] = mn; redx[wvi] = mx; redd[wvi] = dmx; }
    __syncthreads();
    if (t == 0) {
        for (int z = 1; z < 4; ++z) {
            redn[0] = fminf(redn[0], redn[z]);
            redx[0] = fmaxf(redx[0], redx[z]);
            redd[0] = fmaxf(redd[0], redd[z]);
        }
        g_smin[b] = redn[0]; g_smax[b] = redx[0];
        if (redd[0] > 0.f) atomicOr(&g_bnz, 1);
    }
    __syncthreads();
    // betti: only NONZERO deaths can satisfy g < death (g >= 0 always) -> exact prefilter
    const float dmax  = redd[0];
    const float stepg = dmax / 999.0f;             // f32 linspace step, start = 0
    const int   nd    = ndCnt;
    for (int tt = t; tt < RESN; tt += 256) {
        const float g = (tt == RESN - 1) ? dmax : (float)tt * stepg;
        int c2 = 0;
        for (int s = 0; s < nd; ++s) c2 += (g < ndArr[s]) ? 1 : 0;
        g_betti[b * RESN + tt] = (float)c2;
    }
}

// ---------------- 4) merged outputs: 500 landscape blocks + 4 fit blocks (basis inlined) --------
__global__ void __launch_bounds__(256) k_out(float* __restrict__ out) {
    const int nLand = NB * RESN / LPB;   // 500 blocks, each: one b, LPB grid points
    const int t = threadIdx.x;
    const int wv = t >> 6, lane = t & 63;
    if (blockIdx.x < nLand) {
        const int blocksPerB = RESN / LPB;             // 125
        const int b      = blockIdx.x / blocksPerB;
        const int ptBase = (blockIdx.x % blocksPerB) * LPB;
        __shared__ float2 prL[PAIR_N];
        // 2475 float4: 10-deep manual unroll, clamped (one latency exposure)
        {
            const float4* __restrict__ gp4 = (const float4*)g_pair[b];
            float4 s[10];
            {
                int i8 = t + 2048; if (i8 > 2474) i8 = 2474;
                int i9 = t + 2304; if (i9 > 2474) i9 = 2474;
                s[0] = gp4[t];        s[1] = gp4[t + 256];  s[2] = gp4[t + 512];
                s[3] = gp4[t + 768];  s[4] = gp4[t + 1024]; s[5] = gp4[t + 1280];
                s[6] = gp4[t + 1536]; s[7] = gp4[t + 1792]; s[8] = gp4[i8];
                s[9] = gp4[i9];
            }
            float4* p4 = (float4*)prL;
            p4[t] = s[0]; p4[t + 256] = s[1]; p4[t + 512] = s[2]; p4[t + 768] = s[3];
            p4[t + 1024] = s[4]; p4[t + 1280] = s[5]; p4[t + 1536] = s[6]; p4[t + 1792] = s[7];
            if (t + 2048 < 2475) p4[t + 2048] = s[8];
            if (t + 2304 < 2475) p4[t + 2304] = s[9];
        }
        __syncthreads();
        const float smn = g_smin[b], smx = g_smax[b];
        const float stepg = (smx - smn) / 999.0f;
        const int tt0 = ptBase + 2 * wv, tt1 = tt0 + 1;
        const float g0 = (tt0 == RESN - 1) ? smx : smn + (float)tt0 * stepg;
        const float g1 = (tt1 == RESN - 1) ? smx : smn + (float)tt1 * stepg;
        const float SQ2 = 1.41421356f;                 // f32 sqrt(2), as reference
        // two top-5 sets in NAMED scalars (no runtime indexing -> registers)
        float a0 = 0.f, a1 = 0.f, a2 = 0.f, a3 = 0.f, a4 = 0.f;
        float c0 = 0.f, c1 = 0.f, c2 = 0.f, c3 = 0.f, c4 = 0.f;
        #pragma unroll 2
        for (int e = lane; e < PAIR_N; e += 64) {
            const float2 p = prL[e];
            float v = fminf(g0 - p.x, p.y - g0);
            v = v > 0.f ? v : 0.f;
            v *= SQ2;
            if (v > a4) {
                a4 = v;
                if (a4 > a3) { const float s = a3; a3 = a4; a4 = s;
                    if (a3 > a2) { const float s2 = a2; a2 = a3; a3 = s2;
                        if (a2 > a1) { const float s3 = a1; a1 = a2; a2 = s3;
                            if (a1 > a0) { const float s4 = a0; a0 = a1; a1 = s4; } } } }
            }
            float w = fminf(g1 - p.x, p.y - g1);
            w = w > 0.f ? w : 0.f;
            w *= SQ2;
            if (w > c4) {
                c4 = w;
                if (c4 > c3) { const float s = c3; c3 = c4; c4 = s;
                    if (c3 > c2) { const float s2 = c2; c2 = c3; c3 = s2;
                        if (c2 > c1) { const float s3 = c1; c1 = c2; c2 = s3;
                            if (c1 > c0) { const float s4 = c0; c0 = c1; c1 = s4; } } } }
            }
        }
        // butterfly reduce: exact top-5 merge network, C[k] = max(A[k],B[k],max_{i+j=k-1} min(A[i],B[j]))
        #pragma unroll
        for (int off = 1; off < 64; off <<= 1) {
            {
                const float b0 = __shfl_xor(a0, off, 64);
                const float b1 = __shfl_xor(a1, off, 64);
                const float b2 = __shfl_xor(a2, off, 64);
                const float b3 = __shfl_xor(a3, off, 64);
                const float b4 = __shfl_xor(a4, off, 64);
                const float r0 = fmaxf(a0, b0);
                const float r1 = fmaxf(fmaxf(a1, b1), fminf(a0, b0));
                const float r2 = fmaxf(fmaxf(a2, b2), fmaxf(fminf(a0, b1), fminf(a1, b0)));
                const float r3 = fmaxf(fmaxf(a3, b3),
                                       fmaxf(fminf(a0, b2), fmaxf(fminf(a1, b1), fminf(a2, b0))));
                const float r4 = fmaxf(fmaxf(a4, b4),
                                       fmaxf(fmaxf(fminf(a0, b3), fminf(a3, b0)),
                                             fmaxf(fminf(a1, b2), fminf(a2, b1))));
                a0 = r0; a1 = r1; a2 = r2; a3 = r3; a4 = r4;
            }
            {
                const float b0 = __shfl_xor(c0, off, 64);
                const float b1 = __shfl_xor(c1, off, 64);
                const float b2 = __shfl_xor(c2, off, 64);
                const float b3 = __shfl_xor(c3, off, 64);
                const float b4 = __shfl_xor(c4, off, 64);
                const float r0 = fmaxf(c0, b0);
                const float r1 = fmaxf(fmaxf(c1, b1), fminf(c0, b0));
                const float r2 = fmaxf(fmaxf(c2, b2), fmaxf(fminf(c0, b1), fminf(c1, b0)));
                const float r3 = fmaxf(fmaxf(c3, b3),
                                       fmaxf(fminf(c0, b2), fmaxf(fminf(c1, b1), fminf(c2, b0))));
                const float r4 = fmaxf(fmaxf(c4, b4),
                                       fmaxf(fmaxf(fminf(c0, b3), fminf(c3, b0)),
                                             fmaxf(fminf(c1, b2), fminf(c2, b1))));
                c0 = r0; c1 = r1; c2 = r2; c3 = r3; c4 = r4;
            }
        }
        if (lane == 0) {
            const float land0 = (a0 + a1 + a2 + a3 + a4) / 5.0f;
            const float land1 = (c0 + c1 + c2 + c3 + c4) / 5.0f;
            for (int rep = 0; rep < BREP; ++rep) {
                out[(rep * NB + b) * RESN + tt0] = land0;
                out[(rep * NB + b) * RESN + tt1] = land1;
            }
        }
        return;
    }
    // ---- fit blocks: re-zero g_adj for the next call (replaces k_zero; see invariant) ----
    const int b = blockIdx.x - nLand;
    {
        float4* az = (float4*)(g_adj + b * NROI * NROI);
        const float4 z4 = make_float4(0.f, 0.f, 0.f, 0.f);
        for (int i = t; i < NROI * NROI / 4; i += 256) az[i] = z4;
    }
    // ---- polynomial fit outputs (basis computed inline per-b; dead path when bnz==0) ----
    float* oy = out + BREP * NB * RESN;
    float* od = out + 2 * BREP * NB * RESN;
    if (g_bnz == 0) {
        // betti == 0 everywhere -> coef == 0 -> yvals/fderiv exactly 0
        for (int tt = t; tt < RESN; tt += 256) {
            for (int rep = 0; rep < BREP; ++rep) {
                oy[(rep * NB + b) * RESN + tt] = 0.f;
                if (tt >= SAMP && tt < RESN - SAMP)
                    od[(rep * NB + b) * (RESN - 2 * SAMP) + (tt - SAMP)] = 0.f;
            }
        }
        return;
    }
    // --- orthonormal basis (Lanczos on diag(x), CGS x2, f64), 256-thread version ---
    {
        __shared__ double xs[RESN];
        __shared__ double w[RESN], dwv[RESN];
        __shared__ double cj[NMODE], ctot[NMODE];
        __shared__ double red2[4];
        for (int tt = t; tt < RESN; tt += 256) {
            xs[tt] = (2.0 * (double)tt - 999.0) / 999.0;
            g_qb[b][0][tt]  = 1.0 / sqrt(1000.0);
            g_qdb[b][0][tt] = 0.0;
        }
        __syncthreads();
        for (int k = 0; k < MDEG; ++k) {
            for (int tt = t; tt < RESN; tt += 256) {
                w[tt]   = xs[tt] * g_qb[b][k][tt];
                dwv[tt] = g_qb[b][k][tt] + xs[tt] * g_qdb[b][k][tt];
            }
            if (t < NMODE) ctot[t] = 0.0;
            __syncthreads();
            for (int round = 0; round < 2; ++round) {
                for (int j = wv; j <= k; j += 4) {
                    double p = 0.0;
                    for (int tt = lane; tt < RESN; tt += 64) p += w[tt] * g_qb[b][j][tt];
                    p = wave_sum_f64(p);
                    if (lane == 0) cj[j] = p;
                }
                __syncthreads();
                for (int tt = t; tt < RESN; tt += 256) {
                    double acc = w[tt];
                    for (int j = 0; j <= k; ++j) acc -= cj[j] * g_qb[b][j][tt];
                    w[tt] = acc;
                }
                if (t <= k) ctot[t] += cj[t];
                __syncthreads();
            }
            for (int tt = t; tt < RESN; tt += 256) {
                double acc = dwv[tt];
                for (int j = 0; j <= k; ++j) acc -= ctot[j] * g_qdb[b][j][tt];
                dwv[tt] = acc;
            }
            double p = 0.0;
            for (int tt = t; tt < RESN; tt += 256) p += w[tt] * w[tt];
            p = wave_sum_f64(p);
            if (lane == 0) red2[wv] = p;
            __syncthreads();
            if (t == 0) red2[0] = sqrt(red2[0] + red2[1] + red2[2] + red2[3]);
            __syncthreads();
            const double beta = red2[0];
            for (int tt = t; tt < RESN; tt += 256) {
                g_qb[b][k + 1][tt]  = w[tt] / beta;
                g_qdb[b][k + 1][tt] = dwv[tt] / beta;
            }
            __syncthreads();
        }
    }
    // --- fit: project betti onto basis; emit yvals and |derivative|*scale ---
    {
        __shared__ double dk[NMODE];
        __shared__ float  bet[RESN];
        for (int tt = t; tt < RESN; tt += 256) bet[tt] = g_betti[b * RESN + tt];
        __syncthreads();
        for (int k = wv; k < NMODE; k += 4) {
            double p = 0.0;
            for (int tt = lane; tt < RESN; tt += 64) p += (double)bet[tt] * g_qb[b][k][tt];
            p = wave_sum_f64(p);
            if (lane == 0) dk[k] = p;
        }
        __syncthreads();
        const double scale = 2.0 / 999.0;
        for (int tt = t; tt < RESN; tt += 256) {
            double y = 0.0, d = 0.0;
            for (int k = 0; k < NMODE; ++k) {
                y += dk[k] * g_qb[b][k][tt];
                d += dk[k] * g_qdb[b][k][tt];
            }
            const float yv = (float)y;
            const float fd = (float)(fabs(d) * scale);
            for (int rep = 0; rep < BREP; ++rep) {
                oy[(rep * NB + b) * RESN + tt] = yv;
                if (tt >= SAMP && tt < RESN - SAMP)
                    od[(rep * NB + b) * (RESN - 2 * SAMP) + (tt - SAMP)] = fd;
            }
        }
    }
}

// ---------------- launcher (4 dispatches) ----------------
extern "C" void kernel_launch(void* const* d_in, const int* in_sizes, int n_in,
                              void* d_out, int out_size, void* d_ws, size_t ws_size,
                              hipStream_t stream) {
    const int*   ei  = (const int*)d_in[1];    // edge_index (2, 160000)
    const float* ea  = (const float*)d_in[2];  // edge_attr  (160000, 1)
    float*       out = (float*)d_out;          // [land 32x1000 | yvals 32x1000 | fderiv 32x900]

    k_scatter<<<(NEDGE + 255) / 256, 256, 0, stream>>>(ei, ea);
    k_death1<<<(NB * NROI * NROI + 255) / 256, 256, 0, stream>>>();
    k_prim<<<NB, 256, 0, stream>>>();
    k_out<<<NB * RESN / LPB + NB, 256, 0, stream>>>(out);
}